// Round 7
// baseline (16469.550 us; speedup 1.0000x reference)
//
#include <hip/hip_runtime.h>
#include <cstdint>
#include <cstddef>

__device__ __forceinline__ float sigf(float x) { return 1.f / (1.f + expf(-x)); }

// fp16 pack/unpack helpers (weights-only precision reduction)
__device__ __forceinline__ unsigned packh(float a, float b) {
  union { unsigned u; _Float16 h[2]; } cv;
  cv.h[0] = (_Float16)a; cv.h[1] = (_Float16)b; return cv.u;
}
__device__ __forceinline__ float2 uph(unsigned u) {
  union { unsigned uu; _Float16 h[2]; } cv; cv.uu = u;
  return make_float2((float)cv.h[0], (float)cv.h[1]);
}

static constexpr int TT = 8192;   // frames
static constexpr int MM = 64;     // actions
static constexpr int CC = 32;     // classes
static constexpr int DD = 512;    // model dim

// ---------------------------------------------------------------- ws zeroing
__global__ void zero_k(float* __restrict__ p, long n) {
  long i = (long)blockIdx.x * 256 + threadIdx.x;
  long stride = (long)gridDim.x * 256;
  for (; i < n; i += stride) p[i] = 0.f;
}

// ---------------------------------------------------------------- elementwise
__global__ void copy_k(const float* __restrict__ a, float* __restrict__ o, int n) {
  int i = blockIdx.x * 256 + threadIdx.x;
  if (i < n) o[i] = a[i];
}
__global__ void addff_k(const float* __restrict__ a, const float* __restrict__ b, float* __restrict__ o, int n) {
  int i = blockIdx.x * 256 + threadIdx.x;
  if (i < n) o[i] = a[i] + b[i];
}
__global__ void acomb_k(const float* __restrict__ hf, const float* __restrict__ hb, float* __restrict__ o, int n) {
  int i = blockIdx.x * 256 + threadIdx.x;
  if (i >= n) return;
  int s = i >> 9, j = i & 511;
  float v = (j < 256) ? hf[(size_t)s * 256 + j] : hb[(size_t)s * 256 + (j - 256)];
  o[i] = fmaxf(v, 0.f);
}
__global__ void gatherpos_k(const float* __restrict__ fpos, const int* __restrict__ centers,
                            float* __restrict__ segpos, int n) {
  int i = blockIdx.x * 256 + threadIdx.x;
  if (i >= n) return;
  int s = i >> 9, dd = i & 511;
  int ct = centers[s];
  ct = ct < 0 ? 0 : (ct > TT - 1 ? TT - 1 : ct);
  segpos[i] = fpos[(size_t)ct * 512 + dd];
}

// ---------------------------------------------------------------- text norms
__global__ void tnorm_k(const float* __restrict__ text, float* __restrict__ tnorm) {
  int c = blockIdx.x * 256 + threadIdx.x;
  if (c >= 32) return;
  float s = 0.f;
  for (int dd = 0; dd < 512; dd++) { float v = text[(size_t)c * 512 + dd]; s += v * v; }
  tnorm[c] = sqrtf(s);
}

// ---------------------------------------------------- naive GEMM (small ops)
__global__ void ngemm_k(const float* __restrict__ A, const float* __restrict__ B,
                        const float* __restrict__ bias, float* __restrict__ C,
                        int M, int N, int K) {
  int idx = blockIdx.x * 256 + threadIdx.x;
  if (idx >= M * N) return;
  int m = idx / N, n = idx - m * N;
  float a = bias ? bias[n] : 0.f;
  const float* Ar = A + (size_t)m * K;
  for (int k = 0; k < K; k++) a += Ar[k] * B[(size_t)k * N + n];
  C[idx] = a;
}

// ---------------------------------------------------- naive attention pieces
__global__ void nlogit_k(const float* __restrict__ Q, const float* __restrict__ Kk,
                         float* __restrict__ L, int NY, int NX) {
  int idx = blockIdx.x * 256 + threadIdx.x;
  if (idx >= NY * NX) return;
  int y = idx / NX, x = idx - y * NX;
  const float* qr = Q + (size_t)y * 512;
  const float* kr = Kk + (size_t)x * 512;
  float d = 0.f;
  for (int k = 0; k < 512; k++) d += qr[k] * kr[k];
  L[idx] = d * 0.044194173824159216f;  // 1/sqrt(512)
}
__global__ void nsoft_k(float* __restrict__ L, int NY, int NX) {  // 1 thread / row
  int y = blockIdx.x * 256 + threadIdx.x;
  if (y >= NY) return;
  float* row = L + (size_t)y * NX;
  float m = row[0];
  for (int x = 1; x < NX; x++) m = fmaxf(m, row[x]);
  float s = 0.f;
  for (int x = 0; x < NX; x++) { float p = expf(row[x] - m); row[x] = p; s += p; }
  const float inv = 1.f / s;
  for (int x = 0; x < NX; x++) row[x] *= inv;
}
__global__ void nav_k(const float* __restrict__ P, const float* __restrict__ V,
                      float* __restrict__ O, int NY, int NX) {
  int idx = blockIdx.x * 256 + threadIdx.x;
  if (idx >= NY * 512) return;
  int y = idx >> 9, dd = idx & 511;
  const float* pr = P + (size_t)y * NX;
  float o = 0.f;
  for (int x = 0; x < NX; x++) o += pr[x] * V[(size_t)x * 512 + dd];
  O[idx] = o;
}

// ------------------------------------------------------ naive argmax (pred)
__global__ void nargmax_k(const float* __restrict__ V, const float* __restrict__ text,
                          const float* __restrict__ tnorm, int* __restrict__ pred) {
  int r = blockIdx.x * 256 + threadIdx.x;
  if (r >= TT) return;
  const float* vr = V + (size_t)r * 512;
  float best = -1e30f; int bc = 0;
  for (int c = 0; c < 32; c++) {
    float dot = 0.f;
    for (int dd = 0; dd < 512; dd++) dot += vr[dd] * text[(size_t)c * 512 + dd];
    dot /= tnorm[c];
    if (dot > best) { best = dot; bc = c; }
  }
  pred[r] = bc;
}

// ------------------------------------- sequential segmentation (single thread)
__global__ void nseg_k(const int* __restrict__ pred, int* __restrict__ segid,
                       int* __restrict__ starts, int* __restrict__ centers,
                       int* __restrict__ cnts) {
  if (blockIdx.x != 0 || threadIdx.x != 0) return;
  int sid = 0;
  starts[0] = 0;
  for (int t = 0; t < TT; t++) {
    if (t > 0 && pred[t] != pred[t - 1]) { sid++; starts[sid] = t; }
    segid[t] = sid;
  }
  const int Sd = sid + 1;
  for (int s = 0; s < TT; s++) {
    if (s < Sd) {
      int e = (s == Sd - 1) ? (TT - 1) : (starts[s + 1] - 1);
      centers[s] = (starts[s] + e) >> 1;
      cnts[s] = e - starts[s] + 1;
    } else { starts[s] = 0; cnts[s] = 1; centers[s] = 0; }
  }
}

// ---------------------------------------------------------- segment mean pool
__global__ void segmean_k(const float* __restrict__ ff, const int* __restrict__ starts,
                          const int* __restrict__ cnts, float* __restrict__ segmean, int S) {
  int idx = blockIdx.x * 256 + threadIdx.x;
  if (idx >= S * 512) return;
  int s = idx >> 9, dd = idx & 511;
  int st = starts[s], n = cnts[s];
  st = st < 0 ? 0 : (st > TT - 1 ? TT - 1 : st);
  n = n < 1 ? 1 : n;
  if (st + n > TT) n = TT - st;
  float a = 0.f;
  for (int t = st; t < st + n; t++) a += ff[(size_t)t * 512 + dd];
  segmean[idx] = a / (float)n;
}

// -------------------------- action-GRU weight repack: W(512,1536) -> packed T
// agT[j*256 + p] = packh(W[2p][j], W[2p+1][j]),  j in [0,1536), p in [0,256)
__global__ void agt_k(const float* __restrict__ W, unsigned* __restrict__ T) {
  int idx = blockIdx.x * 256 + threadIdx.x;
  if (idx >= 1536 * 256) return;
  int j = idx >> 8, p = idx & 255;
  T[idx] = packh(W[(size_t)(2 * p) * 1536 + j], W[(size_t)(2 * p + 1) * 1536 + j]);
}

// ----------------------------------------- fused bidirectional seg GRU (H=256)
// Whh column resident in registers as packed fp16 (128 VGPRs/thread).
__launch_bounds__(768)
__global__ void gru_seg_k(const float* __restrict__ gi_f, const float* __restrict__ gi_b,
                          const float* __restrict__ Whh_f, const float* __restrict__ bhh_f,
                          const float* __restrict__ Whh_b, const float* __restrict__ bhh_b,
                          float* __restrict__ hf, float* __restrict__ hb, int S) {
  const bool bwd = (blockIdx.x == 1);
  const float* gi = bwd ? gi_b : gi_f;
  const float* Whh = bwd ? Whh_b : Whh_f;
  const float* bhh = bwd ? bhh_b : bhh_f;
  float* ho = bwd ? hb : hf;
  __shared__ float hs[256];
  __shared__ __align__(16) _Float16 hh[256];
  __shared__ float ghs[768];
  const int tid = threadIdx.x;
  // load my Whh column, packed fp16 pairs: wreg[p] = (W[2p][tid], W[2p+1][tid])
  unsigned wreg[128];
#pragma unroll
  for (int p = 0; p < 128; p++) {
    const float w0 = Whh[(size_t)(2 * p) * 768 + tid];
    const float w1 = Whh[(size_t)(2 * p + 1) * 768 + tid];
    wreg[p] = packh(w0, w1);
  }
  if (tid < 256) { hs[tid] = 0.f; hh[tid] = (_Float16)0.f; }
  const float bj = bhh[tid];
  __syncthreads();
  const uint4* hp4 = reinterpret_cast<const uint4*>(hh);
  for (int step = 0; step < S; step++) {
    const int s = bwd ? (S - 1 - step) : step;
    float a0 = 0.f, a1 = 0.f, a2 = 0.f, a3 = 0.f;
#pragma unroll
    for (int q = 0; q < 32; q++) {
      const uint4 hv = hp4[q];
      const float2 h0 = uph(hv.x), h1 = uph(hv.y), h2 = uph(hv.z), h3 = uph(hv.w);
      const float2 w0 = uph(wreg[4 * q + 0]), w1 = uph(wreg[4 * q + 1]);
      const float2 w2 = uph(wreg[4 * q + 2]), w3 = uph(wreg[4 * q + 3]);
      a0 += h0.x * w0.x + h0.y * w0.y;
      a1 += h1.x * w1.x + h1.y * w1.y;
      a2 += h2.x * w2.x + h2.y * w2.y;
      a3 += h3.x * w3.x + h3.y * w3.y;
    }
    ghs[tid] = bj + (a0 + a1) + (a2 + a3);
    __syncthreads();
    if (tid < 256) {
      const float r = sigf(gi[(size_t)s * 768 + tid] + ghs[tid]);
      const float z = sigf(gi[(size_t)s * 768 + 256 + tid] + ghs[256 + tid]);
      const float nn = tanhf(gi[(size_t)s * 768 + 512 + tid] + r * ghs[512 + tid]);
      const float hn = (1.f - z) * nn + z * hs[tid];
      hs[tid] = hn;
      hh[tid] = (_Float16)hn;
      ho[(size_t)s * 256 + tid] = hn;
    }
    __syncthreads();
  }
}

// ----------------------------------------------- fused action GRU (H=512)
// Streams packed-fp16 transposed weights (agT) with uint4 loads.
__launch_bounds__(768)
__global__ void gru_act_k(const float* __restrict__ gi, const unsigned* __restrict__ agT,
                          const float* __restrict__ bhh, float* __restrict__ hout, int steps) {
  __shared__ float hs[512];
  __shared__ __align__(16) _Float16 hh[512];
  __shared__ float ghs[1536];
  const int tid = threadIdx.x;
  if (tid < 512) { hs[tid] = 0.f; hh[tid] = (_Float16)0.f; }
  const float bj0 = bhh[tid];
  const float bj1 = bhh[tid + 768];
  __syncthreads();
  const uint4* hp4 = reinterpret_cast<const uint4*>(hh);          // 64 uint4 = 512 h
  const uint4* c0 = reinterpret_cast<const uint4*>(agT + (size_t)tid * 256);
  const uint4* c1 = reinterpret_cast<const uint4*>(agT + (size_t)(tid + 768) * 256);
  for (int step = 0; step < steps; step++) {
    float g0 = 0.f, g1 = 0.f, g0b = 0.f, g1b = 0.f;
#pragma unroll 8
    for (int q = 0; q < 64; q++) {
      const uint4 hv = hp4[q];
      const uint4 wa = c0[q];
      const uint4 wb = c1[q];
      const float2 h0 = uph(hv.x), h1 = uph(hv.y), h2 = uph(hv.z), h3 = uph(hv.w);
      const float2 a0 = uph(wa.x), a1 = uph(wa.y), a2 = uph(wa.z), a3 = uph(wa.w);
      const float2 b0 = uph(wb.x), b1 = uph(wb.y), b2 = uph(wb.z), b3 = uph(wb.w);
      g0  += h0.x * a0.x + h0.y * a0.y + h1.x * a1.x + h1.y * a1.y;
      g0b += h2.x * a2.x + h2.y * a2.y + h3.x * a3.x + h3.y * a3.y;
      g1  += h0.x * b0.x + h0.y * b0.y + h1.x * b1.x + h1.y * b1.y;
      g1b += h2.x * b2.x + h2.y * b2.y + h3.x * b3.x + h3.y * b3.y;
    }
    ghs[tid] = bj0 + g0 + g0b;
    ghs[tid + 768] = bj1 + g1 + g1b;
    __syncthreads();
    if (tid < 512) {
      const float r = sigf(gi[(size_t)step * 1536 + tid] + ghs[tid]);
      const float z = sigf(gi[(size_t)step * 1536 + 512 + tid] + ghs[512 + tid]);
      const float nn = tanhf(gi[(size_t)step * 1536 + 1024 + tid] + r * ghs[1024 + tid]);
      const float hn = (1.f - z) * nn + z * hs[tid];
      hs[tid] = hn;
      hh[tid] = (_Float16)hn;
      hout[(size_t)step * 512 + tid] = hn;
    }
    __syncthreads();
  }
}

// ------------------------------------------------------------ tiled GEMM
// C[M,N] = A[M,K] @ B[K,N] + bias   (M,N multiples of 64 ONLY)
__launch_bounds__(256)
__global__ void gemm_k(const float* __restrict__ A, const float* __restrict__ B,
                       const float* __restrict__ bias, float* __restrict__ C,
                       int M, int N, int K) {
  __shared__ float As[16][64];
  __shared__ float Bs[16][64];
  const int tid = threadIdx.x;
  const int n0 = blockIdx.x * 64, m0 = blockIdx.y * 64;
  const int tx = tid & 15, ty = tid >> 4;
  const int am = tid >> 2, ak = (tid & 3) << 2;
  const int bk = tid >> 4, bn = (tid & 15) << 2;
  float acc[4][4] = {};
  for (int k0 = 0; k0 < K; k0 += 16) {
    const float4 av = *reinterpret_cast<const float4*>(A + (size_t)(m0 + am) * K + k0 + ak);
    As[ak + 0][am] = av.x; As[ak + 1][am] = av.y; As[ak + 2][am] = av.z; As[ak + 3][am] = av.w;
    const float4 bv = *reinterpret_cast<const float4*>(B + (size_t)(k0 + bk) * N + n0 + bn);
    Bs[bk][bn + 0] = bv.x; Bs[bk][bn + 1] = bv.y; Bs[bk][bn + 2] = bv.z; Bs[bk][bn + 3] = bv.w;
    __syncthreads();
#pragma unroll
    for (int i = 0; i < 16; i++) {
      const float4 a4 = *reinterpret_cast<const float4*>(&As[i][ty * 4]);
      const float4 b4 = *reinterpret_cast<const float4*>(&Bs[i][tx * 4]);
      const float aa[4] = {a4.x, a4.y, a4.z, a4.w};
      const float bb[4] = {b4.x, b4.y, b4.z, b4.w};
#pragma unroll
      for (int x = 0; x < 4; x++)
#pragma unroll
        for (int y = 0; y < 4; y++) acc[x][y] += aa[x] * bb[y];
    }
    __syncthreads();
  }
#pragma unroll
  for (int x = 0; x < 4; x++) {
    const int m = m0 + ty * 4 + x;
#pragma unroll
    for (int y = 0; y < 4; y++) {
      const int n = n0 + tx * 4 + y;
      float v = acc[x][y];
      if (bias) v += bias[n];
      C[(size_t)m * N + n] = v;
    }
  }
}

// ---------------------------- ff2 = relu([seg2[seg_id[t]], ff[t]] @ Wsf + bsf)
// writes TRANSPOSED (D, T) for the TCN.  K=1024.
__launch_bounds__(256)
__global__ void ff2_k(const float* __restrict__ seg2, const float* __restrict__ ff,
                      const int* __restrict__ segid, const float* __restrict__ Wsf,
                      const float* __restrict__ bsf, float* __restrict__ Y, int S) {
  __shared__ float As[16][64];  // [k][m]  m = frame
  __shared__ float Bs[16][64];  // [k][n]  n = out dim
  const int tid = threadIdx.x;
  const int m0 = blockIdx.x * 64;  // frames
  const int n0 = blockIdx.y * 64;  // dims
  const int tx = tid & 15, ty = tid >> 4;
  const int am = tid >> 2, ak = (tid & 3) << 2;
  const int bk = tid >> 4, bn = (tid & 15) << 2;
  const int t = m0 + am;
  int sid = segid[t];
  sid = sid < 0 ? 0 : (sid >= S ? S - 1 : sid);
  float acc[4][4] = {};  // [n][m]
  for (int k0 = 0; k0 < 1024; k0 += 16) {
    const float* src = (k0 + ak < 512) ? (seg2 + (size_t)sid * 512 + k0 + ak)
                                       : (ff + (size_t)t * 512 + (k0 + ak - 512));
    const float4 av = *reinterpret_cast<const float4*>(src);
    As[ak + 0][am] = av.x; As[ak + 1][am] = av.y; As[ak + 2][am] = av.z; As[ak + 3][am] = av.w;
    const float4 bv = *reinterpret_cast<const float4*>(Wsf + (size_t)(k0 + bk) * 512 + n0 + bn);
    Bs[bk][bn + 0] = bv.x; Bs[bk][bn + 1] = bv.y; Bs[bk][bn + 2] = bv.z; Bs[bk][bn + 3] = bv.w;
    __syncthreads();
#pragma unroll
    for (int i = 0; i < 16; i++) {
      const float4 a4 = *reinterpret_cast<const float4*>(&As[i][tx * 4]);
      const float4 b4 = *reinterpret_cast<const float4*>(&Bs[i][ty * 4]);
      const float aa[4] = {a4.x, a4.y, a4.z, a4.w};
      const float bb[4] = {b4.x, b4.y, b4.z, b4.w};
#pragma unroll
      for (int yy = 0; yy < 4; yy++)
#pragma unroll
        for (int xx = 0; xx < 4; xx++) acc[yy][xx] += bb[yy] * aa[xx];
    }
    __syncthreads();
  }
#pragma unroll
  for (int yy = 0; yy < 4; yy++) {
    const int n = n0 + ty * 4 + yy;
    const float bb = bsf[n];
    float4 o;
    o.x = fmaxf(acc[yy][0] + bb, 0.f);
    o.y = fmaxf(acc[yy][1] + bb, 0.f);
    o.z = fmaxf(acc[yy][2] + bb, 0.f);
    o.w = fmaxf(acc[yy][3] + bb, 0.f);
    *reinterpret_cast<float4*>(Y + (size_t)n * TT + m0 + tx * 4) = o;
  }
}

// ------------------------------------------------------------------- TCN conv
// X,Y: (512,T).  NTAPS==1: W[o][i]; NTAPS==3: W[o][i][3]; 'SAME', dilation d<=32.
template<int NTAPS, int RELU, int RES>
__launch_bounds__(256)
__global__ void conv_k(const float* __restrict__ X, const float* __restrict__ W,
                       const float* __restrict__ bias, const float* __restrict__ Res,
                       float* __restrict__ Y, int dil) {
  __shared__ float Xs[16][128];
  __shared__ float Ws[NTAPS][16][64];
  const int t0 = blockIdx.x * 64, c0 = blockIdx.y * 64;
  const int d = (NTAPS == 3) ? dil : 0;
  const int width = 64 + 2 * d;
  const int tid = threadIdx.x, tx = tid & 15, ty = tid >> 4;
  const int wc = tid >> 2, wi0 = (tid & 3) << 2;
  float acc[4][4] = {};  // [c][t]
  for (int k0 = 0; k0 < 512; k0 += 16) {
    for (int e = tid; e < 16 * width; e += 256) {
      const int ttl = e % width, ii = e / width;
      const int gt = t0 - d + ttl;
      Xs[ii][ttl] = (gt >= 0 && gt < TT) ? X[(size_t)(k0 + ii) * TT + gt] : 0.f;
    }
    if (NTAPS == 1) {
      const float4 wv = *reinterpret_cast<const float4*>(W + (size_t)(c0 + wc) * 512 + k0 + wi0);
      Ws[0][wi0 + 0][wc] = wv.x; Ws[0][wi0 + 1][wc] = wv.y;
      Ws[0][wi0 + 2][wc] = wv.z; Ws[0][wi0 + 3][wc] = wv.w;
    } else {
#pragma unroll
      for (int j = 0; j < 4; j++)
#pragma unroll
        for (int tap = 0; tap < NTAPS; tap++)
          Ws[tap][wi0 + j][wc] = W[((size_t)(c0 + wc) * 512 + k0 + wi0 + j) * 3 + tap];
    }
    __syncthreads();
#pragma unroll
    for (int i = 0; i < 16; i++) {
#pragma unroll
      for (int tap = 0; tap < NTAPS; tap++) {
        const float4 w4 = *reinterpret_cast<const float4*>(&Ws[tap][i][ty * 4]);
        const float wv4[4] = {w4.x, w4.y, w4.z, w4.w};
        const int xb = tx * 4 + tap * d;
        float xv[4];
        xv[0] = Xs[i][xb + 0]; xv[1] = Xs[i][xb + 1];
        xv[2] = Xs[i][xb + 2]; xv[3] = Xs[i][xb + 3];
#pragma unroll
        for (int a = 0; a < 4; a++)
#pragma unroll
          for (int b = 0; b < 4; b++) acc[a][b] += wv4[a] * xv[b];
      }
    }
    __syncthreads();
  }
#pragma unroll
  for (int a = 0; a < 4; a++) {
    const int c = c0 + ty * 4 + a;
    const float bb = bias[c];
    float vals[4];
#pragma unroll
    for (int b = 0; b < 4; b++) {
      float v = acc[a][b] + bb;
      if (RES) v += Res[(size_t)c * TT + t0 + tx * 4 + b];
      if (RELU) v = fmaxf(v, 0.f);
      vals[b] = v;
    }
    *reinterpret_cast<float4*>(Y + (size_t)c * TT + t0 + tx * 4) =
        make_float4(vals[0], vals[1], vals[2], vals[3]);
  }
}

// -------------------- tiled transpose (512,T) -> out (T,512) + f32 copy (T,512)
__launch_bounds__(256)
__global__ void temit_k(const float* __restrict__ Xin, float* __restrict__ outp,
                        float* __restrict__ Aout) {
  __shared__ float tile[32][33];
  const int t0 = blockIdx.x * 32, d0 = blockIdx.y * 32;
  const int lx = threadIdx.x & 31, ly = threadIdx.x >> 5;
#pragma unroll
  for (int r = 0; r < 4; r++)
    tile[ly + 8 * r][lx] = Xin[(size_t)(d0 + ly + 8 * r) * TT + t0 + lx];
  __syncthreads();
#pragma unroll
  for (int r = 0; r < 4; r++) {
    const int t = t0 + ly + 8 * r, dd = d0 + lx;
    const float v = tile[lx][ly + 8 * r];
    outp[(size_t)t * 512 + dd] = v;
    Aout[(size_t)t * 512 + dd] = v;
  }
}

// ---------------------------------------------------------------- cosine sim
__global__ void nsim_k(const float* __restrict__ V, const float* __restrict__ text,
                       const float* __restrict__ tnorm, float* __restrict__ out, int R) {
  int idx = blockIdx.x * 256 + threadIdx.x;  // r*32 + c
  if (idx >= R * 32) return;
  int r = idx >> 5, c = idx & 31;
  const float* vr = V + (size_t)r * 512;
  float ss = 0.f, dot = 0.f;
  for (int dd = 0; dd < 512; dd++) {
    float v = vr[dd];
    ss += v * v;
    dot += v * text[(size_t)c * 512 + dd];
  }
  out[idx] = dot / (sqrtf(ss) * tnorm[c]);
}

// ======================================================================= host
extern "C" void kernel_launch(void* const* d_in, const int* in_sizes, int n_in,
                              void* d_out, int out_size, void* d_ws, size_t ws_size,
                              hipStream_t stream) {
  const float* in_ff   = (const float*)d_in[0];
  const float* in_act  = (const float*)d_in[1];
  const float* in_fpos = (const float*)d_in[2];
  const float* in_apos = (const float*)d_in[3];
  const float* in_text = (const float*)d_in[4];
  const float* Wf2c = (const float*)d_in[5];  const float* bf2c = (const float*)d_in[6];
  const float* Wa2c = (const float*)d_in[7];  const float* ba2c = (const float*)d_in[8];
  const float* Ws2c = (const float*)d_in[9];  const float* bs2c = (const float*)d_in[10];
  const float* Wih_f = (const float*)d_in[11]; const float* Whh_f = (const float*)d_in[12];
  const float* bih_f = (const float*)d_in[13]; const float* bhh_f = (const float*)d_in[14];
  const float* Wih_b = (const float*)d_in[15]; const float* Whh_b = (const float*)d_in[16];
  const float* bih_b = (const float*)d_in[17]; const float* bhh_b = (const float*)d_in[18];
  const float* Wcomb = (const float*)d_in[19]; const float* bcomb = (const float*)d_in[20];
  const float* f2a_Wq = (const float*)d_in[21]; const float* f2a_Wk = (const float*)d_in[22];
  const float* f2a_Wv = (const float*)d_in[23]; const float* f2a_Wo = (const float*)d_in[24];
  const float* f2a_bo = (const float*)d_in[25];
  const float* ag_Wih = (const float*)d_in[26]; const float* ag_Whh = (const float*)d_in[27];
  const float* ag_bih = (const float*)d_in[28]; const float* ag_bhh = (const float*)d_in[29];
  const float* a2f_Wq = (const float*)d_in[30]; const float* a2f_Wk = (const float*)d_in[31];
  const float* a2f_Wv = (const float*)d_in[32]; const float* a2f_Wo = (const float*)d_in[33];
  const float* a2f_bo = (const float*)d_in[34];
  const float* Wsf = (const float*)d_in[35]; const float* bsf = (const float*)d_in[36];
  const float* tcn_inW = (const float*)d_in[37]; const float* tcn_inb = (const float*)d_in[38];
  const float* tcn_dW = (const float*)d_in[39]; const float* tcn_db = (const float*)d_in[40];
  const float* tcn_pW = (const float*)d_in[41]; const float* tcn_pb = (const float*)d_in[42];
  const float* tcn_outW = (const float*)d_in[43]; const float* tcn_outb = (const float*)d_in[44];

  int S = (out_size - (TT * DD + MM * DD + TT * CC + MM * CC)) / CC;
  if (S < 1) S = 1;
  if (S > TT) S = TT;

  // ---------------- workspace layout
  char* ws = (char*)d_ws;
  size_t off = 0;
  auto alloc = [&](size_t b) -> char* { char* p = ws + off; off += (b + 255) & ~(size_t)255; return p; };
  const size_t BTD = (size_t)TT * DD * 4;
  float* bufA = (float*)alloc(BTD);
  float* bufB = (float*)alloc(BTD);
  unsigned* agT = (unsigned*)alloc((size_t)1536 * 256 * 4);
  int* pred    = (int*)alloc((size_t)TT * 4);
  int* segid   = (int*)alloc((size_t)TT * 4);
  int* starts  = (int*)alloc((size_t)TT * 4);
  int* centers = (int*)alloc((size_t)TT * 4);
  int* cnts    = (int*)alloc((size_t)TT * 4);
  float* tnorm = (float*)alloc(32 * 4);
  float* segmean = (float*)alloc((size_t)S * 512 * 4);
  float* gif  = (float*)alloc((size_t)S * 768 * 4);
  float* gib  = (float*)alloc((size_t)S * 768 * 4);
  float* hfb  = (float*)alloc((size_t)S * 256 * 4);
  float* hbb  = (float*)alloc((size_t)S * 256 * 4);
  float* acmb = (float*)alloc((size_t)S * 512 * 4);
  float* segc = (float*)alloc((size_t)S * 512 * 4);
  float* segpos = (float*)alloc((size_t)S * 512 * 4);
  float* kin  = (float*)alloc((size_t)S * 512 * 4);
  float* kf2a = (float*)alloc((size_t)S * 512 * 4);
  float* vf2a = (float*)alloc((size_t)S * 512 * 4);
  float* q2   = (float*)alloc((size_t)S * 512 * 4);
  float* att2 = (float*)alloc((size_t)S * 512 * 4);
  float* seg2 = (float*)alloc((size_t)S * 512 * 4);
  float* vseg = (float*)alloc((size_t)S * 512 * 4);
  float* pbuf = (float*)alloc((size_t)64 * S * 4);
  float* qin  = (float*)alloc((size_t)64 * 512 * 4);
  float* qf2a = (float*)alloc((size_t)64 * 512 * 4);
  float* att1 = (float*)alloc((size_t)64 * 512 * 4);
  float* af0  = (float*)alloc((size_t)64 * 512 * 4);
  float* aggi = (float*)alloc((size_t)64 * 1536 * 4);
  float* afg  = (float*)alloc((size_t)64 * 512 * 4);
  float* k2in = (float*)alloc((size_t)64 * 512 * 4);
  float* k2   = (float*)alloc((size_t)64 * 512 * 4);
  float* v2   = (float*)alloc((size_t)64 * 512 * 4);
  float* vaf  = (float*)alloc((size_t)64 * 512 * 4);
  (void)ws_size; (void)in_sizes; (void)n_in;

  float* outp = (float*)d_out;
  float* out_ff   = outp;
  float* out_af   = outp + (size_t)TT * DD;
  float* out_fsim = out_af + (size_t)MM * DD;
  float* out_asim = out_fsim + (size_t)TT * CC;
  float* out_ssim = out_asim + (size_t)MM * CC;

  auto GR = [](long n) { return (unsigned)((n + 255) / 256); };

  // zero ws (defensive)
  zero_k<<<2048, 256, 0, stream>>>((float*)d_ws, (long)(off / 4));

  tnorm_k<<<1, 256, 0, stream>>>(in_text, tnorm);
  agt_k<<<1536, 256, 0, stream>>>(ag_Whh, agT);

  // segmentation (tiled GEMM for the T-sized projection)
  gemm_k<<<dim3(8, 128), 256, 0, stream>>>(in_ff, Wf2c, bf2c, bufA, TT, 512, 512);
  nargmax_k<<<GR(TT), 256, 0, stream>>>(bufA, in_text, tnorm, pred);
  nseg_k<<<1, 64, 0, stream>>>(pred, segid, starts, centers, cnts);
  segmean_k<<<GR((long)S * 512), 256, 0, stream>>>(in_ff, starts, cnts, segmean, S);

  // seg BiGRU (register-resident fp16 weights)
  ngemm_k<<<GR((long)S * 768), 256, 0, stream>>>(segmean, Wih_f, bih_f, gif, S, 768, 512);
  ngemm_k<<<GR((long)S * 768), 256, 0, stream>>>(segmean, Wih_b, bih_b, gib, S, 768, 512);
  gru_seg_k<<<2, 768, 0, stream>>>(gif, gib, Whh_f, bhh_f, Whh_b, bhh_b, hfb, hbb, S);
  acomb_k<<<GR((long)S * 512), 256, 0, stream>>>(hfb, hbb, acmb, S * 512);
  ngemm_k<<<GR((long)S * 512), 256, 0, stream>>>(acmb, Wcomb, bcomb, segc, S, 512, 512);
  gatherpos_k<<<GR((long)S * 512), 256, 0, stream>>>(in_fpos, centers, segpos, S * 512);

  // f2a attention (actions query segments)
  addff_k<<<GR(64 * 512), 256, 0, stream>>>(in_act, in_apos, qin, 64 * 512);
  addff_k<<<GR((long)S * 512), 256, 0, stream>>>(segc, segpos, kin, S * 512);
  ngemm_k<<<GR(64 * 512), 256, 0, stream>>>(qin, f2a_Wq, nullptr, qf2a, 64, 512, 512);
  ngemm_k<<<GR((long)S * 512), 256, 0, stream>>>(kin, f2a_Wk, nullptr, kf2a, S, 512, 512);
  ngemm_k<<<GR((long)S * 512), 256, 0, stream>>>(segc, f2a_Wv, nullptr, vf2a, S, 512, 512);
  nlogit_k<<<GR((long)64 * S), 256, 0, stream>>>(qf2a, kf2a, pbuf, 64, S);
  nsoft_k<<<1, 256, 0, stream>>>(pbuf, 64, S);
  nav_k<<<GR(64 * 512), 256, 0, stream>>>(pbuf, vf2a, att1, 64, S);
  ngemm_k<<<GR(64 * 512), 256, 0, stream>>>(att1, f2a_Wo, f2a_bo, af0, 64, 512, 512);

  // action GRU (streamed packed-fp16 transposed weights)
  ngemm_k<<<GR(64 * 1536), 256, 0, stream>>>(af0, ag_Wih, ag_bih, aggi, 64, 1536, 512);
  gru_act_k<<<1, 768, 0, stream>>>(aggi, agT, ag_bhh, afg, MM);
  copy_k<<<GR(64 * 512), 256, 0, stream>>>(afg, out_af, 64 * 512);

  // a2f attention (segments query actions)
  addff_k<<<GR(64 * 512), 256, 0, stream>>>(afg, in_apos, k2in, 64 * 512);
  ngemm_k<<<GR((long)S * 512), 256, 0, stream>>>(kin, a2f_Wq, nullptr, q2, S, 512, 512);
  ngemm_k<<<GR(64 * 512), 256, 0, stream>>>(k2in, a2f_Wk, nullptr, k2, 64, 512, 512);
  ngemm_k<<<GR(64 * 512), 256, 0, stream>>>(afg, a2f_Wv, nullptr, v2, 64, 512, 512);
  nlogit_k<<<GR((long)S * 64), 256, 0, stream>>>(q2, k2, pbuf, S, 64);
  nsoft_k<<<GR(S), 256, 0, stream>>>(pbuf, S, 64);
  nav_k<<<GR((long)S * 512), 256, 0, stream>>>(pbuf, v2, att2, S, 64);
  ngemm_k<<<GR((long)S * 512), 256, 0, stream>>>(att2, a2f_Wo, a2f_bo, seg2, S, 512, 512);

  // frame fusion + TCN (tiled), ping-pong bufA <-> bufB as (D,T)
  ff2_k<<<dim3(128, 8), 256, 0, stream>>>(seg2, in_ff, segid, Wsf, bsf, bufA, S);
  conv_k<1, 0, 0><<<dim3(128, 8), 256, 0, stream>>>(bufA, tcn_inW, tcn_inb, nullptr, bufB, 1);
  for (int l = 0; l < 6; l++) {
    conv_k<3, 1, 0><<<dim3(128, 8), 256, 0, stream>>>(
        bufB, tcn_dW + (size_t)l * 512 * 512 * 3, tcn_db + (size_t)l * 512, nullptr, bufA, 1 << l);
    conv_k<1, 0, 1><<<dim3(128, 8), 256, 0, stream>>>(
        bufA, tcn_pW + (size_t)l * 512 * 512, tcn_pb + (size_t)l * 512, bufB, bufB, 1);
  }
  conv_k<1, 0, 0><<<dim3(128, 8), 256, 0, stream>>>(bufB, tcn_outW, tcn_outb, nullptr, bufA, 1);
  temit_k<<<dim3(256, 16), 256, 0, stream>>>(bufA, out_ff, bufB);

  // similarity heads (tiled GEMM for the T-sized projection)
  gemm_k<<<dim3(8, 128), 256, 0, stream>>>(bufB, Wf2c, bf2c, bufA, TT, 512, 512);
  nsim_k<<<GR((long)TT * 32), 256, 0, stream>>>(bufA, in_text, tnorm, out_fsim, TT);
  ngemm_k<<<GR(64 * 512), 256, 0, stream>>>(afg, Wa2c, ba2c, vaf, 64, 512, 512);
  nsim_k<<<GR(64 * 32), 256, 0, stream>>>(vaf, in_text, tnorm, out_asim, 64);
  ngemm_k<<<GR((long)S * 512), 256, 0, stream>>>(seg2, Ws2c, bs2c, vseg, S, 512, 512);
  nsim_k<<<GR((long)S * 32), 256, 0, stream>>>(vseg, in_text, tnorm, out_ssim, S);
}

// Round 8
// 9583.322 us; speedup vs baseline: 1.7186x; 1.7186x over previous
//
#include <hip/hip_runtime.h>
#include <cstdint>
#include <cstddef>

__device__ __forceinline__ float sigf(float x) { return 1.f / (1.f + expf(-x)); }

// fp16 pack/unpack helpers (weights-only precision reduction)
__device__ __forceinline__ unsigned packh(float a, float b) {
  union { unsigned u; _Float16 h[2]; } cv;
  cv.h[0] = (_Float16)a; cv.h[1] = (_Float16)b; return cv.u;
}
__device__ __forceinline__ float2 uph(unsigned u) {
  union { unsigned uu; _Float16 h[2]; } cv; cv.uu = u;
  return make_float2((float)cv.h[0], (float)cv.h[1]);
}

static constexpr int TT = 8192;   // frames
static constexpr int MM = 64;     // actions
static constexpr int CC = 32;     // classes
static constexpr int DD = 512;    // model dim
static constexpr unsigned GUARD_MAX = 1u << 30;

// ---------------------------------------------------------------- ws zeroing
__global__ void zero_k(float* __restrict__ p, long n) {
  long i = (long)blockIdx.x * 256 + threadIdx.x;
  long stride = (long)gridDim.x * 256;
  for (; i < n; i += stride) p[i] = 0.f;
}

// ---------------------------------------------------------------- elementwise
__global__ void copy_k(const float* __restrict__ a, float* __restrict__ o, int n) {
  int i = blockIdx.x * 256 + threadIdx.x;
  if (i < n) o[i] = a[i];
}
__global__ void addff_k(const float* __restrict__ a, const float* __restrict__ b, float* __restrict__ o, int n) {
  int i = blockIdx.x * 256 + threadIdx.x;
  if (i < n) o[i] = a[i] + b[i];
}
__global__ void acomb_k(const float* __restrict__ hf, const float* __restrict__ hb, float* __restrict__ o, int n) {
  int i = blockIdx.x * 256 + threadIdx.x;
  if (i >= n) return;
  int s = i >> 9, j = i & 511;
  float v = (j < 256) ? hf[(size_t)s * 256 + j] : hb[(size_t)s * 256 + (j - 256)];
  o[i] = fmaxf(v, 0.f);
}
__global__ void gatherpos_k(const float* __restrict__ fpos, const int* __restrict__ centers,
                            float* __restrict__ segpos, int n) {
  int i = blockIdx.x * 256 + threadIdx.x;
  if (i >= n) return;
  int s = i >> 9, dd = i & 511;
  int ct = centers[s];
  ct = ct < 0 ? 0 : (ct > TT - 1 ? TT - 1 : ct);
  segpos[i] = fpos[(size_t)ct * 512 + dd];
}

// ---------------------------------------------------------------- text norms
__global__ void tnorm_k(const float* __restrict__ text, float* __restrict__ tnorm) {
  int c = blockIdx.x * 256 + threadIdx.x;
  if (c >= 32) return;
  float s = 0.f;
  for (int dd = 0; dd < 512; dd++) { float v = text[(size_t)c * 512 + dd]; s += v * v; }
  tnorm[c] = sqrtf(s);
}

// ---------------------------------------------------- naive GEMM (small ops)
__global__ void ngemm_k(const float* __restrict__ A, const float* __restrict__ B,
                        const float* __restrict__ bias, float* __restrict__ C,
                        int M, int N, int K) {
  int idx = blockIdx.x * 256 + threadIdx.x;
  if (idx >= M * N) return;
  int m = idx / N, n = idx - m * N;
  float a = bias ? bias[n] : 0.f;
  const float* Ar = A + (size_t)m * K;
  for (int k = 0; k < K; k++) a += Ar[k] * B[(size_t)k * N + n];
  C[idx] = a;
}

// ---------------------------------------------------- naive attention pieces
__global__ void nlogit_k(const float* __restrict__ Q, const float* __restrict__ Kk,
                         float* __restrict__ L, int NY, int NX) {
  int idx = blockIdx.x * 256 + threadIdx.x;
  if (idx >= NY * NX) return;
  int y = idx / NX, x = idx - y * NX;
  const float* qr = Q + (size_t)y * 512;
  const float* kr = Kk + (size_t)x * 512;
  float d = 0.f;
  for (int k = 0; k < 512; k++) d += qr[k] * kr[k];
  L[idx] = d * 0.044194173824159216f;  // 1/sqrt(512)
}
__global__ void nsoft_k(float* __restrict__ L, int NY, int NX) {  // 1 thread / row
  int y = blockIdx.x * 256 + threadIdx.x;
  if (y >= NY) return;
  float* row = L + (size_t)y * NX;
  float m = row[0];
  for (int x = 1; x < NX; x++) m = fmaxf(m, row[x]);
  float s = 0.f;
  for (int x = 0; x < NX; x++) { float p = expf(row[x] - m); row[x] = p; s += p; }
  const float inv = 1.f / s;
  for (int x = 0; x < NX; x++) row[x] *= inv;
}
__global__ void nav_k(const float* __restrict__ P, const float* __restrict__ V,
                      float* __restrict__ O, int NY, int NX) {
  int idx = blockIdx.x * 256 + threadIdx.x;
  if (idx >= NY * 512) return;
  int y = idx >> 9, dd = idx & 511;
  const float* pr = P + (size_t)y * NX;
  float o = 0.f;
  for (int x = 0; x < NX; x++) o += pr[x] * V[(size_t)x * 512 + dd];
  O[idx] = o;
}

// ------------------------------------------------------ naive argmax (pred)
__global__ void nargmax_k(const float* __restrict__ V, const float* __restrict__ text,
                          const float* __restrict__ tnorm, int* __restrict__ pred) {
  int r = blockIdx.x * 256 + threadIdx.x;
  if (r >= TT) return;
  const float* vr = V + (size_t)r * 512;
  float best = -1e30f; int bc = 0;
  for (int c = 0; c < 32; c++) {
    float dot = 0.f;
    for (int dd = 0; dd < 512; dd++) dot += vr[dd] * text[(size_t)c * 512 + dd];
    dot /= tnorm[c];
    if (dot > best) { best = dot; bc = c; }
  }
  pred[r] = bc;
}

// ------------------------------------- sequential segmentation (single thread)
__global__ void nseg_k(const int* __restrict__ pred, int* __restrict__ segid,
                       int* __restrict__ starts, int* __restrict__ centers,
                       int* __restrict__ cnts) {
  if (blockIdx.x != 0 || threadIdx.x != 0) return;
  int sid = 0;
  starts[0] = 0;
  for (int t = 0; t < TT; t++) {
    if (t > 0 && pred[t] != pred[t - 1]) { sid++; starts[sid] = t; }
    segid[t] = sid;
  }
  const int Sd = sid + 1;
  for (int s = 0; s < TT; s++) {
    if (s < Sd) {
      int e = (s == Sd - 1) ? (TT - 1) : (starts[s + 1] - 1);
      centers[s] = (starts[s] + e) >> 1;
      cnts[s] = e - starts[s] + 1;
    } else { starts[s] = 0; cnts[s] = 1; centers[s] = 0; }
  }
}

// ---------------------------------------------------------- segment mean pool
__global__ void segmean_k(const float* __restrict__ ff, const int* __restrict__ starts,
                          const int* __restrict__ cnts, float* __restrict__ segmean, int S) {
  int idx = blockIdx.x * 256 + threadIdx.x;
  if (idx >= S * 512) return;
  int s = idx >> 9, dd = idx & 511;
  int st = starts[s], n = cnts[s];
  st = st < 0 ? 0 : (st > TT - 1 ? TT - 1 : st);
  n = n < 1 ? 1 : n;
  if (st + n > TT) n = TT - st;
  float a = 0.f;
  for (int t = st; t < st + n; t++) a += ff[(size_t)t * 512 + dd];
  segmean[idx] = a / (float)n;
}

// ------------------- multi-block bidirectional seg GRU (H=256), LDS weights
// 8 blocks: dir = blk>>2, part = blk&3 owns h-indices [part*64, part*64+64).
// Per-step device-scope counter barrier among the 4 blocks of a direction.
__launch_bounds__(192)
__global__ void gru_seg_mb_k(const float* __restrict__ gi_f, const float* __restrict__ gi_b,
                             const float* __restrict__ Whh_f, const float* __restrict__ bhh_f,
                             const float* __restrict__ Whh_b, const float* __restrict__ bhh_b,
                             float* __restrict__ hf, float* __restrict__ hb, int S,
                             int* __restrict__ cnt_f, int* __restrict__ cnt_b) {
  const int dir = blockIdx.x >> 2;
  const int part = blockIdx.x & 3;
  const float* gi = dir ? gi_b : gi_f;
  const float* Whh = dir ? Whh_b : Whh_f;
  const float* bhh = dir ? bhh_b : bhh_f;
  float* ho = dir ? hb : hf;
  int* cnt = dir ? cnt_b : cnt_f;
  const int tid = threadIdx.x;        // 0..191 : one gate per thread
  const int h0 = part * 64;
  const int grp = tid >> 6;           // 0=r 1=z 2=n
  const int jj = tid & 63;
  const int j = grp * 256 + h0 + jj;  // global gate index
  __shared__ unsigned wlds[128 * 192];   // [i2][g] fp16-pairs, bank-free (192%32==0)
  __shared__ unsigned hpk[128];
  __shared__ float hcur[256];
  __shared__ float rbuf[64], zbuf[64], gnbuf[64];
  for (int e = tid; e < 128 * 192; e += 192) {
    const int i2 = e / 192, g = e - i2 * 192;
    const int gg = (g >> 6) * 256 + h0 + (g & 63);
    wlds[e] = packh(Whh[(size_t)(2 * i2) * 768 + gg], Whh[(size_t)(2 * i2 + 1) * 768 + gg]);
  }
  for (int e = tid; e < 128; e += 192) hpk[e] = 0u;
  for (int e = tid; e < 256; e += 192) hcur[e] = 0.f;
  const float bj = bhh[j];
  __syncthreads();
  for (int step = 0; step < S; step++) {
    const int s = dir ? (S - 1 - step) : step;
    float a0 = 0.f, a1 = 0.f;
#pragma unroll 16
    for (int i2 = 0; i2 < 128; i2 += 2) {
      const float2 hv0 = uph(hpk[i2]);
      const float2 hv1 = uph(hpk[i2 + 1]);
      const float2 w0 = uph(wlds[i2 * 192 + tid]);
      const float2 w1 = uph(wlds[(i2 + 1) * 192 + tid]);
      a0 += hv0.x * w0.x + hv0.y * w0.y;
      a1 += hv1.x * w1.x + hv1.y * w1.y;
    }
    const float gh = bj + a0 + a1;
    if (grp == 0)      rbuf[jj] = sigf(gi[(size_t)s * 768 + j] + gh);
    else if (grp == 1) zbuf[jj] = sigf(gi[(size_t)s * 768 + j] + gh);
    else               gnbuf[jj] = gh;   // n-gate: keep gh, gi added at update
    __syncthreads();
    if (tid < 64) {
      const float ginv = gi[(size_t)s * 768 + 512 + h0 + tid];
      const float nval = tanhf(ginv + rbuf[tid] * gnbuf[tid]);
      const float hn = (1.f - zbuf[tid]) * nval + zbuf[tid] * hcur[h0 + tid];
      __hip_atomic_store(&ho[(size_t)s * 256 + h0 + tid], hn,
                         __ATOMIC_RELEASE, __HIP_MEMORY_SCOPE_AGENT);
    }
    __syncthreads();
    if (tid == 0) {
      __hip_atomic_fetch_add(cnt + step, 1, __ATOMIC_ACQ_REL, __HIP_MEMORY_SCOPE_AGENT);
      unsigned guard = 0;
      while (__hip_atomic_load(cnt + step, __ATOMIC_ACQUIRE, __HIP_MEMORY_SCOPE_AGENT) < 4 &&
             ++guard < GUARD_MAX) {}
    }
    __syncthreads();
    for (int e = tid; e < 256; e += 192)
      hcur[e] = __hip_atomic_load(&ho[(size_t)s * 256 + e],
                                  __ATOMIC_ACQUIRE, __HIP_MEMORY_SCOPE_AGENT);
    __syncthreads();
    for (int e = tid; e < 128; e += 192) hpk[e] = packh(hcur[2 * e], hcur[2 * e + 1]);
    __syncthreads();
  }
}

// ------------------------- multi-block action GRU (H=512), LDS weights
// 16 blocks, block b owns h-indices [b*32, b*32+32).
__launch_bounds__(128)
__global__ void gru_act_mb_k(const float* __restrict__ gi, const float* __restrict__ Whh,
                             const float* __restrict__ bhh, float* __restrict__ hout,
                             int steps, int* __restrict__ cnt) {
  const int part = blockIdx.x;        // 0..15
  const int tid = threadIdx.x;        // 0..127 (96 matvec-active)
  const int h0 = part * 32;
  const int grp = tid >> 5;           // 0..3
  const int jj = tid & 31;
  const bool act = (tid < 96);
  const int j = act ? (grp * 512 + h0 + jj) : 0;
  __shared__ unsigned wlds[256 * 96];    // [i2][g] fp16-pairs, bank-free (96%32==0)
  __shared__ unsigned hpk[256];
  __shared__ float hcur[512];
  __shared__ float rbuf[32], zbuf[32], gnbuf[32];
  for (int e = tid; e < 256 * 96; e += 128) {
    const int i2 = e / 96, g = e - i2 * 96;
    const int gg = (g >> 5) * 512 + h0 + (g & 31);
    wlds[e] = packh(Whh[(size_t)(2 * i2) * 1536 + gg], Whh[(size_t)(2 * i2 + 1) * 1536 + gg]);
  }
  for (int e = tid; e < 256; e += 128) hpk[e] = 0u;
  for (int e = tid; e < 512; e += 128) hcur[e] = 0.f;
  const float bj = act ? bhh[j] : 0.f;
  __syncthreads();
  for (int step = 0; step < steps; step++) {
    if (act) {
      float a0 = 0.f, a1 = 0.f;
#pragma unroll 16
      for (int i2 = 0; i2 < 256; i2 += 2) {
        const float2 hv0 = uph(hpk[i2]);
        const float2 hv1 = uph(hpk[i2 + 1]);
        const float2 w0 = uph(wlds[i2 * 96 + tid]);
        const float2 w1 = uph(wlds[(i2 + 1) * 96 + tid]);
        a0 += hv0.x * w0.x + hv0.y * w0.y;
        a1 += hv1.x * w1.x + hv1.y * w1.y;
      }
      const float gh = bj + a0 + a1;
      if (grp == 0)      rbuf[jj] = sigf(gi[(size_t)step * 1536 + j] + gh);
      else if (grp == 1) zbuf[jj] = sigf(gi[(size_t)step * 1536 + j] + gh);
      else               gnbuf[jj] = gh;
    }
    __syncthreads();
    if (tid < 32) {
      const float ginv = gi[(size_t)step * 1536 + 1024 + h0 + tid];
      const float nval = tanhf(ginv + rbuf[tid] * gnbuf[tid]);
      const float hn = (1.f - zbuf[tid]) * nval + zbuf[tid] * hcur[h0 + tid];
      __hip_atomic_store(&hout[(size_t)step * 512 + h0 + tid], hn,
                         __ATOMIC_RELEASE, __HIP_MEMORY_SCOPE_AGENT);
    }
    __syncthreads();
    if (tid == 0) {
      __hip_atomic_fetch_add(cnt + step, 1, __ATOMIC_ACQ_REL, __HIP_MEMORY_SCOPE_AGENT);
      unsigned guard = 0;
      while (__hip_atomic_load(cnt + step, __ATOMIC_ACQUIRE, __HIP_MEMORY_SCOPE_AGENT) < 16 &&
             ++guard < GUARD_MAX) {}
    }
    __syncthreads();
    for (int e = tid; e < 512; e += 128)
      hcur[e] = __hip_atomic_load(&hout[(size_t)step * 512 + e],
                                  __ATOMIC_ACQUIRE, __HIP_MEMORY_SCOPE_AGENT);
    __syncthreads();
    for (int e = tid; e < 256; e += 128) hpk[e] = packh(hcur[2 * e], hcur[2 * e + 1]);
    __syncthreads();
  }
}

// ------------------------------------------------------------ tiled GEMM
// C[M,N] = A[M,K] @ B[K,N] + bias   (M,N multiples of 64 ONLY)
__launch_bounds__(256)
__global__ void gemm_k(const float* __restrict__ A, const float* __restrict__ B,
                       const float* __restrict__ bias, float* __restrict__ C,
                       int M, int N, int K) {
  __shared__ float As[16][64];
  __shared__ float Bs[16][64];
  const int tid = threadIdx.x;
  const int n0 = blockIdx.x * 64, m0 = blockIdx.y * 64;
  const int tx = tid & 15, ty = tid >> 4;
  const int am = tid >> 2, ak = (tid & 3) << 2;
  const int bk = tid >> 4, bn = (tid & 15) << 2;
  float acc[4][4] = {};
  for (int k0 = 0; k0 < K; k0 += 16) {
    const float4 av = *reinterpret_cast<const float4*>(A + (size_t)(m0 + am) * K + k0 + ak);
    As[ak + 0][am] = av.x; As[ak + 1][am] = av.y; As[ak + 2][am] = av.z; As[ak + 3][am] = av.w;
    const float4 bv = *reinterpret_cast<const float4*>(B + (size_t)(k0 + bk) * N + n0 + bn);
    Bs[bk][bn + 0] = bv.x; Bs[bk][bn + 1] = bv.y; Bs[bk][bn + 2] = bv.z; Bs[bk][bn + 3] = bv.w;
    __syncthreads();
#pragma unroll
    for (int i = 0; i < 16; i++) {
      const float4 a4 = *reinterpret_cast<const float4*>(&As[i][ty * 4]);
      const float4 b4 = *reinterpret_cast<const float4*>(&Bs[i][tx * 4]);
      const float aa[4] = {a4.x, a4.y, a4.z, a4.w};
      const float bb[4] = {b4.x, b4.y, b4.z, b4.w};
#pragma unroll
      for (int x = 0; x < 4; x++)
#pragma unroll
        for (int y = 0; y < 4; y++) acc[x][y] += aa[x] * bb[y];
    }
    __syncthreads();
  }
#pragma unroll
  for (int x = 0; x < 4; x++) {
    const int m = m0 + ty * 4 + x;
#pragma unroll
    for (int y = 0; y < 4; y++) {
      const int n = n0 + tx * 4 + y;
      float v = acc[x][y];
      if (bias) v += bias[n];
      C[(size_t)m * N + n] = v;
    }
  }
}

// ---------------------------- ff2 = relu([seg2[seg_id[t]], ff[t]] @ Wsf + bsf)
// writes TRANSPOSED (D, T) for the TCN.  K=1024.
__launch_bounds__(256)
__global__ void ff2_k(const float* __restrict__ seg2, const float* __restrict__ ff,
                      const int* __restrict__ segid, const float* __restrict__ Wsf,
                      const float* __restrict__ bsf, float* __restrict__ Y, int S) {
  __shared__ float As[16][64];  // [k][m]  m = frame
  __shared__ float Bs[16][64];  // [k][n]  n = out dim
  const int tid = threadIdx.x;
  const int m0 = blockIdx.x * 64;  // frames
  const int n0 = blockIdx.y * 64;  // dims
  const int tx = tid & 15, ty = tid >> 4;
  const int am = tid >> 2, ak = (tid & 3) << 2;
  const int bk = tid >> 4, bn = (tid & 15) << 2;
  const int t = m0 + am;
  int sid = segid[t];
  sid = sid < 0 ? 0 : (sid >= S ? S - 1 : sid);
  float acc[4][4] = {};  // [n][m]
  for (int k0 = 0; k0 < 1024; k0 += 16) {
    const float* src = (k0 + ak < 512) ? (seg2 + (size_t)sid * 512 + k0 + ak)
                                       : (ff + (size_t)t * 512 + (k0 + ak - 512));
    const float4 av = *reinterpret_cast<const float4*>(src);
    As[ak + 0][am] = av.x; As[ak + 1][am] = av.y; As[ak + 2][am] = av.z; As[ak + 3][am] = av.w;
    const float4 bv = *reinterpret_cast<const float4*>(Wsf + (size_t)(k0 + bk) * 512 + n0 + bn);
    Bs[bk][bn + 0] = bv.x; Bs[bk][bn + 1] = bv.y; Bs[bk][bn + 2] = bv.z; Bs[bk][bn + 3] = bv.w;
    __syncthreads();
#pragma unroll
    for (int i = 0; i < 16; i++) {
      const float4 a4 = *reinterpret_cast<const float4*>(&As[i][tx * 4]);
      const float4 b4 = *reinterpret_cast<const float4*>(&Bs[i][ty * 4]);
      const float aa[4] = {a4.x, a4.y, a4.z, a4.w};
      const float bb[4] = {b4.x, b4.y, b4.z, b4.w};
#pragma unroll
      for (int yy = 0; yy < 4; yy++)
#pragma unroll
        for (int xx = 0; xx < 4; xx++) acc[yy][xx] += bb[yy] * aa[xx];
    }
    __syncthreads();
  }
#pragma unroll
  for (int yy = 0; yy < 4; yy++) {
    const int n = n0 + ty * 4 + yy;
    const float bb = bsf[n];
    float4 o;
    o.x = fmaxf(acc[yy][0] + bb, 0.f);
    o.y = fmaxf(acc[yy][1] + bb, 0.f);
    o.z = fmaxf(acc[yy][2] + bb, 0.f);
    o.w = fmaxf(acc[yy][3] + bb, 0.f);
    *reinterpret_cast<float4*>(Y + (size_t)n * TT + m0 + tx * 4) = o;
  }
}

// ------------------------------------------------------------------- TCN conv
// X,Y: (512,T).  NTAPS==1: W[o][i]; NTAPS==3: W[o][i][3]; 'SAME', dilation d<=32.
template<int NTAPS, int RELU, int RES>
__launch_bounds__(256)
__global__ void conv_k(const float* __restrict__ X, const float* __restrict__ W,
                       const float* __restrict__ bias, const float* __restrict__ Res,
                       float* __restrict__ Y, int dil) {
  __shared__ float Xs[16][128];
  __shared__ float Ws[NTAPS][16][64];
  const int t0 = blockIdx.x * 64, c0 = blockIdx.y * 64;
  const int d = (NTAPS == 3) ? dil : 0;
  const int width = 64 + 2 * d;
  const int tid = threadIdx.x, tx = tid & 15, ty = tid >> 4;
  const int wc = tid >> 2, wi0 = (tid & 3) << 2;
  float acc[4][4] = {};  // [c][t]
  for (int k0 = 0; k0 < 512; k0 += 16) {
    for (int e = tid; e < 16 * width; e += 256) {
      const int ttl = e % width, ii = e / width;
      const int gt = t0 - d + ttl;
      Xs[ii][ttl] = (gt >= 0 && gt < TT) ? X[(size_t)(k0 + ii) * TT + gt] : 0.f;
    }
    if (NTAPS == 1) {
      const float4 wv = *reinterpret_cast<const float4*>(W + (size_t)(c0 + wc) * 512 + k0 + wi0);
      Ws[0][wi0 + 0][wc] = wv.x; Ws[0][wi0 + 1][wc] = wv.y;
      Ws[0][wi0 + 2][wc] = wv.z; Ws[0][wi0 + 3][wc] = wv.w;
    } else {
#pragma unroll
      for (int j = 0; j < 4; j++)
#pragma unroll
        for (int tap = 0; tap < NTAPS; tap++)
          Ws[tap][wi0 + j][wc] = W[((size_t)(c0 + wc) * 512 + k0 + wi0 + j) * 3 + tap];
    }
    __syncthreads();
#pragma unroll
    for (int i = 0; i < 16; i++) {
#pragma unroll
      for (int tap = 0; tap < NTAPS; tap++) {
        const float4 w4 = *reinterpret_cast<const float4*>(&Ws[tap][i][ty * 4]);
        const float wv4[4] = {w4.x, w4.y, w4.z, w4.w};
        const int xb = tx * 4 + tap * d;
        float xv[4];
        xv[0] = Xs[i][xb + 0]; xv[1] = Xs[i][xb + 1];
        xv[2] = Xs[i][xb + 2]; xv[3] = Xs[i][xb + 3];
#pragma unroll
        for (int a = 0; a < 4; a++)
#pragma unroll
          for (int b = 0; b < 4; b++) acc[a][b] += wv4[a] * xv[b];
      }
    }
    __syncthreads();
  }
#pragma unroll
  for (int a = 0; a < 4; a++) {
    const int c = c0 + ty * 4 + a;
    const float bb = bias[c];
    float vals[4];
#pragma unroll
    for (int b = 0; b < 4; b++) {
      float v = acc[a][b] + bb;
      if (RES) v += Res[(size_t)c * TT + t0 + tx * 4 + b];
      if (RELU) v = fmaxf(v, 0.f);
      vals[b] = v;
    }
    *reinterpret_cast<float4*>(Y + (size_t)c * TT + t0 + tx * 4) =
        make_float4(vals[0], vals[1], vals[2], vals[3]);
  }
}

// -------------------- tiled transpose (512,T) -> out (T,512) + f32 copy (T,512)
__launch_bounds__(256)
__global__ void temit_k(const float* __restrict__ Xin, float* __restrict__ outp,
                        float* __restrict__ Aout) {
  __shared__ float tile[32][33];
  const int t0 = blockIdx.x * 32, d0 = blockIdx.y * 32;
  const int lx = threadIdx.x & 31, ly = threadIdx.x >> 5;
#pragma unroll
  for (int r = 0; r < 4; r++)
    tile[ly + 8 * r][lx] = Xin[(size_t)(d0 + ly + 8 * r) * TT + t0 + lx];
  __syncthreads();
#pragma unroll
  for (int r = 0; r < 4; r++) {
    const int t = t0 + ly + 8 * r, dd = d0 + lx;
    const float v = tile[lx][ly + 8 * r];
    outp[(size_t)t * 512 + dd] = v;
    Aout[(size_t)t * 512 + dd] = v;
  }
}

// ---------------------------------------------------------------- cosine sim
__global__ void nsim_k(const float* __restrict__ V, const float* __restrict__ text,
                       const float* __restrict__ tnorm, float* __restrict__ out, int R) {
  int idx = blockIdx.x * 256 + threadIdx.x;  // r*32 + c
  if (idx >= R * 32) return;
  int r = idx >> 5, c = idx & 31;
  const float* vr = V + (size_t)r * 512;
  float ss = 0.f, dot = 0.f;
  for (int dd = 0; dd < 512; dd++) {
    float v = vr[dd];
    ss += v * v;
    dot += v * text[(size_t)c * 512 + dd];
  }
  out[idx] = dot / (sqrtf(ss) * tnorm[c]);
}

// ======================================================================= host
extern "C" void kernel_launch(void* const* d_in, const int* in_sizes, int n_in,
                              void* d_out, int out_size, void* d_ws, size_t ws_size,
                              hipStream_t stream) {
  const float* in_ff   = (const float*)d_in[0];
  const float* in_act  = (const float*)d_in[1];
  const float* in_fpos = (const float*)d_in[2];
  const float* in_apos = (const float*)d_in[3];
  const float* in_text = (const float*)d_in[4];
  const float* Wf2c = (const float*)d_in[5];  const float* bf2c = (const float*)d_in[6];
  const float* Wa2c = (const float*)d_in[7];  const float* ba2c = (const float*)d_in[8];
  const float* Ws2c = (const float*)d_in[9];  const float* bs2c = (const float*)d_in[10];
  const float* Wih_f = (const float*)d_in[11]; const float* Whh_f = (const float*)d_in[12];
  const float* bih_f = (const float*)d_in[13]; const float* bhh_f = (const float*)d_in[14];
  const float* Wih_b = (const float*)d_in[15]; const float* Whh_b = (const float*)d_in[16];
  const float* bih_b = (const float*)d_in[17]; const float* bhh_b = (const float*)d_in[18];
  const float* Wcomb = (const float*)d_in[19]; const float* bcomb = (const float*)d_in[20];
  const float* f2a_Wq = (const float*)d_in[21]; const float* f2a_Wk = (const float*)d_in[22];
  const float* f2a_Wv = (const float*)d_in[23]; const float* f2a_Wo = (const float*)d_in[24];
  const float* f2a_bo = (const float*)d_in[25];
  const float* ag_Wih = (const float*)d_in[26]; const float* ag_Whh = (const float*)d_in[27];
  const float* ag_bih = (const float*)d_in[28]; const float* ag_bhh = (const float*)d_in[29];
  const float* a2f_Wq = (const float*)d_in[30]; const float* a2f_Wk = (const float*)d_in[31];
  const float* a2f_Wv = (const float*)d_in[32]; const float* a2f_Wo = (const float*)d_in[33];
  const float* a2f_bo = (const float*)d_in[34];
  const float* Wsf = (const float*)d_in[35]; const float* bsf = (const float*)d_in[36];
  const float* tcn_inW = (const float*)d_in[37]; const float* tcn_inb = (const float*)d_in[38];
  const float* tcn_dW = (const float*)d_in[39]; const float* tcn_db = (const float*)d_in[40];
  const float* tcn_pW = (const float*)d_in[41]; const float* tcn_pb = (const float*)d_in[42];
  const float* tcn_outW = (const float*)d_in[43]; const float* tcn_outb = (const float*)d_in[44];

  int S = (out_size - (TT * DD + MM * DD + TT * CC + MM * CC)) / CC;
  if (S < 1) S = 1;
  if (S > TT) S = TT;

  // ---------------- workspace layout
  char* ws = (char*)d_ws;
  size_t off = 0;
  auto alloc = [&](size_t b) -> char* { char* p = ws + off; off += (b + 255) & ~(size_t)255; return p; };
  const size_t BTD = (size_t)TT * DD * 4;
  float* bufA = (float*)alloc(BTD);
  float* bufB = (float*)alloc(BTD);
  int* pred    = (int*)alloc((size_t)TT * 4);
  int* segid   = (int*)alloc((size_t)TT * 4);
  int* starts  = (int*)alloc((size_t)TT * 4);
  int* centers = (int*)alloc((size_t)TT * 4);
  int* cnts    = (int*)alloc((size_t)TT * 4);
  int* cntF    = (int*)alloc((size_t)TT * 4);   // seg GRU fwd barrier counters
  int* cntB    = (int*)alloc((size_t)TT * 4);   // seg GRU bwd barrier counters
  int* cntA    = (int*)alloc((size_t)256 * 4);  // action GRU barrier counters
  float* tnorm = (float*)alloc(32 * 4);
  float* segmean = (float*)alloc((size_t)S * 512 * 4);
  float* gif  = (float*)alloc((size_t)S * 768 * 4);
  float* gib  = (float*)alloc((size_t)S * 768 * 4);
  float* hfb  = (float*)alloc((size_t)S * 256 * 4);
  float* hbb  = (float*)alloc((size_t)S * 256 * 4);
  float* acmb = (float*)alloc((size_t)S * 512 * 4);
  float* segc = (float*)alloc((size_t)S * 512 * 4);
  float* segpos = (float*)alloc((size_t)S * 512 * 4);
  float* kin  = (float*)alloc((size_t)S * 512 * 4);
  float* kf2a = (float*)alloc((size_t)S * 512 * 4);
  float* vf2a = (float*)alloc((size_t)S * 512 * 4);
  float* q2   = (float*)alloc((size_t)S * 512 * 4);
  float* att2 = (float*)alloc((size_t)S * 512 * 4);
  float* seg2 = (float*)alloc((size_t)S * 512 * 4);
  float* vseg = (float*)alloc((size_t)S * 512 * 4);
  float* pbuf = (float*)alloc((size_t)64 * S * 4);
  float* qin  = (float*)alloc((size_t)64 * 512 * 4);
  float* qf2a = (float*)alloc((size_t)64 * 512 * 4);
  float* att1 = (float*)alloc((size_t)64 * 512 * 4);
  float* af0  = (float*)alloc((size_t)64 * 512 * 4);
  float* aggi = (float*)alloc((size_t)64 * 1536 * 4);
  float* afg  = (float*)alloc((size_t)64 * 512 * 4);
  float* k2in = (float*)alloc((size_t)64 * 512 * 4);
  float* k2   = (float*)alloc((size_t)64 * 512 * 4);
  float* v2   = (float*)alloc((size_t)64 * 512 * 4);
  float* vaf  = (float*)alloc((size_t)64 * 512 * 4);
  (void)ws_size; (void)in_sizes; (void)n_in;

  float* outp = (float*)d_out;
  float* out_ff   = outp;
  float* out_af   = outp + (size_t)TT * DD;
  float* out_fsim = out_af + (size_t)MM * DD;
  float* out_asim = out_fsim + (size_t)TT * CC;
  float* out_ssim = out_asim + (size_t)MM * CC;

  auto GR = [](long n) { return (unsigned)((n + 255) / 256); };

  // zero ws (incl. barrier counters -> 0, mandatory every launch)
  zero_k<<<2048, 256, 0, stream>>>((float*)d_ws, (long)(off / 4));

  tnorm_k<<<1, 256, 0, stream>>>(in_text, tnorm);

  // segmentation (tiled GEMM for the T-sized projection)
  gemm_k<<<dim3(8, 128), 256, 0, stream>>>(in_ff, Wf2c, bf2c, bufA, TT, 512, 512);
  nargmax_k<<<GR(TT), 256, 0, stream>>>(bufA, in_text, tnorm, pred);
  nseg_k<<<1, 64, 0, stream>>>(pred, segid, starts, centers, cnts);
  segmean_k<<<GR((long)S * 512), 256, 0, stream>>>(in_ff, starts, cnts, segmean, S);

  // seg BiGRU (multi-block LDS-resident scan)
  ngemm_k<<<GR((long)S * 768), 256, 0, stream>>>(segmean, Wih_f, bih_f, gif, S, 768, 512);
  ngemm_k<<<GR((long)S * 768), 256, 0, stream>>>(segmean, Wih_b, bih_b, gib, S, 768, 512);
  gru_seg_mb_k<<<8, 192, 0, stream>>>(gif, gib, Whh_f, bhh_f, Whh_b, bhh_b,
                                      hfb, hbb, S, cntF, cntB);
  acomb_k<<<GR((long)S * 512), 256, 0, stream>>>(hfb, hbb, acmb, S * 512);
  ngemm_k<<<GR((long)S * 512), 256, 0, stream>>>(acmb, Wcomb, bcomb, segc, S, 512, 512);
  gatherpos_k<<<GR((long)S * 512), 256, 0, stream>>>(in_fpos, centers, segpos, S * 512);

  // f2a attention (actions query segments)
  addff_k<<<GR(64 * 512), 256, 0, stream>>>(in_act, in_apos, qin, 64 * 512);
  addff_k<<<GR((long)S * 512), 256, 0, stream>>>(segc, segpos, kin, S * 512);
  ngemm_k<<<GR(64 * 512), 256, 0, stream>>>(qin, f2a_Wq, nullptr, qf2a, 64, 512, 512);
  ngemm_k<<<GR((long)S * 512), 256, 0, stream>>>(kin, f2a_Wk, nullptr, kf2a, S, 512, 512);
  ngemm_k<<<GR((long)S * 512), 256, 0, stream>>>(segc, f2a_Wv, nullptr, vf2a, S, 512, 512);
  nlogit_k<<<GR((long)64 * S), 256, 0, stream>>>(qf2a, kf2a, pbuf, 64, S);
  nsoft_k<<<1, 256, 0, stream>>>(pbuf, 64, S);
  nav_k<<<GR(64 * 512), 256, 0, stream>>>(pbuf, vf2a, att1, 64, S);
  ngemm_k<<<GR(64 * 512), 256, 0, stream>>>(att1, f2a_Wo, f2a_bo, af0, 64, 512, 512);

  // action GRU (multi-block LDS-resident scan)
  ngemm_k<<<GR(64 * 1536), 256, 0, stream>>>(af0, ag_Wih, ag_bih, aggi, 64, 1536, 512);
  gru_act_mb_k<<<16, 128, 0, stream>>>(aggi, ag_Whh, ag_bhh, afg, MM, cntA);
  copy_k<<<GR(64 * 512), 256, 0, stream>>>(afg, out_af, 64 * 512);

  // a2f attention (segments query actions)
  addff_k<<<GR(64 * 512), 256, 0, stream>>>(afg, in_apos, k2in, 64 * 512);
  ngemm_k<<<GR((long)S * 512), 256, 0, stream>>>(kin, a2f_Wq, nullptr, q2, S, 512, 512);
  ngemm_k<<<GR(64 * 512), 256, 0, stream>>>(k2in, a2f_Wk, nullptr, k2, 64, 512, 512);
  ngemm_k<<<GR(64 * 512), 256, 0, stream>>>(afg, a2f_Wv, nullptr, v2, 64, 512, 512);
  nlogit_k<<<GR((long)S * 64), 256, 0, stream>>>(q2, k2, pbuf, S, 64);
  nsoft_k<<<GR(S), 256, 0, stream>>>(pbuf, S, 64);
  nav_k<<<GR((long)S * 512), 256, 0, stream>>>(pbuf, v2, att2, S, 64);
  ngemm_k<<<GR((long)S * 512), 256, 0, stream>>>(att2, a2f_Wo, a2f_bo, seg2, S, 512, 512);

  // frame fusion + TCN (tiled), ping-pong bufA <-> bufB as (D,T)
  ff2_k<<<dim3(128, 8), 256, 0, stream>>>(seg2, in_ff, segid, Wsf, bsf, bufA, S);
  conv_k<1, 0, 0><<<dim3(128, 8), 256, 0, stream>>>(bufA, tcn_inW, tcn_inb, nullptr, bufB, 1);
  for (int l = 0; l < 6; l++) {
    conv_k<3, 1, 0><<<dim3(128, 8), 256, 0, stream>>>(
        bufB, tcn_dW + (size_t)l * 512 * 512 * 3, tcn_db + (size_t)l * 512, nullptr, bufA, 1 << l);
    conv_k<1, 0, 1><<<dim3(128, 8), 256, 0, stream>>>(
        bufA, tcn_pW + (size_t)l * 512 * 512, tcn_pb + (size_t)l * 512, bufB, bufB, 1);
  }
  conv_k<1, 0, 0><<<dim3(128, 8), 256, 0, stream>>>(bufB, tcn_outW, tcn_outb, nullptr, bufA, 1);
  temit_k<<<dim3(256, 16), 256, 0, stream>>>(bufA, out_ff, bufB);

  // similarity heads (tiled GEMM for the T-sized projection)
  gemm_k<<<dim3(8, 128), 256, 0, stream>>>(bufB, Wf2c, bf2c, bufA, TT, 512, 512);
  nsim_k<<<GR((long)TT * 32), 256, 0, stream>>>(bufA, in_text, tnorm, out_fsim, TT);
  ngemm_k<<<GR(64 * 512), 256, 0, stream>>>(afg, Wa2c, ba2c, vaf, 64, 512, 512);
  nsim_k<<<GR(64 * 32), 256, 0, stream>>>(vaf, in_text, tnorm, out_asim, 64);
  ngemm_k<<<GR((long)S * 512), 256, 0, stream>>>(seg2, Ws2c, bs2c, vseg, S, 512, 512);
  nsim_k<<<GR((long)S * 32), 256, 0, stream>>>(vseg, in_text, tnorm, out_ssim, S);
}

// Round 9
// 8312.186 us; speedup vs baseline: 1.9814x; 1.1529x over previous
//
#include <hip/hip_runtime.h>
#include <cstdint>
#include <cstddef>

__device__ __forceinline__ float sigf(float x) { return 1.f / (1.f + expf(-x)); }

// fp16 pack/unpack helpers (weights-only precision reduction)
__device__ __forceinline__ unsigned packh(float a, float b) {
  union { unsigned u; _Float16 h[2]; } cv;
  cv.h[0] = (_Float16)a; cv.h[1] = (_Float16)b; return cv.u;
}
__device__ __forceinline__ float2 uph(unsigned u) {
  union { unsigned uu; _Float16 h[2]; } cv; cv.uu = u;
  return make_float2((float)cv.h[0], (float)cv.h[1]);
}

static constexpr int TT = 8192;   // frames
static constexpr int MM = 64;     // actions
static constexpr int CC = 32;     // classes
static constexpr int DD = 512;    // model dim
static constexpr unsigned GUARD_MAX = 1u << 30;
static constexpr int CNT_STRIDE = 16;   // 64B spacing between per-step counters

// ---------------------------------------------------------------- ws zeroing
__global__ void zero_k(float* __restrict__ p, long n) {
  long i = (long)blockIdx.x * 256 + threadIdx.x;
  long stride = (long)gridDim.x * 256;
  for (; i < n; i += stride) p[i] = 0.f;
}

// ---------------------------------------------------------------- elementwise
__global__ void copy_k(const float* __restrict__ a, float* __restrict__ o, int n) {
  int i = blockIdx.x * 256 + threadIdx.x;
  if (i < n) o[i] = a[i];
}
__global__ void addff_k(const float* __restrict__ a, const float* __restrict__ b, float* __restrict__ o, int n) {
  int i = blockIdx.x * 256 + threadIdx.x;
  if (i < n) o[i] = a[i] + b[i];
}
__global__ void acomb_k(const float* __restrict__ hf, const float* __restrict__ hb, float* __restrict__ o, int n) {
  int i = blockIdx.x * 256 + threadIdx.x;
  if (i >= n) return;
  int s = i >> 9, j = i & 511;
  float v = (j < 256) ? hf[(size_t)s * 256 + j] : hb[(size_t)s * 256 + (j - 256)];
  o[i] = fmaxf(v, 0.f);
}
__global__ void gatherpos_k(const float* __restrict__ fpos, const int* __restrict__ centers,
                            float* __restrict__ segpos, int n) {
  int i = blockIdx.x * 256 + threadIdx.x;
  if (i >= n) return;
  int s = i >> 9, dd = i & 511;
  int ct = centers[s];
  ct = ct < 0 ? 0 : (ct > TT - 1 ? TT - 1 : ct);
  segpos[i] = fpos[(size_t)ct * 512 + dd];
}

// ---------------------------------------------------------------- text norms
__global__ void tnorm_k(const float* __restrict__ text, float* __restrict__ tnorm) {
  int c = blockIdx.x * 256 + threadIdx.x;
  if (c >= 32) return;
  float s = 0.f;
  for (int dd = 0; dd < 512; dd++) { float v = text[(size_t)c * 512 + dd]; s += v * v; }
  tnorm[c] = sqrtf(s);
}

// ---------------------------------------------------- naive GEMM (small ops)
__global__ void ngemm_k(const float* __restrict__ A, const float* __restrict__ B,
                        const float* __restrict__ bias, float* __restrict__ C,
                        int M, int N, int K) {
  int idx = blockIdx.x * 256 + threadIdx.x;
  if (idx >= M * N) return;
  int m = idx / N, n = idx - m * N;
  float a = bias ? bias[n] : 0.f;
  const float* Ar = A + (size_t)m * K;
  for (int k = 0; k < K; k++) a += Ar[k] * B[(size_t)k * N + n];
  C[idx] = a;
}

// ---------------------------------------------------- naive attention pieces
__global__ void nlogit_k(const float* __restrict__ Q, const float* __restrict__ Kk,
                         float* __restrict__ L, int NY, int NX) {
  int idx = blockIdx.x * 256 + threadIdx.x;
  if (idx >= NY * NX) return;
  int y = idx / NX, x = idx - y * NX;
  const float* qr = Q + (size_t)y * 512;
  const float* kr = Kk + (size_t)x * 512;
  float d = 0.f;
  for (int k = 0; k < 512; k++) d += qr[k] * kr[k];
  L[idx] = d * 0.044194173824159216f;  // 1/sqrt(512)
}
__global__ void nsoft_k(float* __restrict__ L, int NY, int NX) {  // 1 thread / row
  int y = blockIdx.x * 256 + threadIdx.x;
  if (y >= NY) return;
  float* row = L + (size_t)y * NX;
  float m = row[0];
  for (int x = 1; x < NX; x++) m = fmaxf(m, row[x]);
  float s = 0.f;
  for (int x = 0; x < NX; x++) { float p = expf(row[x] - m); row[x] = p; s += p; }
  const float inv = 1.f / s;
  for (int x = 0; x < NX; x++) row[x] *= inv;
}
__global__ void nav_k(const float* __restrict__ P, const float* __restrict__ V,
                      float* __restrict__ O, int NY, int NX) {
  int idx = blockIdx.x * 256 + threadIdx.x;
  if (idx >= NY * 512) return;
  int y = idx >> 9, dd = idx & 511;
  const float* pr = P + (size_t)y * NX;
  float o = 0.f;
  for (int x = 0; x < NX; x++) o += pr[x] * V[(size_t)x * 512 + dd];
  O[idx] = o;
}

// ------------------------------------------ argmax over classes: block per row
__global__ void argmax_k(const float* __restrict__ V, const float* __restrict__ text,
                         const float* __restrict__ tnorm, int* __restrict__ pred) {
  __shared__ float vs[512];
  __shared__ float dots[32];
  const int r = blockIdx.x, tid = threadIdx.x;
  for (int dd = tid; dd < 512; dd += 256) vs[dd] = V[(size_t)r * 512 + dd];
  __syncthreads();
  if (tid < 32) {
    float dot = 0.f;
    const float* tr = text + (size_t)tid * 512;
    for (int dd = 0; dd < 512; dd++) dot += vs[dd] * tr[dd];
    dots[tid] = dot / tnorm[tid];
  }
  __syncthreads();
  if (tid == 0) {
    int best = 0; float bv = dots[0];
    for (int c = 1; c < 32; c++) if (dots[c] > bv) { bv = dots[c]; best = c; }
    pred[r] = best;
  }
}

// ------------------------------- parallel run-length segmentation (one block)
__global__ void segscan_k(const int* __restrict__ pred, int* __restrict__ segid,
                          int* __restrict__ starts, int* __restrict__ centers,
                          int* __restrict__ cnts) {
  __shared__ int base[256];
  __shared__ int SS;
  const int tid = threadIdx.x;
  int lc = 0;
  unsigned flags = 0;
  int prev = (tid > 0) ? pred[tid * 32 - 1] : 0;
  for (int i = 0; i < 32; i++) {
    const int t = tid * 32 + i;
    const int cur = pred[t];
    const int c = (t > 0) && (cur != prev);
    prev = cur;
    flags |= ((unsigned)c) << i;
    lc += c;
  }
  base[tid] = lc;
  __syncthreads();
  if (tid == 0) {
    int run = 0;
    for (int i = 0; i < 256; i++) { const int v = base[i]; base[i] = run; run += v; }
    SS = run + 1;
  }
  __syncthreads();
  int b = base[tid];
  for (int i = 0; i < 32; i++) {
    const int t = tid * 32 + i;
    if ((flags >> i) & 1u) { b++; starts[b] = t; }
    segid[t] = b;
  }
  if (tid == 0) starts[0] = 0;
  __threadfence_block();
  __syncthreads();
  const int S = SS;
  for (int s = tid; s < TT; s += 256) {
    if (s < S) {
      const int e = (s == S - 1) ? (TT - 1) : (starts[s + 1] - 1);
      centers[s] = (starts[s] + e) >> 1;
      cnts[s] = e - starts[s] + 1;
    } else {
      starts[s] = 0; cnts[s] = 1; centers[s] = 0;
    }
  }
}

// ---------------------------------------------------------- segment mean pool
__global__ void segmean_k(const float* __restrict__ ff, const int* __restrict__ starts,
                          const int* __restrict__ cnts, float* __restrict__ segmean, int S) {
  int idx = blockIdx.x * 256 + threadIdx.x;
  if (idx >= S * 512) return;
  int s = idx >> 9, dd = idx & 511;
  int st = starts[s], n = cnts[s];
  st = st < 0 ? 0 : (st > TT - 1 ? TT - 1 : st);
  n = n < 1 ? 1 : n;
  if (st + n > TT) n = TT - st;
  float a = 0.f;
  for (int t = st; t < st + n; t++) a += ff[(size_t)t * 512 + dd];
  segmean[idx] = a / (float)n;
}

// ------------------- multi-block bidirectional seg GRU (H=256), LDS weights
// 8 blocks: dir = blk>>2, part = blk&3 owns h-indices [part*64, part*64+64).
__launch_bounds__(192)
__global__ void gru_seg_mb_k(const float* __restrict__ gi_f, const float* __restrict__ gi_b,
                             const float* __restrict__ Whh_f, const float* __restrict__ bhh_f,
                             const float* __restrict__ Whh_b, const float* __restrict__ bhh_b,
                             float* __restrict__ hf, float* __restrict__ hb, int S,
                             int* __restrict__ cnt_f, int* __restrict__ cnt_b) {
  const int dir = blockIdx.x >> 2;
  const int part = blockIdx.x & 3;
  const float* gi = dir ? gi_b : gi_f;
  const float* Whh = dir ? Whh_b : Whh_f;
  const float* bhh = dir ? bhh_b : bhh_f;
  float* ho = dir ? hb : hf;
  int* cnt = dir ? cnt_b : cnt_f;
  const int tid = threadIdx.x;        // 0..191 : one gate per thread
  const int h0 = part * 64;
  const int grp = tid >> 6;           // 0=r 1=z 2=n
  const int jj = tid & 63;
  const int j = grp * 256 + h0 + jj;  // global gate index
  __shared__ unsigned wlds[128 * 192];   // [i2][g] fp16-pairs
  __shared__ unsigned hpk[128];
  __shared__ float hcur[256];
  __shared__ float rbuf[64], zbuf[64], gnbuf[64];
  for (int e = tid; e < 128 * 192; e += 192) {
    const int i2 = e / 192, g = e - i2 * 192;
    const int gg = (g >> 6) * 256 + h0 + (g & 63);
    wlds[e] = packh(Whh[(size_t)(2 * i2) * 768 + gg], Whh[(size_t)(2 * i2 + 1) * 768 + gg]);
  }
  for (int e = tid; e < 128; e += 192) hpk[e] = 0u;
  for (int e = tid; e < 256; e += 192) hcur[e] = 0.f;
  const float bj = bhh[j];
  __syncthreads();
  for (int step = 0; step < S; step++) {
    const int s = dir ? (S - 1 - step) : step;
    float a0 = 0.f, a1 = 0.f;
#pragma unroll 16
    for (int i2 = 0; i2 < 128; i2 += 2) {
      const float2 hv0 = uph(hpk[i2]);
      const float2 hv1 = uph(hpk[i2 + 1]);
      const float2 w0 = uph(wlds[i2 * 192 + tid]);
      const float2 w1 = uph(wlds[(i2 + 1) * 192 + tid]);
      a0 += hv0.x * w0.x + hv0.y * w0.y;
      a1 += hv1.x * w1.x + hv1.y * w1.y;
    }
    const float gh = bj + a0 + a1;
    if (grp == 0)      rbuf[jj] = sigf(gi[(size_t)s * 768 + j] + gh);
    else if (grp == 1) zbuf[jj] = sigf(gi[(size_t)s * 768 + j] + gh);
    else               gnbuf[jj] = gh;   // n-gate: keep gh, gi added at update
    __syncthreads();
    if (tid < 64) {
      const float ginv = gi[(size_t)s * 768 + 512 + h0 + tid];
      const float nval = tanhf(ginv + rbuf[tid] * gnbuf[tid]);
      const float hn = (1.f - zbuf[tid]) * nval + zbuf[tid] * hcur[h0 + tid];
      __hip_atomic_store(&ho[(size_t)s * 256 + h0 + tid], hn,
                         __ATOMIC_RELAXED, __HIP_MEMORY_SCOPE_AGENT);
    }
    __syncthreads();
    if (tid == 0) {
      // RELEASE RMW publishes our h slice (relaxed stores above are prior in program order)
      __hip_atomic_fetch_add(cnt + step * CNT_STRIDE, 1,
                             __ATOMIC_RELEASE, __HIP_MEMORY_SCOPE_AGENT);
      unsigned guard = 0;
      while (__hip_atomic_load(cnt + step * CNT_STRIDE,
                               __ATOMIC_RELAXED, __HIP_MEMORY_SCOPE_AGENT) < 4 &&
             ++guard < GUARD_MAX) {
        __builtin_amdgcn_s_sleep(8);
      }
      // pairing ACQUIRE: synchronizes-with the other blocks' release RMWs
      (void)__hip_atomic_load(cnt + step * CNT_STRIDE,
                              __ATOMIC_ACQUIRE, __HIP_MEMORY_SCOPE_AGENT);
    }
    __syncthreads();
    for (int e = tid; e < 256; e += 192)
      hcur[e] = __hip_atomic_load(&ho[(size_t)s * 256 + e],
                                  __ATOMIC_RELAXED, __HIP_MEMORY_SCOPE_AGENT);
    __syncthreads();
    for (int e = tid; e < 128; e += 192) hpk[e] = packh(hcur[2 * e], hcur[2 * e + 1]);
    __syncthreads();
  }
}

// ------------------------- multi-block action GRU (H=512), LDS weights
// 16 blocks, block b owns h-indices [b*32, b*32+32).
__launch_bounds__(128)
__global__ void gru_act_mb_k(const float* __restrict__ gi, const float* __restrict__ Whh,
                             const float* __restrict__ bhh, float* __restrict__ hout,
                             int steps, int* __restrict__ cnt) {
  const int part = blockIdx.x;        // 0..15
  const int tid = threadIdx.x;        // 0..127 (96 matvec-active)
  const int h0 = part * 32;
  const int grp = tid >> 5;           // 0..3
  const int jj = tid & 31;
  const bool act = (tid < 96);
  const int j = act ? (grp * 512 + h0 + jj) : 0;
  __shared__ unsigned wlds[256 * 96];    // [i2][g] fp16-pairs
  __shared__ unsigned hpk[256];
  __shared__ float hcur[512];
  __shared__ float rbuf[32], zbuf[32], gnbuf[32];
  for (int e = tid; e < 256 * 96; e += 128) {
    const int i2 = e / 96, g = e - i2 * 96;
    const int gg = (g >> 5) * 512 + h0 + (g & 31);
    wlds[e] = packh(Whh[(size_t)(2 * i2) * 1536 + gg], Whh[(size_t)(2 * i2 + 1) * 1536 + gg]);
  }
  for (int e = tid; e < 256; e += 128) hpk[e] = 0u;
  for (int e = tid; e < 512; e += 128) hcur[e] = 0.f;
  const float bj = act ? bhh[j] : 0.f;
  __syncthreads();
  for (int step = 0; step < steps; step++) {
    if (act) {
      float a0 = 0.f, a1 = 0.f;
#pragma unroll 16
      for (int i2 = 0; i2 < 256; i2 += 2) {
        const float2 hv0 = uph(hpk[i2]);
        const float2 hv1 = uph(hpk[i2 + 1]);
        const float2 w0 = uph(wlds[i2 * 96 + tid]);
        const float2 w1 = uph(wlds[(i2 + 1) * 96 + tid]);
        a0 += hv0.x * w0.x + hv0.y * w0.y;
        a1 += hv1.x * w1.x + hv1.y * w1.y;
      }
      const float gh = bj + a0 + a1;
      if (grp == 0)      rbuf[jj] = sigf(gi[(size_t)step * 1536 + j] + gh);
      else if (grp == 1) zbuf[jj] = sigf(gi[(size_t)step * 1536 + j] + gh);
      else               gnbuf[jj] = gh;
    }
    __syncthreads();
    if (tid < 32) {
      const float ginv = gi[(size_t)step * 1536 + 1024 + h0 + tid];
      const float nval = tanhf(ginv + rbuf[tid] * gnbuf[tid]);
      const float hn = (1.f - zbuf[tid]) * nval + zbuf[tid] * hcur[h0 + tid];
      __hip_atomic_store(&hout[(size_t)step * 512 + h0 + tid], hn,
                         __ATOMIC_RELAXED, __HIP_MEMORY_SCOPE_AGENT);
    }
    __syncthreads();
    if (tid == 0) {
      __hip_atomic_fetch_add(cnt + step * CNT_STRIDE, 1,
                             __ATOMIC_RELEASE, __HIP_MEMORY_SCOPE_AGENT);
      unsigned guard = 0;
      while (__hip_atomic_load(cnt + step * CNT_STRIDE,
                               __ATOMIC_RELAXED, __HIP_MEMORY_SCOPE_AGENT) < 16 &&
             ++guard < GUARD_MAX) {
        __builtin_amdgcn_s_sleep(8);
      }
      (void)__hip_atomic_load(cnt + step * CNT_STRIDE,
                              __ATOMIC_ACQUIRE, __HIP_MEMORY_SCOPE_AGENT);
    }
    __syncthreads();
    for (int e = tid; e < 512; e += 128)
      hcur[e] = __hip_atomic_load(&hout[(size_t)step * 512 + e],
                                  __ATOMIC_RELAXED, __HIP_MEMORY_SCOPE_AGENT);
    __syncthreads();
    for (int e = tid; e < 256; e += 128) hpk[e] = packh(hcur[2 * e], hcur[2 * e + 1]);
    __syncthreads();
  }
}

// ------------------------------------------------------------ tiled GEMM
// C[M,N] = A[M,K] @ B[K,N] + bias   (M,N multiples of 64 ONLY)
__launch_bounds__(256)
__global__ void gemm_k(const float* __restrict__ A, const float* __restrict__ B,
                       const float* __restrict__ bias, float* __restrict__ C,
                       int M, int N, int K) {
  __shared__ float As[16][64];
  __shared__ float Bs[16][64];
  const int tid = threadIdx.x;
  const int n0 = blockIdx.x * 64, m0 = blockIdx.y * 64;
  const int tx = tid & 15, ty = tid >> 4;
  const int am = tid >> 2, ak = (tid & 3) << 2;
  const int bk = tid >> 4, bn = (tid & 15) << 2;
  float acc[4][4] = {};
  for (int k0 = 0; k0 < K; k0 += 16) {
    const float4 av = *reinterpret_cast<const float4*>(A + (size_t)(m0 + am) * K + k0 + ak);
    As[ak + 0][am] = av.x; As[ak + 1][am] = av.y; As[ak + 2][am] = av.z; As[ak + 3][am] = av.w;
    const float4 bv = *reinterpret_cast<const float4*>(B + (size_t)(k0 + bk) * N + n0 + bn);
    Bs[bk][bn + 0] = bv.x; Bs[bk][bn + 1] = bv.y; Bs[bk][bn + 2] = bv.z; Bs[bk][bn + 3] = bv.w;
    __syncthreads();
#pragma unroll
    for (int i = 0; i < 16; i++) {
      const float4 a4 = *reinterpret_cast<const float4*>(&As[i][ty * 4]);
      const float4 b4 = *reinterpret_cast<const float4*>(&Bs[i][tx * 4]);
      const float aa[4] = {a4.x, a4.y, a4.z, a4.w};
      const float bb[4] = {b4.x, b4.y, b4.z, b4.w};
#pragma unroll
      for (int x = 0; x < 4; x++)
#pragma unroll
        for (int y = 0; y < 4; y++) acc[x][y] += aa[x] * bb[y];
    }
    __syncthreads();
  }
#pragma unroll
  for (int x = 0; x < 4; x++) {
    const int m = m0 + ty * 4 + x;
#pragma unroll
    for (int y = 0; y < 4; y++) {
      const int n = n0 + tx * 4 + y;
      float v = acc[x][y];
      if (bias) v += bias[n];
      C[(size_t)m * N + n] = v;
    }
  }
}

// ---------------------------- ff2 = relu([seg2[seg_id[t]], ff[t]] @ Wsf + bsf)
// writes TRANSPOSED (D, T) for the TCN.  K=1024.
__launch_bounds__(256)
__global__ void ff2_k(const float* __restrict__ seg2, const float* __restrict__ ff,
                      const int* __restrict__ segid, const float* __restrict__ Wsf,
                      const float* __restrict__ bsf, float* __restrict__ Y, int S) {
  __shared__ float As[16][64];  // [k][m]  m = frame
  __shared__ float Bs[16][64];  // [k][n]  n = out dim
  const int tid = threadIdx.x;
  const int m0 = blockIdx.x * 64;  // frames
  const int n0 = blockIdx.y * 64;  // dims
  const int tx = tid & 15, ty = tid >> 4;
  const int am = tid >> 2, ak = (tid & 3) << 2;
  const int bk = tid >> 4, bn = (tid & 15) << 2;
  const int t = m0 + am;
  int sid = segid[t];
  sid = sid < 0 ? 0 : (sid >= S ? S - 1 : sid);
  float acc[4][4] = {};  // [n][m]
  for (int k0 = 0; k0 < 1024; k0 += 16) {
    const float* src = (k0 + ak < 512) ? (seg2 + (size_t)sid * 512 + k0 + ak)
                                       : (ff + (size_t)t * 512 + (k0 + ak - 512));
    const float4 av = *reinterpret_cast<const float4*>(src);
    As[ak + 0][am] = av.x; As[ak + 1][am] = av.y; As[ak + 2][am] = av.z; As[ak + 3][am] = av.w;
    const float4 bv = *reinterpret_cast<const float4*>(Wsf + (size_t)(k0 + bk) * 512 + n0 + bn);
    Bs[bk][bn + 0] = bv.x; Bs[bk][bn + 1] = bv.y; Bs[bk][bn + 2] = bv.z; Bs[bk][bn + 3] = bv.w;
    __syncthreads();
#pragma unroll
    for (int i = 0; i < 16; i++) {
      const float4 a4 = *reinterpret_cast<const float4*>(&As[i][tx * 4]);
      const float4 b4 = *reinterpret_cast<const float4*>(&Bs[i][ty * 4]);
      const float aa[4] = {a4.x, a4.y, a4.z, a4.w};
      const float bb[4] = {b4.x, b4.y, b4.z, b4.w};
#pragma unroll
      for (int yy = 0; yy < 4; yy++)
#pragma unroll
        for (int xx = 0; xx < 4; xx++) acc[yy][xx] += bb[yy] * aa[xx];
    }
    __syncthreads();
  }
#pragma unroll
  for (int yy = 0; yy < 4; yy++) {
    const int n = n0 + ty * 4 + yy;
    const float bb = bsf[n];
    float4 o;
    o.x = fmaxf(acc[yy][0] + bb, 0.f);
    o.y = fmaxf(acc[yy][1] + bb, 0.f);
    o.z = fmaxf(acc[yy][2] + bb, 0.f);
    o.w = fmaxf(acc[yy][3] + bb, 0.f);
    *reinterpret_cast<float4*>(Y + (size_t)n * TT + m0 + tx * 4) = o;
  }
}

// ------------------------------------------------------------------- TCN conv
// X,Y: (512,T).  NTAPS==1: W[o][i]; NTAPS==3: W[o][i][3]; 'SAME', dilation d<=32.
template<int NTAPS, int RELU, int RES>
__launch_bounds__(256)
__global__ void conv_k(const float* __restrict__ X, const float* __restrict__ W,
                       const float* __restrict__ bias, const float* __restrict__ Res,
                       float* __restrict__ Y, int dil) {
  __shared__ float Xs[16][128];
  __shared__ float Ws[NTAPS][16][64];
  const int t0 = blockIdx.x * 64, c0 = blockIdx.y * 64;
  const int d = (NTAPS == 3) ? dil : 0;
  const int width = 64 + 2 * d;
  const int tid = threadIdx.x, tx = tid & 15, ty = tid >> 4;
  const int wc = tid >> 2, wi0 = (tid & 3) << 2;
  float acc[4][4] = {};  // [c][t]
  for (int k0 = 0; k0 < 512; k0 += 16) {
    for (int e = tid; e < 16 * width; e += 256) {
      const int ttl = e % width, ii = e / width;
      const int gt = t0 - d + ttl;
      Xs[ii][ttl] = (gt >= 0 && gt < TT) ? X[(size_t)(k0 + ii) * TT + gt] : 0.f;
    }
    if (NTAPS == 1) {
      const float4 wv = *reinterpret_cast<const float4*>(W + (size_t)(c0 + wc) * 512 + k0 + wi0);
      Ws[0][wi0 + 0][wc] = wv.x; Ws[0][wi0 + 1][wc] = wv.y;
      Ws[0][wi0 + 2][wc] = wv.z; Ws[0][wi0 + 3][wc] = wv.w;
    } else {
#pragma unroll
      for (int j = 0; j < 4; j++)
#pragma unroll
        for (int tap = 0; tap < NTAPS; tap++)
          Ws[tap][wi0 + j][wc] = W[((size_t)(c0 + wc) * 512 + k0 + wi0 + j) * 3 + tap];
    }
    __syncthreads();
#pragma unroll
    for (int i = 0; i < 16; i++) {
#pragma unroll
      for (int tap = 0; tap < NTAPS; tap++) {
        const float4 w4 = *reinterpret_cast<const float4*>(&Ws[tap][i][ty * 4]);
        const float wv4[4] = {w4.x, w4.y, w4.z, w4.w};
        const int xb = tx * 4 + tap * d;
        float xv[4];
        xv[0] = Xs[i][xb + 0]; xv[1] = Xs[i][xb + 1];
        xv[2] = Xs[i][xb + 2]; xv[3] = Xs[i][xb + 3];
#pragma unroll
        for (int a = 0; a < 4; a++)
#pragma unroll
          for (int b = 0; b < 4; b++) acc[a][b] += wv4[a] * xv[b];
      }
    }
    __syncthreads();
  }
#pragma unroll
  for (int a = 0; a < 4; a++) {
    const int c = c0 + ty * 4 + a;
    const float bb = bias[c];
    float vals[4];
#pragma unroll
    for (int b = 0; b < 4; b++) {
      float v = acc[a][b] + bb;
      if (RES) v += Res[(size_t)c * TT + t0 + tx * 4 + b];
      if (RELU) v = fmaxf(v, 0.f);
      vals[b] = v;
    }
    *reinterpret_cast<float4*>(Y + (size_t)c * TT + t0 + tx * 4) =
        make_float4(vals[0], vals[1], vals[2], vals[3]);
  }
}

// -------------------- tiled transpose (512,T) -> out (T,512) + f32 copy (T,512)
__launch_bounds__(256)
__global__ void temit_k(const float* __restrict__ Xin, float* __restrict__ outp,
                        float* __restrict__ Aout) {
  __shared__ float tile[32][33];
  const int t0 = blockIdx.x * 32, d0 = blockIdx.y * 32;
  const int lx = threadIdx.x & 31, ly = threadIdx.x >> 5;
#pragma unroll
  for (int r = 0; r < 4; r++)
    tile[ly + 8 * r][lx] = Xin[(size_t)(d0 + ly + 8 * r) * TT + t0 + lx];
  __syncthreads();
#pragma unroll
  for (int r = 0; r < 4; r++) {
    const int t = t0 + ly + 8 * r, dd = d0 + lx;
    const float v = tile[lx][ly + 8 * r];
    outp[(size_t)t * 512 + dd] = v;
    Aout[(size_t)t * 512 + dd] = v;
  }
}

// ---------------------------------------------------------------- cosine sim
__global__ void nsim_k(const float* __restrict__ V, const float* __restrict__ text,
                       const float* __restrict__ tnorm, float* __restrict__ out, int R) {
  int idx = blockIdx.x * 256 + threadIdx.x;  // r*32 + c
  if (idx >= R * 32) return;
  int r = idx >> 5, c = idx & 31;
  const float* vr = V + (size_t)r * 512;
  float ss = 0.f, dot = 0.f;
  for (int dd = 0; dd < 512; dd++) {
    float v = vr[dd];
    ss += v * v;
    dot += v * text[(size_t)c * 512 + dd];
  }
  out[idx] = dot / (sqrtf(ss) * tnorm[c]);
}

// ======================================================================= host
extern "C" void kernel_launch(void* const* d_in, const int* in_sizes, int n_in,
                              void* d_out, int out_size, void* d_ws, size_t ws_size,
                              hipStream_t stream) {
  const float* in_ff   = (const float*)d_in[0];
  const float* in_act  = (const float*)d_in[1];
  const float* in_fpos = (const float*)d_in[2];
  const float* in_apos = (const float*)d_in[3];
  const float* in_text = (const float*)d_in[4];
  const float* Wf2c = (const float*)d_in[5];  const float* bf2c = (const float*)d_in[6];
  const float* Wa2c = (const float*)d_in[7];  const float* ba2c = (const float*)d_in[8];
  const float* Ws2c = (const float*)d_in[9];  const float* bs2c = (const float*)d_in[10];
  const float* Wih_f = (const float*)d_in[11]; const float* Whh_f = (const float*)d_in[12];
  const float* bih_f = (const float*)d_in[13]; const float* bhh_f = (const float*)d_in[14];
  const float* Wih_b = (const float*)d_in[15]; const float* Whh_b = (const float*)d_in[16];
  const float* bih_b = (const float*)d_in[17]; const float* bhh_b = (const float*)d_in[18];
  const float* Wcomb = (const float*)d_in[19]; const float* bcomb = (const float*)d_in[20];
  const float* f2a_Wq = (const float*)d_in[21]; const float* f2a_Wk = (const float*)d_in[22];
  const float* f2a_Wv = (const float*)d_in[23]; const float* f2a_Wo = (const float*)d_in[24];
  const float* f2a_bo = (const float*)d_in[25];
  const float* ag_Wih = (const float*)d_in[26]; const float* ag_Whh = (const float*)d_in[27];
  const float* ag_bih = (const float*)d_in[28]; const float* ag_bhh = (const float*)d_in[29];
  const float* a2f_Wq = (const float*)d_in[30]; const float* a2f_Wk = (const float*)d_in[31];
  const float* a2f_Wv = (const float*)d_in[32]; const float* a2f_Wo = (const float*)d_in[33];
  const float* a2f_bo = (const float*)d_in[34];
  const float* Wsf = (const float*)d_in[35]; const float* bsf = (const float*)d_in[36];
  const float* tcn_inW = (const float*)d_in[37]; const float* tcn_inb = (const float*)d_in[38];
  const float* tcn_dW = (const float*)d_in[39]; const float* tcn_db = (const float*)d_in[40];
  const float* tcn_pW = (const float*)d_in[41]; const float* tcn_pb = (const float*)d_in[42];
  const float* tcn_outW = (const float*)d_in[43]; const float* tcn_outb = (const float*)d_in[44];

  int S = (out_size - (TT * DD + MM * DD + TT * CC + MM * CC)) / CC;
  if (S < 1) S = 1;
  if (S > TT) S = TT;

  // ---------------- workspace layout
  char* ws = (char*)d_ws;
  size_t off = 0;
  auto alloc = [&](size_t b) -> char* { char* p = ws + off; off += (b + 255) & ~(size_t)255; return p; };
  const size_t BTD = (size_t)TT * DD * 4;
  float* bufA = (float*)alloc(BTD);
  float* bufB = (float*)alloc(BTD);
  int* pred    = (int*)alloc((size_t)TT * 4);
  int* segid   = (int*)alloc((size_t)TT * 4);
  int* starts  = (int*)alloc((size_t)TT * 4);
  int* centers = (int*)alloc((size_t)TT * 4);
  int* cnts    = (int*)alloc((size_t)TT * 4);
  int* cntF    = (int*)alloc((size_t)TT * CNT_STRIDE * 4);   // seg fwd barrier counters
  int* cntB    = (int*)alloc((size_t)TT * CNT_STRIDE * 4);   // seg bwd barrier counters
  int* cntA    = (int*)alloc((size_t)256 * CNT_STRIDE * 4);  // action barrier counters
  float* tnorm = (float*)alloc(32 * 4);
  float* segmean = (float*)alloc((size_t)S * 512 * 4);
  float* gif  = (float*)alloc((size_t)S * 768 * 4);
  float* gib  = (float*)alloc((size_t)S * 768 * 4);
  float* hfb  = (float*)alloc((size_t)S * 256 * 4);
  float* hbb  = (float*)alloc((size_t)S * 256 * 4);
  float* acmb = (float*)alloc((size_t)S * 512 * 4);
  float* segc = (float*)alloc((size_t)S * 512 * 4);
  float* segpos = (float*)alloc((size_t)S * 512 * 4);
  float* kin  = (float*)alloc((size_t)S * 512 * 4);
  float* kf2a = (float*)alloc((size_t)S * 512 * 4);
  float* vf2a = (float*)alloc((size_t)S * 512 * 4);
  float* q2   = (float*)alloc((size_t)S * 512 * 4);
  float* att2 = (float*)alloc((size_t)S * 512 * 4);
  float* seg2 = (float*)alloc((size_t)S * 512 * 4);
  float* vseg = (float*)alloc((size_t)S * 512 * 4);
  float* pbuf = (float*)alloc((size_t)64 * S * 4);
  float* qin  = (float*)alloc((size_t)64 * 512 * 4);
  float* qf2a = (float*)alloc((size_t)64 * 512 * 4);
  float* att1 = (float*)alloc((size_t)64 * 512 * 4);
  float* af0  = (float*)alloc((size_t)64 * 512 * 4);
  float* aggi = (float*)alloc((size_t)64 * 1536 * 4);
  float* afg  = (float*)alloc((size_t)64 * 512 * 4);
  float* k2in = (float*)alloc((size_t)64 * 512 * 4);
  float* k2   = (float*)alloc((size_t)64 * 512 * 4);
  float* v2   = (float*)alloc((size_t)64 * 512 * 4);
  float* vaf  = (float*)alloc((size_t)64 * 512 * 4);
  (void)ws_size; (void)in_sizes; (void)n_in;

  float* outp = (float*)d_out;
  float* out_ff   = outp;
  float* out_af   = outp + (size_t)TT * DD;
  float* out_fsim = out_af + (size_t)MM * DD;
  float* out_asim = out_fsim + (size_t)TT * CC;
  float* out_ssim = out_asim + (size_t)MM * CC;

  auto GR = [](long n) { return (unsigned)((n + 255) / 256); };

  // zero ws (incl. barrier counters -> 0, mandatory every launch)
  zero_k<<<2048, 256, 0, stream>>>((float*)d_ws, (long)(off / 4));

  tnorm_k<<<1, 256, 0, stream>>>(in_text, tnorm);

  // segmentation (tiled GEMM for the T-sized projection)
  gemm_k<<<dim3(8, 128), 256, 0, stream>>>(in_ff, Wf2c, bf2c, bufA, TT, 512, 512);
  argmax_k<<<TT, 256, 0, stream>>>(bufA, in_text, tnorm, pred);
  segscan_k<<<1, 256, 0, stream>>>(pred, segid, starts, centers, cnts);
  segmean_k<<<GR((long)S * 512), 256, 0, stream>>>(in_ff, starts, cnts, segmean, S);

  // seg BiGRU (multi-block LDS-resident scan)
  ngemm_k<<<GR((long)S * 768), 256, 0, stream>>>(segmean, Wih_f, bih_f, gif, S, 768, 512);
  ngemm_k<<<GR((long)S * 768), 256, 0, stream>>>(segmean, Wih_b, bih_b, gib, S, 768, 512);
  gru_seg_mb_k<<<8, 192, 0, stream>>>(gif, gib, Whh_f, bhh_f, Whh_b, bhh_b,
                                      hfb, hbb, S, cntF, cntB);
  acomb_k<<<GR((long)S * 512), 256, 0, stream>>>(hfb, hbb, acmb, S * 512);
  ngemm_k<<<GR((long)S * 512), 256, 0, stream>>>(acmb, Wcomb, bcomb, segc, S, 512, 512);
  gatherpos_k<<<GR((long)S * 512), 256, 0, stream>>>(in_fpos, centers, segpos, S * 512);

  // f2a attention (actions query segments)
  addff_k<<<GR(64 * 512), 256, 0, stream>>>(in_act, in_apos, qin, 64 * 512);
  addff_k<<<GR((long)S * 512), 256, 0, stream>>>(segc, segpos, kin, S * 512);
  ngemm_k<<<GR(64 * 512), 256, 0, stream>>>(qin, f2a_Wq, nullptr, qf2a, 64, 512, 512);
  ngemm_k<<<GR((long)S * 512), 256, 0, stream>>>(kin, f2a_Wk, nullptr, kf2a, S, 512, 512);
  ngemm_k<<<GR((long)S * 512), 256, 0, stream>>>(segc, f2a_Wv, nullptr, vf2a, S, 512, 512);
  nlogit_k<<<GR((long)64 * S), 256, 0, stream>>>(qf2a, kf2a, pbuf, 64, S);
  nsoft_k<<<1, 256, 0, stream>>>(pbuf, 64, S);
  nav_k<<<GR(64 * 512), 256, 0, stream>>>(pbuf, vf2a, att1, 64, S);
  ngemm_k<<<GR(64 * 512), 256, 0, stream>>>(att1, f2a_Wo, f2a_bo, af0, 64, 512, 512);

  // action GRU (multi-block LDS-resident scan)
  ngemm_k<<<GR(64 * 1536), 256, 0, stream>>>(af0, ag_Wih, ag_bih, aggi, 64, 1536, 512);
  gru_act_mb_k<<<16, 128, 0, stream>>>(aggi, ag_Whh, ag_bhh, afg, MM, cntA);
  copy_k<<<GR(64 * 512), 256, 0, stream>>>(afg, out_af, 64 * 512);

  // a2f attention (segments query actions)
  addff_k<<<GR(64 * 512), 256, 0, stream>>>(afg, in_apos, k2in, 64 * 512);
  ngemm_k<<<GR((long)S * 512), 256, 0, stream>>>(kin, a2f_Wq, nullptr, q2, S, 512, 512);
  ngemm_k<<<GR(64 * 512), 256, 0, stream>>>(k2in, a2f_Wk, nullptr, k2, 64, 512, 512);
  ngemm_k<<<GR(64 * 512), 256, 0, stream>>>(afg, a2f_Wv, nullptr, v2, 64, 512, 512);
  nlogit_k<<<GR((long)S * 64), 256, 0, stream>>>(q2, k2, pbuf, S, 64);
  nsoft_k<<<GR(S), 256, 0, stream>>>(pbuf, S, 64);
  nav_k<<<GR((long)S * 512), 256, 0, stream>>>(pbuf, v2, att2, S, 64);
  ngemm_k<<<GR((long)S * 512), 256, 0, stream>>>(att2, a2f_Wo, a2f_bo, seg2, S, 512, 512);

  // frame fusion + TCN (tiled), ping-pong bufA <-> bufB as (D,T)
  ff2_k<<<dim3(128, 8), 256, 0, stream>>>(seg2, in_ff, segid, Wsf, bsf, bufA, S);
  conv_k<1, 0, 0><<<dim3(128, 8), 256, 0, stream>>>(bufA, tcn_inW, tcn_inb, nullptr, bufB, 1);
  for (int l = 0; l < 6; l++) {
    conv_k<3, 1, 0><<<dim3(128, 8), 256, 0, stream>>>(
        bufB, tcn_dW + (size_t)l * 512 * 512 * 3, tcn_db + (size_t)l * 512, nullptr, bufA, 1 << l);
    conv_k<1, 0, 1><<<dim3(128, 8), 256, 0, stream>>>(
        bufA, tcn_pW + (size_t)l * 512 * 512, tcn_pb + (size_t)l * 512, bufB, bufB, 1);
  }
  conv_k<1, 0, 0><<<dim3(128, 8), 256, 0, stream>>>(bufB, tcn_outW, tcn_outb, nullptr, bufA, 1);
  temit_k<<<dim3(256, 16), 256, 0, stream>>>(bufA, out_ff, bufB);

  // similarity heads (tiled GEMM for the T-sized projection)
  gemm_k<<<dim3(8, 128), 256, 0, stream>>>(bufB, Wf2c, bf2c, bufA, TT, 512, 512);
  nsim_k<<<GR((long)TT * 32), 256, 0, stream>>>(bufA, in_text, tnorm, out_fsim, TT);
  ngemm_k<<<GR(64 * 512), 256, 0, stream>>>(afg, Wa2c, ba2c, vaf, 64, 512, 512);
  nsim_k<<<GR(64 * 32), 256, 0, stream>>>(vaf, in_text, tnorm, out_asim, 64);
  ngemm_k<<<GR((long)S * 512), 256, 0, stream>>>(seg2, Ws2c, bs2c, vseg, S, 512, 512);
  nsim_k<<<GR((long)S * 32), 256, 0, stream>>>(vseg, in_text, tnorm, out_ssim, S);
}

// Round 10
// 7190.117 us; speedup vs baseline: 2.2906x; 1.1561x over previous
//
#include <hip/hip_runtime.h>
#include <cstdint>
#include <cstddef>

__device__ __forceinline__ float sigf(float x) { return 1.f / (1.f + expf(-x)); }

// fp16 pack/unpack helpers (weights-only precision reduction)
__device__ __forceinline__ unsigned packh(float a, float b) {
  union { unsigned u; _Float16 h[2]; } cv;
  cv.h[0] = (_Float16)a; cv.h[1] = (_Float16)b; return cv.u;
}
__device__ __forceinline__ float2 uph(unsigned u) {
  union { unsigned uu; _Float16 h[2]; } cv; cv.uu = u;
  return make_float2((float)cv.h[0], (float)cv.h[1]);
}

typedef _Float16 f16x8 __attribute__((ext_vector_type(8)));
typedef float f32x16 __attribute__((ext_vector_type(16)));

static constexpr int TT = 8192;   // frames
static constexpr int MM = 64;     // actions
static constexpr int CC = 32;     // classes
static constexpr int DD = 512;    // model dim
static constexpr unsigned GUARD_MAX = 1u << 30;
static constexpr int CNT_STRIDE = 16;   // 64B spacing between per-step counters

// ---------------------------------------------------------------- ws zeroing
__global__ void zero_k(float* __restrict__ p, long n) {
  long i = (long)blockIdx.x * 256 + threadIdx.x;
  long stride = (long)gridDim.x * 256;
  for (; i < n; i += stride) p[i] = 0.f;
}

// ---------------------------------------------------------------- elementwise
__global__ void copy_k(const float* __restrict__ a, float* __restrict__ o, int n) {
  int i = blockIdx.x * 256 + threadIdx.x;
  if (i < n) o[i] = a[i];
}
__global__ void addff_k(const float* __restrict__ a, const float* __restrict__ b, float* __restrict__ o, int n) {
  int i = blockIdx.x * 256 + threadIdx.x;
  if (i < n) o[i] = a[i] + b[i];
}
__global__ void acomb_k(const float* __restrict__ hf, const float* __restrict__ hb, float* __restrict__ o, int n) {
  int i = blockIdx.x * 256 + threadIdx.x;
  if (i >= n) return;
  int s = i >> 9, j = i & 511;
  float v = (j < 256) ? hf[(size_t)s * 256 + j] : hb[(size_t)s * 256 + (j - 256)];
  o[i] = fmaxf(v, 0.f);
}
__global__ void gatherpos_k(const float* __restrict__ fpos, const int* __restrict__ centers,
                            float* __restrict__ segpos, int n) {
  int i = blockIdx.x * 256 + threadIdx.x;
  if (i >= n) return;
  int s = i >> 9, dd = i & 511;
  int ct = centers[s];
  ct = ct < 0 ? 0 : (ct > TT - 1 ? TT - 1 : ct);
  segpos[i] = fpos[(size_t)ct * 512 + dd];
}

// ---------------------------------------------------------------- text norms
__global__ void tnorm_k(const float* __restrict__ text, float* __restrict__ tnorm) {
  int c = blockIdx.x * 256 + threadIdx.x;
  if (c >= 32) return;
  float s = 0.f;
  for (int dd = 0; dd < 512; dd++) { float v = text[(size_t)c * 512 + dd]; s += v * v; }
  tnorm[c] = sqrtf(s);
}

// ---------------------------------------------------- naive GEMM (small ops)
__global__ void ngemm_k(const float* __restrict__ A, const float* __restrict__ B,
                        const float* __restrict__ bias, float* __restrict__ C,
                        int M, int N, int K) {
  int idx = blockIdx.x * 256 + threadIdx.x;
  if (idx >= M * N) return;
  int m = idx / N, n = idx - m * N;
  float a = bias ? bias[n] : 0.f;
  const float* Ar = A + (size_t)m * K;
  for (int k = 0; k < K; k++) a += Ar[k] * B[(size_t)k * N + n];
  C[idx] = a;
}

// ---------------------------------------------------- naive attention pieces
__global__ void nlogit_k(const float* __restrict__ Q, const float* __restrict__ Kk,
                         float* __restrict__ L, int NY, int NX) {
  int idx = blockIdx.x * 256 + threadIdx.x;
  if (idx >= NY * NX) return;
  int y = idx / NX, x = idx - y * NX;
  const float* qr = Q + (size_t)y * 512;
  const float* kr = Kk + (size_t)x * 512;
  float d = 0.f;
  for (int k = 0; k < 512; k++) d += qr[k] * kr[k];
  L[idx] = d * 0.044194173824159216f;  // 1/sqrt(512)
}
__global__ void nsoft_k(float* __restrict__ L, int NY, int NX) {  // 1 thread / row
  int y = blockIdx.x * 256 + threadIdx.x;
  if (y >= NY) return;
  float* row = L + (size_t)y * NX;
  float m = row[0];
  for (int x = 1; x < NX; x++) m = fmaxf(m, row[x]);
  float s = 0.f;
  for (int x = 0; x < NX; x++) { float p = expf(row[x] - m); row[x] = p; s += p; }
  const float inv = 1.f / s;
  for (int x = 0; x < NX; x++) row[x] *= inv;
}
__global__ void nav_k(const float* __restrict__ P, const float* __restrict__ V,
                      float* __restrict__ O, int NY, int NX) {
  int idx = blockIdx.x * 256 + threadIdx.x;
  if (idx >= NY * 512) return;
  int y = idx >> 9, dd = idx & 511;
  const float* pr = P + (size_t)y * NX;
  float o = 0.f;
  for (int x = 0; x < NX; x++) o += pr[x] * V[(size_t)x * 512 + dd];
  O[idx] = o;
}

// ------------------------------------------ argmax over classes: block per row
__global__ void argmax_k(const float* __restrict__ V, const float* __restrict__ text,
                         const float* __restrict__ tnorm, int* __restrict__ pred) {
  __shared__ float vs[512];
  __shared__ float dots[32];
  const int r = blockIdx.x, tid = threadIdx.x;
  for (int dd = tid; dd < 512; dd += 256) vs[dd] = V[(size_t)r * 512 + dd];
  __syncthreads();
  if (tid < 32) {
    float dot = 0.f;
    const float* tr = text + (size_t)tid * 512;
    for (int dd = 0; dd < 512; dd++) dot += vs[dd] * tr[dd];
    dots[tid] = dot / tnorm[tid];
  }
  __syncthreads();
  if (tid == 0) {
    int best = 0; float bv = dots[0];
    for (int c = 1; c < 32; c++) if (dots[c] > bv) { bv = dots[c]; best = c; }
    pred[r] = best;
  }
}

// ------------------------------- parallel run-length segmentation (one block)
__global__ void segscan_k(const int* __restrict__ pred, int* __restrict__ segid,
                          int* __restrict__ starts, int* __restrict__ centers,
                          int* __restrict__ cnts) {
  __shared__ int base[256];
  __shared__ int SS;
  const int tid = threadIdx.x;
  int lc = 0;
  unsigned flags = 0;
  int prev = (tid > 0) ? pred[tid * 32 - 1] : 0;
  for (int i = 0; i < 32; i++) {
    const int t = tid * 32 + i;
    const int cur = pred[t];
    const int c = (t > 0) && (cur != prev);
    prev = cur;
    flags |= ((unsigned)c) << i;
    lc += c;
  }
  base[tid] = lc;
  __syncthreads();
  if (tid == 0) {
    int run = 0;
    for (int i = 0; i < 256; i++) { const int v = base[i]; base[i] = run; run += v; }
    SS = run + 1;
  }
  __syncthreads();
  int b = base[tid];
  for (int i = 0; i < 32; i++) {
    const int t = tid * 32 + i;
    if ((flags >> i) & 1u) { b++; starts[b] = t; }
    segid[t] = b;
  }
  if (tid == 0) starts[0] = 0;
  __threadfence_block();
  __syncthreads();
  const int S = SS;
  for (int s = tid; s < TT; s += 256) {
    if (s < S) {
      const int e = (s == S - 1) ? (TT - 1) : (starts[s + 1] - 1);
      centers[s] = (starts[s] + e) >> 1;
      cnts[s] = e - starts[s] + 1;
    } else {
      starts[s] = 0; cnts[s] = 1; centers[s] = 0;
    }
  }
}

// ---------------------------------------------------------- segment mean pool
__global__ void segmean_k(const float* __restrict__ ff, const int* __restrict__ starts,
                          const int* __restrict__ cnts, float* __restrict__ segmean, int S) {
  int idx = blockIdx.x * 256 + threadIdx.x;
  if (idx >= S * 512) return;
  int s = idx >> 9, dd = idx & 511;
  int st = starts[s], n = cnts[s];
  st = st < 0 ? 0 : (st > TT - 1 ? TT - 1 : st);
  n = n < 1 ? 1 : n;
  if (st + n > TT) n = TT - st;
  float a = 0.f;
  for (int t = st; t < st + n; t++) a += ff[(size_t)t * 512 + dd];
  segmean[idx] = a / (float)n;
}

// ------------------- multi-block bidirectional seg GRU (H=256), LDS weights
__launch_bounds__(192)
__global__ void gru_seg_mb_k(const float* __restrict__ gi_f, const float* __restrict__ gi_b,
                             const float* __restrict__ Whh_f, const float* __restrict__ bhh_f,
                             const float* __restrict__ Whh_b, const float* __restrict__ bhh_b,
                             float* __restrict__ hf, float* __restrict__ hb, int S,
                             int* __restrict__ cnt_f, int* __restrict__ cnt_b) {
  const int dir = blockIdx.x >> 2;
  const int part = blockIdx.x & 3;
  const float* gi = dir ? gi_b : gi_f;
  const float* Whh = dir ? Whh_b : Whh_f;
  const float* bhh = dir ? bhh_b : bhh_f;
  float* ho = dir ? hb : hf;
  int* cnt = dir ? cnt_b : cnt_f;
  const int tid = threadIdx.x;
  const int h0 = part * 64;
  const int grp = tid >> 6;
  const int jj = tid & 63;
  const int j = grp * 256 + h0 + jj;
  __shared__ unsigned wlds[128 * 192];
  __shared__ unsigned hpk[128];
  __shared__ float hcur[256];
  __shared__ float rbuf[64], zbuf[64], gnbuf[64];
  for (int e = tid; e < 128 * 192; e += 192) {
    const int i2 = e / 192, g = e - i2 * 192;
    const int gg = (g >> 6) * 256 + h0 + (g & 63);
    wlds[e] = packh(Whh[(size_t)(2 * i2) * 768 + gg], Whh[(size_t)(2 * i2 + 1) * 768 + gg]);
  }
  for (int e = tid; e < 128; e += 192) hpk[e] = 0u;
  for (int e = tid; e < 256; e += 192) hcur[e] = 0.f;
  const float bj = bhh[j];
  __syncthreads();
  for (int step = 0; step < S; step++) {
    const int s = dir ? (S - 1 - step) : step;
    float a0 = 0.f, a1 = 0.f;
#pragma unroll 16
    for (int i2 = 0; i2 < 128; i2 += 2) {
      const float2 hv0 = uph(hpk[i2]);
      const float2 hv1 = uph(hpk[i2 + 1]);
      const float2 w0 = uph(wlds[i2 * 192 + tid]);
      const float2 w1 = uph(wlds[(i2 + 1) * 192 + tid]);
      a0 += hv0.x * w0.x + hv0.y * w0.y;
      a1 += hv1.x * w1.x + hv1.y * w1.y;
    }
    const float gh = bj + a0 + a1;
    if (grp == 0)      rbuf[jj] = sigf(gi[(size_t)s * 768 + j] + gh);
    else if (grp == 1) zbuf[jj] = sigf(gi[(size_t)s * 768 + j] + gh);
    else               gnbuf[jj] = gh;
    __syncthreads();
    if (tid < 64) {
      const float ginv = gi[(size_t)s * 768 + 512 + h0 + tid];
      const float nval = tanhf(ginv + rbuf[tid] * gnbuf[tid]);
      const float hn = (1.f - zbuf[tid]) * nval + zbuf[tid] * hcur[h0 + tid];
      __hip_atomic_store(&ho[(size_t)s * 256 + h0 + tid], hn,
                         __ATOMIC_RELAXED, __HIP_MEMORY_SCOPE_AGENT);
    }
    __syncthreads();
    if (tid == 0) {
      __hip_atomic_fetch_add(cnt + step * CNT_STRIDE, 1,
                             __ATOMIC_RELEASE, __HIP_MEMORY_SCOPE_AGENT);
      unsigned guard = 0;
      while (__hip_atomic_load(cnt + step * CNT_STRIDE,
                               __ATOMIC_RELAXED, __HIP_MEMORY_SCOPE_AGENT) < 4 &&
             ++guard < GUARD_MAX) {
        __builtin_amdgcn_s_sleep(8);
      }
      (void)__hip_atomic_load(cnt + step * CNT_STRIDE,
                              __ATOMIC_ACQUIRE, __HIP_MEMORY_SCOPE_AGENT);
    }
    __syncthreads();
    for (int e = tid; e < 256; e += 192)
      hcur[e] = __hip_atomic_load(&ho[(size_t)s * 256 + e],
                                  __ATOMIC_RELAXED, __HIP_MEMORY_SCOPE_AGENT);
    __syncthreads();
    for (int e = tid; e < 128; e += 192) hpk[e] = packh(hcur[2 * e], hcur[2 * e + 1]);
    __syncthreads();
  }
}

// ------------------------- multi-block action GRU (H=512), LDS weights
__launch_bounds__(128)
__global__ void gru_act_mb_k(const float* __restrict__ gi, const float* __restrict__ Whh,
                             const float* __restrict__ bhh, float* __restrict__ hout,
                             int steps, int* __restrict__ cnt) {
  const int part = blockIdx.x;
  const int tid = threadIdx.x;
  const int h0 = part * 32;
  const int grp = tid >> 5;
  const int jj = tid & 31;
  const bool act = (tid < 96);
  const int j = act ? (grp * 512 + h0 + jj) : 0;
  __shared__ unsigned wlds[256 * 96];
  __shared__ unsigned hpk[256];
  __shared__ float hcur[512];
  __shared__ float rbuf[32], zbuf[32], gnbuf[32];
  for (int e = tid; e < 256 * 96; e += 128) {
    const int i2 = e / 96, g = e - i2 * 96;
    const int gg = (g >> 5) * 512 + h0 + (g & 31);
    wlds[e] = packh(Whh[(size_t)(2 * i2) * 1536 + gg], Whh[(size_t)(2 * i2 + 1) * 1536 + gg]);
  }
  for (int e = tid; e < 256; e += 128) hpk[e] = 0u;
  for (int e = tid; e < 512; e += 128) hcur[e] = 0.f;
  const float bj = act ? bhh[j] : 0.f;
  __syncthreads();
  for (int step = 0; step < steps; step++) {
    if (act) {
      float a0 = 0.f, a1 = 0.f;
#pragma unroll 16
      for (int i2 = 0; i2 < 256; i2 += 2) {
        const float2 hv0 = uph(hpk[i2]);
        const float2 hv1 = uph(hpk[i2 + 1]);
        const float2 w0 = uph(wlds[i2 * 96 + tid]);
        const float2 w1 = uph(wlds[(i2 + 1) * 96 + tid]);
        a0 += hv0.x * w0.x + hv0.y * w0.y;
        a1 += hv1.x * w1.x + hv1.y * w1.y;
      }
      const float gh = bj + a0 + a1;
      if (grp == 0)      rbuf[jj] = sigf(gi[(size_t)step * 1536 + j] + gh);
      else if (grp == 1) zbuf[jj] = sigf(gi[(size_t)step * 1536 + j] + gh);
      else               gnbuf[jj] = gh;
    }
    __syncthreads();
    if (tid < 32) {
      const float ginv = gi[(size_t)step * 1536 + 1024 + h0 + tid];
      const float nval = tanhf(ginv + rbuf[tid] * gnbuf[tid]);
      const float hn = (1.f - zbuf[tid]) * nval + zbuf[tid] * hcur[h0 + tid];
      __hip_atomic_store(&hout[(size_t)step * 512 + h0 + tid], hn,
                         __ATOMIC_RELAXED, __HIP_MEMORY_SCOPE_AGENT);
    }
    __syncthreads();
    if (tid == 0) {
      __hip_atomic_fetch_add(cnt + step * CNT_STRIDE, 1,
                             __ATOMIC_RELEASE, __HIP_MEMORY_SCOPE_AGENT);
      unsigned guard = 0;
      while (__hip_atomic_load(cnt + step * CNT_STRIDE,
                               __ATOMIC_RELAXED, __HIP_MEMORY_SCOPE_AGENT) < 16 &&
             ++guard < GUARD_MAX) {
        __builtin_amdgcn_s_sleep(8);
      }
      (void)__hip_atomic_load(cnt + step * CNT_STRIDE,
                              __ATOMIC_ACQUIRE, __HIP_MEMORY_SCOPE_AGENT);
    }
    __syncthreads();
    for (int e = tid; e < 512; e += 128)
      hcur[e] = __hip_atomic_load(&hout[(size_t)step * 512 + e],
                                  __ATOMIC_RELAXED, __HIP_MEMORY_SCOPE_AGENT);
    __syncthreads();
    for (int e = tid; e < 256; e += 128) hpk[e] = packh(hcur[2 * e], hcur[2 * e + 1]);
    __syncthreads();
  }
}

// ------------------------------------------------------------ tiled GEMM
// C[M,N] = A[M,K] @ B[K,N] + bias   (M,N multiples of 64 ONLY)
__launch_bounds__(256)
__global__ void gemm_k(const float* __restrict__ A, const float* __restrict__ B,
                       const float* __restrict__ bias, float* __restrict__ C,
                       int M, int N, int K) {
  __shared__ float As[16][64];
  __shared__ float Bs[16][64];
  const int tid = threadIdx.x;
  const int n0 = blockIdx.x * 64, m0 = blockIdx.y * 64;
  const int tx = tid & 15, ty = tid >> 4;
  const int am = tid >> 2, ak = (tid & 3) << 2;
  const int bk = tid >> 4, bn = (tid & 15) << 2;
  float acc[4][4] = {};
  for (int k0 = 0; k0 < K; k0 += 16) {
    const float4 av = *reinterpret_cast<const float4*>(A + (size_t)(m0 + am) * K + k0 + ak);
    As[ak + 0][am] = av.x; As[ak + 1][am] = av.y; As[ak + 2][am] = av.z; As[ak + 3][am] = av.w;
    const float4 bv = *reinterpret_cast<const float4*>(B + (size_t)(k0 + bk) * N + n0 + bn);
    Bs[bk][bn + 0] = bv.x; Bs[bk][bn + 1] = bv.y; Bs[bk][bn + 2] = bv.z; Bs[bk][bn + 3] = bv.w;
    __syncthreads();
#pragma unroll
    for (int i = 0; i < 16; i++) {
      const float4 a4 = *reinterpret_cast<const float4*>(&As[i][ty * 4]);
      const float4 b4 = *reinterpret_cast<const float4*>(&Bs[i][tx * 4]);
      const float aa[4] = {a4.x, a4.y, a4.z, a4.w};
      const float bb[4] = {b4.x, b4.y, b4.z, b4.w};
#pragma unroll
      for (int x = 0; x < 4; x++)
#pragma unroll
        for (int y = 0; y < 4; y++) acc[x][y] += aa[x] * bb[y];
    }
    __syncthreads();
  }
#pragma unroll
  for (int x = 0; x < 4; x++) {
    const int m = m0 + ty * 4 + x;
#pragma unroll
    for (int y = 0; y < 4; y++) {
      const int n = n0 + tx * 4 + y;
      float v = acc[x][y];
      if (bias) v += bias[n];
      C[(size_t)m * N + n] = v;
    }
  }
}

// ---------------------------- ff2 = relu([seg2[seg_id[t]], ff[t]] @ Wsf + bsf)
// writes TRANSPOSED (D, T) for the TCN.  K=1024.
__launch_bounds__(256)
__global__ void ff2_k(const float* __restrict__ seg2, const float* __restrict__ ff,
                      const int* __restrict__ segid, const float* __restrict__ Wsf,
                      const float* __restrict__ bsf, float* __restrict__ Y, int S) {
  __shared__ float As[16][64];  // [k][m]  m = frame
  __shared__ float Bs[16][64];  // [k][n]  n = out dim
  const int tid = threadIdx.x;
  const int m0 = blockIdx.x * 64;  // frames
  const int n0 = blockIdx.y * 64;  // dims
  const int tx = tid & 15, ty = tid >> 4;
  const int am = tid >> 2, ak = (tid & 3) << 2;
  const int bk = tid >> 4, bn = (tid & 15) << 2;
  const int t = m0 + am;
  int sid = segid[t];
  sid = sid < 0 ? 0 : (sid >= S ? S - 1 : sid);
  float acc[4][4] = {};  // [n][m]
  for (int k0 = 0; k0 < 1024; k0 += 16) {
    const float* src = (k0 + ak < 512) ? (seg2 + (size_t)sid * 512 + k0 + ak)
                                       : (ff + (size_t)t * 512 + (k0 + ak - 512));
    const float4 av = *reinterpret_cast<const float4*>(src);
    As[ak + 0][am] = av.x; As[ak + 1][am] = av.y; As[ak + 2][am] = av.z; As[ak + 3][am] = av.w;
    const float4 bv = *reinterpret_cast<const float4*>(Wsf + (size_t)(k0 + bk) * 512 + n0 + bn);
    Bs[bk][bn + 0] = bv.x; Bs[bk][bn + 1] = bv.y; Bs[bk][bn + 2] = bv.z; Bs[bk][bn + 3] = bv.w;
    __syncthreads();
#pragma unroll
    for (int i = 0; i < 16; i++) {
      const float4 a4 = *reinterpret_cast<const float4*>(&As[i][tx * 4]);
      const float4 b4 = *reinterpret_cast<const float4*>(&Bs[i][ty * 4]);
      const float aa[4] = {a4.x, a4.y, a4.z, a4.w};
      const float bb[4] = {b4.x, b4.y, b4.z, b4.w};
#pragma unroll
      for (int yy = 0; yy < 4; yy++)
#pragma unroll
        for (int xx = 0; xx < 4; xx++) acc[yy][xx] += bb[yy] * aa[xx];
    }
    __syncthreads();
  }
#pragma unroll
  for (int yy = 0; yy < 4; yy++) {
    const int n = n0 + ty * 4 + yy;
    const float bb = bsf[n];
    float4 o;
    o.x = fmaxf(acc[yy][0] + bb, 0.f);
    o.y = fmaxf(acc[yy][1] + bb, 0.f);
    o.z = fmaxf(acc[yy][2] + bb, 0.f);
    o.w = fmaxf(acc[yy][3] + bb, 0.f);
    *reinterpret_cast<float4*>(Y + (size_t)n * TT + m0 + tx * 4) = o;
  }
}

// --------------------------------------------------- MFMA TCN conv (fp16 in)
// X,Y: (512,T) f32.  NTAPS==1: W[o][i]; NTAPS==3: W[o][i][3]; 'SAME', d<=32.
// Block tile: 64 c (m) x 128 t (n), 4 waves in 2x2, mfma_f32_32x32x16_f16.
template<int NTAPS, int RELU, int RES>
__launch_bounds__(256)
__global__ void convm_k(const float* __restrict__ X, const float* __restrict__ W,
                        const float* __restrict__ bias, const float* __restrict__ Res,
                        float* __restrict__ Y, int dil) {
  const int d = (NTAPS == 3) ? dil : 0;
  const int width = 128 + 2 * d;            // <= 192
  __shared__ __align__(16) _Float16 Ws16[NTAPS][64][72];   // [tap][m=c][k] pad 72
  __shared__ __align__(16) _Float16 Xs16[192][72];         // [t_local][k]  pad 72
  const int t0 = blockIdx.x * 128, c0 = blockIdx.y * 64;
  const int tid = threadIdx.x;
  const int l = tid & 63, w = tid >> 6;
  const int wm = w & 1, wn = w >> 1;
  const int l31 = l & 31, q = l >> 5;
  f32x16 acc0, acc1;
#pragma unroll
  for (int i = 0; i < 16; i++) { acc0[i] = 0.f; acc1[i] = 0.f; }
  const int xk = tid >> 2;          // k-row 0..63
  const int xu0 = tid & 3;
  for (int kc = 0; kc < 512; kc += 64) {
    __syncthreads();
    // stage X chunk transposed: Xs16[u][k]  (4 lanes per k-row, coalesced)
    {
      const float* xr = X + (size_t)(kc + xk) * TT;
      for (int u = xu0; u < width; u += 4) {
        const int gt = t0 - d + u;
        const float v = (gt >= 0 && gt < TT) ? xr[gt] : 0.f;
        Xs16[u][xk] = (_Float16)v;
      }
    }
    // stage weights (fp32 -> fp16)
    if (NTAPS == 3) {
      for (int e = tid; e < 64 * 64 * 3; e += 256) {
        const int tap = e % 3; const int r = e / 3;
        const int i = r & 63; const int c = r >> 6;
        Ws16[tap][c][i] = (_Float16)W[((size_t)(c0 + c) * 512 + kc + i) * 3 + tap];
      }
    } else {
      for (int e = tid; e < 1024; e += 256) {
        const int c = e >> 4, i0 = (e & 15) << 2;
        const float4 wv = *reinterpret_cast<const float4*>(W + (size_t)(c0 + c) * 512 + kc + i0);
        Ws16[0][c][i0 + 0] = (_Float16)wv.x; Ws16[0][c][i0 + 1] = (_Float16)wv.y;
        Ws16[0][c][i0 + 2] = (_Float16)wv.z; Ws16[0][c][i0 + 3] = (_Float16)wv.w;
      }
    }
    __syncthreads();
#pragma unroll
    for (int tap = 0; tap < NTAPS; tap++) {
#pragma unroll
      for (int ks = 0; ks < 4; ks++) {
        const int k0 = ks * 16 + q * 8;
        const f16x8 a = *reinterpret_cast<const f16x8*>(&Ws16[tap][wm * 32 + l31][k0]);
        const int row0 = wn * 64 + l31 + tap * d;
        const f16x8 b0 = *reinterpret_cast<const f16x8*>(&Xs16[row0][k0]);
        acc0 = __builtin_amdgcn_mfma_f32_32x32x16_f16(a, b0, acc0, 0, 0, 0);
        const f16x8 b1 = *reinterpret_cast<const f16x8*>(&Xs16[row0 + 32][k0]);
        acc1 = __builtin_amdgcn_mfma_f32_32x32x16_f16(a, b1, acc1, 0, 0, 0);
      }
    }
  }
  // epilogue: D layout col=l&31, row=(r&3)+8*(r>>2)+4*(l>>5)
#pragma unroll
  for (int r = 0; r < 16; r++) {
    const int m = wm * 32 + (r & 3) + 8 * (r >> 2) + 4 * q;
    const int c = c0 + m;
    const float bb = bias[c];
    {
      const int t = t0 + wn * 64 + l31;
      float v = acc0[r] + bb;
      if (RES) v += Res[(size_t)c * TT + t];
      if (RELU) v = fmaxf(v, 0.f);
      Y[(size_t)c * TT + t] = v;
    }
    {
      const int t = t0 + wn * 64 + 32 + l31;
      float v = acc1[r] + bb;
      if (RES) v += Res[(size_t)c * TT + t];
      if (RELU) v = fmaxf(v, 0.f);
      Y[(size_t)c * TT + t] = v;
    }
  }
}

// -------------------- tiled transpose (512,T) -> out (T,512) + f32 copy (T,512)
__launch_bounds__(256)
__global__ void temit_k(const float* __restrict__ Xin, float* __restrict__ outp,
                        float* __restrict__ Aout) {
  __shared__ float tile[32][33];
  const int t0 = blockIdx.x * 32, d0 = blockIdx.y * 32;
  const int lx = threadIdx.x & 31, ly = threadIdx.x >> 5;
#pragma unroll
  for (int r = 0; r < 4; r++)
    tile[ly + 8 * r][lx] = Xin[(size_t)(d0 + ly + 8 * r) * TT + t0 + lx];
  __syncthreads();
#pragma unroll
  for (int r = 0; r < 4; r++) {
    const int t = t0 + ly + 8 * r, dd = d0 + lx;
    const float v = tile[lx][ly + 8 * r];
    outp[(size_t)t * 512 + dd] = v;
    Aout[(size_t)t * 512 + dd] = v;
  }
}

// ---------------------------------------------------------------- cosine sim
__global__ void nsim_k(const float* __restrict__ V, const float* __restrict__ text,
                       const float* __restrict__ tnorm, float* __restrict__ out, int R) {
  int idx = blockIdx.x * 256 + threadIdx.x;  // r*32 + c
  if (idx >= R * 32) return;
  int r = idx >> 5, c = idx & 31;
  const float* vr = V + (size_t)r * 512;
  float ss = 0.f, dot = 0.f;
  for (int dd = 0; dd < 512; dd++) {
    float v = vr[dd];
    ss += v * v;
    dot += v * text[(size_t)c * 512 + dd];
  }
  out[idx] = dot / (sqrtf(ss) * tnorm[c]);
}

// ======================================================================= host
extern "C" void kernel_launch(void* const* d_in, const int* in_sizes, int n_in,
                              void* d_out, int out_size, void* d_ws, size_t ws_size,
                              hipStream_t stream) {
  const float* in_ff   = (const float*)d_in[0];
  const float* in_act  = (const float*)d_in[1];
  const float* in_fpos = (const float*)d_in[2];
  const float* in_apos = (const float*)d_in[3];
  const float* in_text = (const float*)d_in[4];
  const float* Wf2c = (const float*)d_in[5];  const float* bf2c = (const float*)d_in[6];
  const float* Wa2c = (const float*)d_in[7];  const float* ba2c = (const float*)d_in[8];
  const float* Ws2c = (const float*)d_in[9];  const float* bs2c = (const float*)d_in[10];
  const float* Wih_f = (const float*)d_in[11]; const float* Whh_f = (const float*)d_in[12];
  const float* bih_f = (const float*)d_in[13]; const float* bhh_f = (const float*)d_in[14];
  const float* Wih_b = (const float*)d_in[15]; const float* Whh_b = (const float*)d_in[16];
  const float* bih_b = (const float*)d_in[17]; const float* bhh_b = (const float*)d_in[18];
  const float* Wcomb = (const float*)d_in[19]; const float* bcomb = (const float*)d_in[20];
  const float* f2a_Wq = (const float*)d_in[21]; const float* f2a_Wk = (const float*)d_in[22];
  const float* f2a_Wv = (const float*)d_in[23]; const float* f2a_Wo = (const float*)d_in[24];
  const float* f2a_bo = (const float*)d_in[25];
  const float* ag_Wih = (const float*)d_in[26]; const float* ag_Whh = (const float*)d_in[27];
  const float* ag_bih = (const float*)d_in[28]; const float* ag_bhh = (const float*)d_in[29];
  const float* a2f_Wq = (const float*)d_in[30]; const float* a2f_Wk = (const float*)d_in[31];
  const float* a2f_Wv = (const float*)d_in[32]; const float* a2f_Wo = (const float*)d_in[33];
  const float* a2f_bo = (const float*)d_in[34];
  const float* Wsf = (const float*)d_in[35]; const float* bsf = (const float*)d_in[36];
  const float* tcn_inW = (const float*)d_in[37]; const float* tcn_inb = (const float*)d_in[38];
  const float* tcn_dW = (const float*)d_in[39]; const float* tcn_db = (const float*)d_in[40];
  const float* tcn_pW = (const float*)d_in[41]; const float* tcn_pb = (const float*)d_in[42];
  const float* tcn_outW = (const float*)d_in[43]; const float* tcn_outb = (const float*)d_in[44];

  int S = (out_size - (TT * DD + MM * DD + TT * CC + MM * CC)) / CC;
  if (S < 1) S = 1;
  if (S > TT) S = TT;

  // ---------------- workspace layout
  char* ws = (char*)d_ws;
  size_t off = 0;
  auto alloc = [&](size_t b) -> char* { char* p = ws + off; off += (b + 255) & ~(size_t)255; return p; };
  const size_t BTD = (size_t)TT * DD * 4;
  float* bufA = (float*)alloc(BTD);
  float* bufB = (float*)alloc(BTD);
  int* pred    = (int*)alloc((size_t)TT * 4);
  int* segid   = (int*)alloc((size_t)TT * 4);
  int* starts  = (int*)alloc((size_t)TT * 4);
  int* centers = (int*)alloc((size_t)TT * 4);
  int* cnts    = (int*)alloc((size_t)TT * 4);
  int* cntF    = (int*)alloc((size_t)TT * CNT_STRIDE * 4);
  int* cntB    = (int*)alloc((size_t)TT * CNT_STRIDE * 4);
  int* cntA    = (int*)alloc((size_t)256 * CNT_STRIDE * 4);
  float* tnorm = (float*)alloc(32 * 4);
  float* segmean = (float*)alloc((size_t)S * 512 * 4);
  float* gif  = (float*)alloc((size_t)S * 768 * 4);
  float* gib  = (float*)alloc((size_t)S * 768 * 4);
  float* hfb  = (float*)alloc((size_t)S * 256 * 4);
  float* hbb  = (float*)alloc((size_t)S * 256 * 4);
  float* acmb = (float*)alloc((size_t)S * 512 * 4);
  float* segc = (float*)alloc((size_t)S * 512 * 4);
  float* segpos = (float*)alloc((size_t)S * 512 * 4);
  float* kin  = (float*)alloc((size_t)S * 512 * 4);
  float* kf2a = (float*)alloc((size_t)S * 512 * 4);
  float* vf2a = (float*)alloc((size_t)S * 512 * 4);
  float* q2   = (float*)alloc((size_t)S * 512 * 4);
  float* att2 = (float*)alloc((size_t)S * 512 * 4);
  float* seg2 = (float*)alloc((size_t)S * 512 * 4);
  float* vseg = (float*)alloc((size_t)S * 512 * 4);
  float* pbuf = (float*)alloc((size_t)64 * S * 4);
  float* qin  = (float*)alloc((size_t)64 * 512 * 4);
  float* qf2a = (float*)alloc((size_t)64 * 512 * 4);
  float* att1 = (float*)alloc((size_t)64 * 512 * 4);
  float* af0  = (float*)alloc((size_t)64 * 512 * 4);
  float* aggi = (float*)alloc((size_t)64 * 1536 * 4);
  float* afg  = (float*)alloc((size_t)64 * 512 * 4);
  float* k2in = (float*)alloc((size_t)64 * 512 * 4);
  float* k2   = (float*)alloc((size_t)64 * 512 * 4);
  float* v2   = (float*)alloc((size_t)64 * 512 * 4);
  float* vaf  = (float*)alloc((size_t)64 * 512 * 4);
  (void)ws_size; (void)in_sizes; (void)n_in;

  float* outp = (float*)d_out;
  float* out_ff   = outp;
  float* out_af   = outp + (size_t)TT * DD;
  float* out_fsim = out_af + (size_t)MM * DD;
  float* out_asim = out_fsim + (size_t)TT * CC;
  float* out_ssim = out_asim + (size_t)MM * CC;

  auto GR = [](long n) { return (unsigned)((n + 255) / 256); };

  // zero ws (incl. barrier counters -> 0, mandatory every launch)
  zero_k<<<2048, 256, 0, stream>>>((float*)d_ws, (long)(off / 4));

  tnorm_k<<<1, 256, 0, stream>>>(in_text, tnorm);

  // segmentation (tiled GEMM for the T-sized projection)
  gemm_k<<<dim3(8, 128), 256, 0, stream>>>(in_ff, Wf2c, bf2c, bufA, TT, 512, 512);
  argmax_k<<<TT, 256, 0, stream>>>(bufA, in_text, tnorm, pred);
  segscan_k<<<1, 256, 0, stream>>>(pred, segid, starts, centers, cnts);
  segmean_k<<<GR((long)S * 512), 256, 0, stream>>>(in_ff, starts, cnts, segmean, S);

  // seg BiGRU (multi-block LDS-resident scan)
  ngemm_k<<<GR((long)S * 768), 256, 0, stream>>>(segmean, Wih_f, bih_f, gif, S, 768, 512);
  ngemm_k<<<GR((long)S * 768), 256, 0, stream>>>(segmean, Wih_b, bih_b, gib, S, 768, 512);
  gru_seg_mb_k<<<8, 192, 0, stream>>>(gif, gib, Whh_f, bhh_f, Whh_b, bhh_b,
                                      hfb, hbb, S, cntF, cntB);
  acomb_k<<<GR((long)S * 512), 256, 0, stream>>>(hfb, hbb, acmb, S * 512);
  ngemm_k<<<GR((long)S * 512), 256, 0, stream>>>(acmb, Wcomb, bcomb, segc, S, 512, 512);
  gatherpos_k<<<GR((long)S * 512), 256, 0, stream>>>(in_fpos, centers, segpos, S * 512);

  // f2a attention (actions query segments)
  addff_k<<<GR(64 * 512), 256, 0, stream>>>(in_act, in_apos, qin, 64 * 512);
  addff_k<<<GR((long)S * 512), 256, 0, stream>>>(segc, segpos, kin, S * 512);
  ngemm_k<<<GR(64 * 512), 256, 0, stream>>>(qin, f2a_Wq, nullptr, qf2a, 64, 512, 512);
  ngemm_k<<<GR((long)S * 512), 256, 0, stream>>>(kin, f2a_Wk, nullptr, kf2a, S, 512, 512);
  ngemm_k<<<GR((long)S * 512), 256, 0, stream>>>(segc, f2a_Wv, nullptr, vf2a, S, 512, 512);
  nlogit_k<<<GR((long)64 * S), 256, 0, stream>>>(qf2a, kf2a, pbuf, 64, S);
  nsoft_k<<<1, 256, 0, stream>>>(pbuf, 64, S);
  nav_k<<<GR(64 * 512), 256, 0, stream>>>(pbuf, vf2a, att1, 64, S);
  ngemm_k<<<GR(64 * 512), 256, 0, stream>>>(att1, f2a_Wo, f2a_bo, af0, 64, 512, 512);

  // action GRU (multi-block LDS-resident scan)
  ngemm_k<<<GR(64 * 1536), 256, 0, stream>>>(af0, ag_Wih, ag_bih, aggi, 64, 1536, 512);
  gru_act_mb_k<<<16, 128, 0, stream>>>(aggi, ag_Whh, ag_bhh, afg, MM, cntA);
  copy_k<<<GR(64 * 512), 256, 0, stream>>>(afg, out_af, 64 * 512);

  // a2f attention (segments query actions)
  addff_k<<<GR(64 * 512), 256, 0, stream>>>(afg, in_apos, k2in, 64 * 512);
  ngemm_k<<<GR((long)S * 512), 256, 0, stream>>>(kin, a2f_Wq, nullptr, q2, S, 512, 512);
  ngemm_k<<<GR(64 * 512), 256, 0, stream>>>(k2in, a2f_Wk, nullptr, k2, 64, 512, 512);
  ngemm_k<<<GR(64 * 512), 256, 0, stream>>>(afg, a2f_Wv, nullptr, v2, 64, 512, 512);
  nlogit_k<<<GR((long)S * 64), 256, 0, stream>>>(q2, k2, pbuf, S, 64);
  nsoft_k<<<GR(S), 256, 0, stream>>>(pbuf, S, 64);
  nav_k<<<GR((long)S * 512), 256, 0, stream>>>(pbuf, v2, att2, S, 64);
  ngemm_k<<<GR((long)S * 512), 256, 0, stream>>>(att2, a2f_Wo, a2f_bo, seg2, S, 512, 512);

  // frame fusion + TCN (MFMA convs), ping-pong bufA <-> bufB as (D,T)
  ff2_k<<<dim3(128, 8), 256, 0, stream>>>(seg2, in_ff, segid, Wsf, bsf, bufA, S);
  convm_k<1, 0, 0><<<dim3(64, 8), 256, 0, stream>>>(bufA, tcn_inW, tcn_inb, nullptr, bufB, 1);
  for (int l = 0; l < 6; l++) {
    convm_k<3, 1, 0><<<dim3(64, 8), 256, 0, stream>>>(
        bufB, tcn_dW + (size_t)l * 512 * 512 * 3, tcn_db + (size_t)l * 512, nullptr, bufA, 1 << l);
    convm_k<1, 0, 1><<<dim3(64, 8), 256, 0, stream>>>(
        bufA, tcn_pW + (size_t)l * 512 * 512, tcn_pb + (size_t)l * 512, bufB, bufB, 1);
  }
  convm_k<1, 0, 0><<<dim3(64, 8), 256, 0, stream>>>(bufB, tcn_outW, tcn_outb, nullptr, bufA, 1);
  temit_k<<<dim3(256, 16), 256, 0, stream>>>(bufA, out_ff, bufB);

  // similarity heads (tiled GEMM for the T-sized projection)
  gemm_k<<<dim3(8, 128), 256, 0, stream>>>(bufB, Wf2c, bf2c, bufA, TT, 512, 512);
  nsim_k<<<GR((long)TT * 32), 256, 0, stream>>>(bufA, in_text, tnorm, out_fsim, TT);
  ngemm_k<<<GR(64 * 512), 256, 0, stream>>>(afg, Wa2c, ba2c, vaf, 64, 512, 512);
  nsim_k<<<GR(64 * 32), 256, 0, stream>>>(vaf, in_text, tnorm, out_asim, 64);
  ngemm_k<<<GR((long)S * 512), 256, 0, stream>>>(seg2, Ws2c, bs2c, vseg, S, 512, 512);
  nsim_k<<<GR((long)S * 32), 256, 0, stream>>>(vseg, in_text, tnorm, out_ssim, S);
}

// Round 11
// 5011.636 us; speedup vs baseline: 3.2863x; 1.4347x over previous
//
#include <hip/hip_runtime.h>
#include <cstdint>
#include <cstddef>

__device__ __forceinline__ float sigf(float x) { return 1.f / (1.f + expf(-x)); }

// fp16 pack/unpack helpers (weights-only precision reduction)
__device__ __forceinline__ unsigned packh(float a, float b) {
  union { unsigned u; _Float16 h[2]; } cv;
  cv.h[0] = (_Float16)a; cv.h[1] = (_Float16)b; return cv.u;
}
__device__ __forceinline__ float2 uph(unsigned u) {
  union { unsigned uu; _Float16 h[2]; } cv; cv.uu = u;
  return make_float2((float)cv.h[0], (float)cv.h[1]);
}

typedef _Float16 f16x8 __attribute__((ext_vector_type(8)));
typedef float f32x16 __attribute__((ext_vector_type(16)));

static constexpr int TT = 8192;   // frames
static constexpr int MM = 64;     // actions
static constexpr int CC = 32;     // classes
static constexpr int DD = 512;    // model dim
static constexpr unsigned GUARD_MAX = 1u << 30;

// ---------------------------------------------------------------- ws zeroing
__global__ void zero_k(float* __restrict__ p, long n) {
  long i = (long)blockIdx.x * 256 + threadIdx.x;
  long stride = (long)gridDim.x * 256;
  for (; i < n; i += stride) p[i] = 0.f;
}

// ---------------------------------------------------------------- elementwise
__global__ void copy_k(const float* __restrict__ a, float* __restrict__ o, int n) {
  int i = blockIdx.x * 256 + threadIdx.x;
  if (i < n) o[i] = a[i];
}
__global__ void addff_k(const float* __restrict__ a, const float* __restrict__ b, float* __restrict__ o, int n) {
  int i = blockIdx.x * 256 + threadIdx.x;
  if (i < n) o[i] = a[i] + b[i];
}
__global__ void acomb_k(const float* __restrict__ hf, const float* __restrict__ hb, float* __restrict__ o, int n) {
  int i = blockIdx.x * 256 + threadIdx.x;
  if (i >= n) return;
  int s = i >> 9, j = i & 511;
  float v = (j < 256) ? hf[(size_t)s * 256 + j] : hb[(size_t)s * 256 + (j - 256)];
  o[i] = fmaxf(v, 0.f);
}
__global__ void gatherpos_k(const float* __restrict__ fpos, const int* __restrict__ centers,
                            float* __restrict__ segpos, int n) {
  int i = blockIdx.x * 256 + threadIdx.x;
  if (i >= n) return;
  int s = i >> 9, dd = i & 511;
  int ct = centers[s];
  ct = ct < 0 ? 0 : (ct > TT - 1 ? TT - 1 : ct);
  segpos[i] = fpos[(size_t)ct * 512 + dd];
}

// ---------------------------------------------------------------- text norms
__global__ void tnorm_k(const float* __restrict__ text, float* __restrict__ tnorm) {
  int c = blockIdx.x * 256 + threadIdx.x;
  if (c >= 32) return;
  float s = 0.f;
  for (int dd = 0; dd < 512; dd++) { float v = text[(size_t)c * 512 + dd]; s += v * v; }
  tnorm[c] = sqrtf(s);
}

// ---------------------------------------------------- naive attention pieces
__global__ void nlogit_k(const float* __restrict__ Q, const float* __restrict__ Kk,
                         float* __restrict__ L, int NY, int NX) {
  int idx = blockIdx.x * 256 + threadIdx.x;
  if (idx >= NY * NX) return;
  int y = idx / NX, x = idx - y * NX;
  const float* qr = Q + (size_t)y * 512;
  const float* kr = Kk + (size_t)x * 512;
  float d = 0.f;
  for (int k = 0; k < 512; k++) d += qr[k] * kr[k];
  L[idx] = d * 0.044194173824159216f;  // 1/sqrt(512)
}
__global__ void nsoft_k(float* __restrict__ L, int NY, int NX) {  // 1 thread / row
  int y = blockIdx.x * 256 + threadIdx.x;
  if (y >= NY) return;
  float* row = L + (size_t)y * NX;
  float m = row[0];
  for (int x = 1; x < NX; x++) m = fmaxf(m, row[x]);
  float s = 0.f;
  for (int x = 0; x < NX; x++) { float p = expf(row[x] - m); row[x] = p; s += p; }
  const float inv = 1.f / s;
  for (int x = 0; x < NX; x++) row[x] *= inv;
}
__global__ void nav_k(const float* __restrict__ P, const float* __restrict__ V,
                      float* __restrict__ O, int NY, int NX) {
  int idx = blockIdx.x * 256 + threadIdx.x;
  if (idx >= NY * 512) return;
  int y = idx >> 9, dd = idx & 511;
  const float* pr = P + (size_t)y * NX;
  float o = 0.f;
  for (int x = 0; x < NX; x++) o += pr[x] * V[(size_t)x * 512 + dd];
  O[idx] = o;
}

// ------------------------------------------ argmax over classes: block per row
__global__ void argmax_k(const float* __restrict__ V, const float* __restrict__ text,
                         const float* __restrict__ tnorm, int* __restrict__ pred) {
  __shared__ float vs[512];
  __shared__ float dots[32];
  const int r = blockIdx.x, tid = threadIdx.x;
  for (int dd = tid; dd < 512; dd += 256) vs[dd] = V[(size_t)r * 512 + dd];
  __syncthreads();
  if (tid < 32) {
    float dot = 0.f;
    const float* tr = text + (size_t)tid * 512;
    for (int dd = 0; dd < 512; dd++) dot += vs[dd] * tr[dd];
    dots[tid] = dot / tnorm[tid];
  }
  __syncthreads();
  if (tid == 0) {
    int best = 0; float bv = dots[0];
    for (int c = 1; c < 32; c++) if (dots[c] > bv) { bv = dots[c]; best = c; }
    pred[r] = best;
  }
}

// ------------------------------- parallel run-length segmentation (one block)
__global__ void segscan_k(const int* __restrict__ pred, int* __restrict__ segid,
                          int* __restrict__ starts, int* __restrict__ centers,
                          int* __restrict__ cnts) {
  __shared__ int base[256];
  __shared__ int SS;
  const int tid = threadIdx.x;
  int lc = 0;
  unsigned flags = 0;
  int prev = (tid > 0) ? pred[tid * 32 - 1] : 0;
  for (int i = 0; i < 32; i++) {
    const int t = tid * 32 + i;
    const int cur = pred[t];
    const int c = (t > 0) && (cur != prev);
    prev = cur;
    flags |= ((unsigned)c) << i;
    lc += c;
  }
  base[tid] = lc;
  __syncthreads();
  if (tid == 0) {
    int run = 0;
    for (int i = 0; i < 256; i++) { const int v = base[i]; base[i] = run; run += v; }
    SS = run + 1;
  }
  __syncthreads();
  int b = base[tid];
  for (int i = 0; i < 32; i++) {
    const int t = tid * 32 + i;
    if ((flags >> i) & 1u) { b++; starts[b] = t; }
    segid[t] = b;
  }
  if (tid == 0) starts[0] = 0;
  __threadfence_block();
  __syncthreads();
  const int S = SS;
  for (int s = tid; s < TT; s += 256) {
    if (s < S) {
      const int e = (s == S - 1) ? (TT - 1) : (starts[s + 1] - 1);
      centers[s] = (starts[s] + e) >> 1;
      cnts[s] = e - starts[s] + 1;
    } else {
      starts[s] = 0; cnts[s] = 1; centers[s] = 0;
    }
  }
}

// ---------------------------------------------------------- segment mean pool
__global__ void segmean_k(const float* __restrict__ ff, const int* __restrict__ starts,
                          const int* __restrict__ cnts, float* __restrict__ segmean, int S) {
  int idx = blockIdx.x * 256 + threadIdx.x;
  if (idx >= S * 512) return;
  int s = idx >> 9, dd = idx & 511;
  int st = starts[s], n = cnts[s];
  st = st < 0 ? 0 : (st > TT - 1 ? TT - 1 : st);
  n = n < 1 ? 1 : n;
  if (st + n > TT) n = TT - st;
  float a = 0.f;
  for (int t = st; t < st + n; t++) a += ff[(size_t)t * 512 + dd];
  segmean[idx] = a / (float)n;
}

// ------------------- multi-block bidirectional seg GRU (H=256), LDS weights
// 8 blocks: dir = blk>>2, part = blk&3 owns h-indices [part*64, part*64+64).
// Per-step per-part flag barrier; weights packed for ds_read_b128.
__launch_bounds__(192)
__global__ void gru_seg_mb_k(const float* __restrict__ gi_f, const float* __restrict__ gi_b,
                             const float* __restrict__ Whh_f, const float* __restrict__ bhh_f,
                             const float* __restrict__ Whh_b, const float* __restrict__ bhh_b,
                             float* __restrict__ hf, float* __restrict__ hb, int S,
                             int* __restrict__ flag_f, int* __restrict__ flag_b) {
  const int dir = blockIdx.x >> 2;
  const int part = blockIdx.x & 3;
  const float* gi = dir ? gi_b : gi_f;
  const float* Whh = dir ? Whh_b : Whh_f;
  const float* bhh = dir ? bhh_b : bhh_f;
  float* ho = dir ? hb : hf;
  int* flg = dir ? flag_b : flag_f;
  const int tid = threadIdx.x;
  const int h0 = part * 64;
  const int grp = tid >> 6;
  const int jj = tid & 63;
  const int j = grp * 256 + h0 + jj;
  // layout: wlds[q*768 + g*4 + r] = pair (i2 = 4q + r) for gate g -> uint4 per (q,g)
  __shared__ __align__(16) unsigned wlds[128 * 192];
  __shared__ __align__(16) unsigned hpk[128];
  __shared__ float hcur[256];
  __shared__ float rbuf[64], zbuf[64], gnbuf[64];
  for (int e = tid; e < 128 * 192; e += 192) {
    const int q = e / 768, rem = e % 768;
    const int g = rem >> 2, r = rem & 3;
    const int i2 = q * 4 + r;
    const int gg = (g >> 6) * 256 + h0 + (g & 63);
    wlds[e] = packh(Whh[(size_t)(2 * i2) * 768 + gg], Whh[(size_t)(2 * i2 + 1) * 768 + gg]);
  }
  for (int e = tid; e < 128; e += 192) hpk[e] = 0u;
  for (int e = tid; e < 256; e += 192) hcur[e] = 0.f;
  const float bj = bhh[j];
  __syncthreads();
  const uint4* hp4 = reinterpret_cast<const uint4*>(hpk);
  const uint4* wp4 = reinterpret_cast<const uint4*>(wlds);
  for (int step = 0; step < S; step++) {
    const int s = dir ? (S - 1 - step) : step;
    float a0 = 0.f, a1 = 0.f, a2 = 0.f, a3 = 0.f;
#pragma unroll 8
    for (int q = 0; q < 32; q++) {
      const uint4 h4 = hp4[q];
      const uint4 w4 = wp4[q * 192 + tid];
      const float2 hh0 = uph(h4.x), hh1 = uph(h4.y), hh2 = uph(h4.z), hh3 = uph(h4.w);
      const float2 ww0 = uph(w4.x), ww1 = uph(w4.y), ww2 = uph(w4.z), ww3 = uph(w4.w);
      a0 += hh0.x * ww0.x + hh0.y * ww0.y;
      a1 += hh1.x * ww1.x + hh1.y * ww1.y;
      a2 += hh2.x * ww2.x + hh2.y * ww2.y;
      a3 += hh3.x * ww3.x + hh3.y * ww3.y;
    }
    const float gh = bj + (a0 + a1) + (a2 + a3);
    if (grp == 0)      rbuf[jj] = sigf(gi[(size_t)s * 768 + j] + gh);
    else if (grp == 1) zbuf[jj] = sigf(gi[(size_t)s * 768 + j] + gh);
    else               gnbuf[jj] = gh;
    __syncthreads();
    if (tid < 64) {
      const float ginv = gi[(size_t)s * 768 + 512 + h0 + tid];
      const float nval = tanhf(ginv + rbuf[tid] * gnbuf[tid]);
      const float hn = (1.f - zbuf[tid]) * nval + zbuf[tid] * hcur[h0 + tid];
      __hip_atomic_store(&ho[(size_t)s * 256 + h0 + tid], hn,
                         __ATOMIC_RELAXED, __HIP_MEMORY_SCOPE_AGENT);
    }
    __syncthreads();
    if (tid == 0)
      __hip_atomic_store(&flg[step * 64 + part * 16], 1,
                         __ATOMIC_RELEASE, __HIP_MEMORY_SCOPE_AGENT);
    if (tid < 4) {
      int* fp = &flg[step * 64 + tid * 16];
      unsigned guard = 0;
      while (__hip_atomic_load(fp, __ATOMIC_RELAXED, __HIP_MEMORY_SCOPE_AGENT) == 0 &&
             ++guard < GUARD_MAX) {
        __builtin_amdgcn_s_sleep(2);
      }
      (void)__hip_atomic_load(fp, __ATOMIC_ACQUIRE, __HIP_MEMORY_SCOPE_AGENT);
    }
    __syncthreads();
    for (int e = tid; e < 256; e += 192)
      hcur[e] = __hip_atomic_load(&ho[(size_t)s * 256 + e],
                                  __ATOMIC_RELAXED, __HIP_MEMORY_SCOPE_AGENT);
    __syncthreads();
    for (int e = tid; e < 128; e += 192) hpk[e] = packh(hcur[2 * e], hcur[2 * e + 1]);
    __syncthreads();
  }
}

// ------------------------- multi-block action GRU (H=512), LDS weights
// 16 blocks, block b owns h-indices [b*32, b*32+32).
__launch_bounds__(128)
__global__ void gru_act_mb_k(const float* __restrict__ gi, const float* __restrict__ Whh,
                             const float* __restrict__ bhh, float* __restrict__ hout,
                             int steps, int* __restrict__ flg) {
  const int part = blockIdx.x;
  const int tid = threadIdx.x;
  const int h0 = part * 32;
  const int grp = tid >> 5;
  const int jj = tid & 31;
  const bool act = (tid < 96);
  const int j = act ? (grp * 512 + h0 + jj) : 0;
  // layout: wlds[q*384 + g*4 + r], q = i2>>2 in [0,64), g in [0,96)
  __shared__ __align__(16) unsigned wlds[256 * 96];
  __shared__ __align__(16) unsigned hpk[256];
  __shared__ float hcur[512];
  __shared__ float rbuf[32], zbuf[32], gnbuf[32];
  for (int e = tid; e < 256 * 96; e += 128) {
    const int q = e / 384, rem = e % 384;
    const int g = rem >> 2, r = rem & 3;
    const int i2 = q * 4 + r;
    const int gg = (g >> 5) * 512 + h0 + (g & 31);
    wlds[e] = packh(Whh[(size_t)(2 * i2) * 1536 + gg], Whh[(size_t)(2 * i2 + 1) * 1536 + gg]);
  }
  for (int e = tid; e < 256; e += 128) hpk[e] = 0u;
  for (int e = tid; e < 512; e += 128) hcur[e] = 0.f;
  const float bj = act ? bhh[j] : 0.f;
  __syncthreads();
  const uint4* hp4 = reinterpret_cast<const uint4*>(hpk);
  const uint4* wp4 = reinterpret_cast<const uint4*>(wlds);
  for (int step = 0; step < steps; step++) {
    if (act) {
      float a0 = 0.f, a1 = 0.f, a2 = 0.f, a3 = 0.f;
#pragma unroll 8
      for (int q = 0; q < 64; q++) {
        const uint4 h4 = hp4[q];
        const uint4 w4 = wp4[q * 96 + tid];
        const float2 hh0 = uph(h4.x), hh1 = uph(h4.y), hh2 = uph(h4.z), hh3 = uph(h4.w);
        const float2 ww0 = uph(w4.x), ww1 = uph(w4.y), ww2 = uph(w4.z), ww3 = uph(w4.w);
        a0 += hh0.x * ww0.x + hh0.y * ww0.y;
        a1 += hh1.x * ww1.x + hh1.y * ww1.y;
        a2 += hh2.x * ww2.x + hh2.y * ww2.y;
        a3 += hh3.x * ww3.x + hh3.y * ww3.y;
      }
      const float gh = bj + (a0 + a1) + (a2 + a3);
      if (grp == 0)      rbuf[jj] = sigf(gi[(size_t)step * 1536 + j] + gh);
      else if (grp == 1) zbuf[jj] = sigf(gi[(size_t)step * 1536 + j] + gh);
      else               gnbuf[jj] = gh;
    }
    __syncthreads();
    if (tid < 32) {
      const float ginv = gi[(size_t)step * 1536 + 1024 + h0 + tid];
      const float nval = tanhf(ginv + rbuf[tid] * gnbuf[tid]);
      const float hn = (1.f - zbuf[tid]) * nval + zbuf[tid] * hcur[h0 + tid];
      __hip_atomic_store(&hout[(size_t)step * 512 + h0 + tid], hn,
                         __ATOMIC_RELAXED, __HIP_MEMORY_SCOPE_AGENT);
    }
    __syncthreads();
    if (tid == 0)
      __hip_atomic_store(&flg[step * 256 + part * 16], 1,
                         __ATOMIC_RELEASE, __HIP_MEMORY_SCOPE_AGENT);
    if (tid < 16) {
      int* fp = &flg[step * 256 + tid * 16];
      unsigned guard = 0;
      while (__hip_atomic_load(fp, __ATOMIC_RELAXED, __HIP_MEMORY_SCOPE_AGENT) == 0 &&
             ++guard < GUARD_MAX) {
        __builtin_amdgcn_s_sleep(2);
      }
      (void)__hip_atomic_load(fp, __ATOMIC_ACQUIRE, __HIP_MEMORY_SCOPE_AGENT);
    }
    __syncthreads();
    for (int e = tid; e < 512; e += 128)
      hcur[e] = __hip_atomic_load(&hout[(size_t)step * 512 + e],
                                  __ATOMIC_RELAXED, __HIP_MEMORY_SCOPE_AGENT);
    __syncthreads();
    for (int e = tid; e < 256; e += 128) hpk[e] = packh(hcur[2 * e], hcur[2 * e + 1]);
    __syncthreads();
  }
}

// ------------------------------------------------------------ tiled GEMM
// C[M,N] = A[M,K] @ B[K,N] + bias   (M,N multiples of 64 ONLY)
__launch_bounds__(256)
__global__ void gemm_k(const float* __restrict__ A, const float* __restrict__ B,
                       const float* __restrict__ bias, float* __restrict__ C,
                       int M, int N, int K) {
  __shared__ float As[16][64];
  __shared__ float Bs[16][64];
  const int tid = threadIdx.x;
  const int n0 = blockIdx.x * 64, m0 = blockIdx.y * 64;
  const int tx = tid & 15, ty = tid >> 4;
  const int am = tid >> 2, ak = (tid & 3) << 2;
  const int bk = tid >> 4, bn = (tid & 15) << 2;
  float acc[4][4] = {};
  for (int k0 = 0; k0 < K; k0 += 16) {
    const float4 av = *reinterpret_cast<const float4*>(A + (size_t)(m0 + am) * K + k0 + ak);
    As[ak + 0][am] = av.x; As[ak + 1][am] = av.y; As[ak + 2][am] = av.z; As[ak + 3][am] = av.w;
    const float4 bv = *reinterpret_cast<const float4*>(B + (size_t)(k0 + bk) * N + n0 + bn);
    Bs[bk][bn + 0] = bv.x; Bs[bk][bn + 1] = bv.y; Bs[bk][bn + 2] = bv.z; Bs[bk][bn + 3] = bv.w;
    __syncthreads();
#pragma unroll
    for (int i = 0; i < 16; i++) {
      const float4 a4 = *reinterpret_cast<const float4*>(&As[i][ty * 4]);
      const float4 b4 = *reinterpret_cast<const float4*>(&Bs[i][tx * 4]);
      const float aa[4] = {a4.x, a4.y, a4.z, a4.w};
      const float bb[4] = {b4.x, b4.y, b4.z, b4.w};
#pragma unroll
      for (int x = 0; x < 4; x++)
#pragma unroll
        for (int y = 0; y < 4; y++) acc[x][y] += aa[x] * bb[y];
    }
    __syncthreads();
  }
#pragma unroll
  for (int x = 0; x < 4; x++) {
    const int m = m0 + ty * 4 + x;
#pragma unroll
    for (int y = 0; y < 4; y++) {
      const int n = n0 + tx * 4 + y;
      float v = acc[x][y];
      if (bias) v += bias[n];
      C[(size_t)m * N + n] = v;
    }
  }
}

// ---------------------------- ff2 = relu([seg2[seg_id[t]], ff[t]] @ Wsf + bsf)
// writes TRANSPOSED (D, T) for the TCN.  K=1024.
__launch_bounds__(256)
__global__ void ff2_k(const float* __restrict__ seg2, const float* __restrict__ ff,
                      const int* __restrict__ segid, const float* __restrict__ Wsf,
                      const float* __restrict__ bsf, float* __restrict__ Y, int S) {
  __shared__ float As[16][64];  // [k][m]  m = frame
  __shared__ float Bs[16][64];  // [k][n]  n = out dim
  const int tid = threadIdx.x;
  const int m0 = blockIdx.x * 64;  // frames
  const int n0 = blockIdx.y * 64;  // dims
  const int tx = tid & 15, ty = tid >> 4;
  const int am = tid >> 2, ak = (tid & 3) << 2;
  const int bk = tid >> 4, bn = (tid & 15) << 2;
  const int t = m0 + am;
  int sid = segid[t];
  sid = sid < 0 ? 0 : (sid >= S ? S - 1 : sid);
  float acc[4][4] = {};  // [n][m]
  for (int k0 = 0; k0 < 1024; k0 += 16) {
    const float* src = (k0 + ak < 512) ? (seg2 + (size_t)sid * 512 + k0 + ak)
                                       : (ff + (size_t)t * 512 + (k0 + ak - 512));
    const float4 av = *reinterpret_cast<const float4*>(src);
    As[ak + 0][am] = av.x; As[ak + 1][am] = av.y; As[ak + 2][am] = av.z; As[ak + 3][am] = av.w;
    const float4 bv = *reinterpret_cast<const float4*>(Wsf + (size_t)(k0 + bk) * 512 + n0 + bn);
    Bs[bk][bn + 0] = bv.x; Bs[bk][bn + 1] = bv.y; Bs[bk][bn + 2] = bv.z; Bs[bk][bn + 3] = bv.w;
    __syncthreads();
#pragma unroll
    for (int i = 0; i < 16; i++) {
      const float4 a4 = *reinterpret_cast<const float4*>(&As[i][tx * 4]);
      const float4 b4 = *reinterpret_cast<const float4*>(&Bs[i][ty * 4]);
      const float aa[4] = {a4.x, a4.y, a4.z, a4.w};
      const float bb[4] = {b4.x, b4.y, b4.z, b4.w};
#pragma unroll
      for (int yy = 0; yy < 4; yy++)
#pragma unroll
        for (int xx = 0; xx < 4; xx++) acc[yy][xx] += bb[yy] * aa[xx];
    }
    __syncthreads();
  }
#pragma unroll
  for (int yy = 0; yy < 4; yy++) {
    const int n = n0 + ty * 4 + yy;
    const float bb = bsf[n];
    float4 o;
    o.x = fmaxf(acc[yy][0] + bb, 0.f);
    o.y = fmaxf(acc[yy][1] + bb, 0.f);
    o.z = fmaxf(acc[yy][2] + bb, 0.f);
    o.w = fmaxf(acc[yy][3] + bb, 0.f);
    *reinterpret_cast<float4*>(Y + (size_t)n * TT + m0 + tx * 4) = o;
  }
}

// --------------------------------------------------- MFMA TCN conv (fp16 in)
// X,Y: (512,T) f32.  NTAPS==1: W[o][i]; NTAPS==3: W[o][i][3]; 'SAME', d<=32.
// Block tile: 64 c (m) x 128 t (n), 4 waves in 2x2, mfma_f32_32x32x16_f16.
template<int NTAPS, int RELU, int RES>
__launch_bounds__(256)
__global__ void convm_k(const float* __restrict__ X, const float* __restrict__ W,
                        const float* __restrict__ bias, const float* __restrict__ Res,
                        float* __restrict__ Y, int dil) {
  const int d = (NTAPS == 3) ? dil : 0;
  const int width = 128 + 2 * d;            // <= 192
  __shared__ __align__(16) _Float16 Ws16[NTAPS][64][72];   // [tap][m=c][k] pad 72
  __shared__ __align__(16) _Float16 Xs16[192][72];         // [t_local][k]  pad 72
  const int t0 = blockIdx.x * 128, c0 = blockIdx.y * 64;
  const int tid = threadIdx.x;
  const int l = tid & 63, w = tid >> 6;
  const int wm = w & 1, wn = w >> 1;
  const int l31 = l & 31, q = l >> 5;
  f32x16 acc0, acc1;
#pragma unroll
  for (int i = 0; i < 16; i++) { acc0[i] = 0.f; acc1[i] = 0.f; }
  const int xk = tid >> 2;          // k-row 0..63
  const int xu0 = tid & 3;
  for (int kc = 0; kc < 512; kc += 64) {
    __syncthreads();
    {
      const float* xr = X + (size_t)(kc + xk) * TT;
      for (int u = xu0; u < width; u += 4) {
        const int gt = t0 - d + u;
        const float v = (gt >= 0 && gt < TT) ? xr[gt] : 0.f;
        Xs16[u][xk] = (_Float16)v;
      }
    }
    if (NTAPS == 3) {
      for (int e = tid; e < 64 * 64 * 3; e += 256) {
        const int tap = e % 3; const int r = e / 3;
        const int i = r & 63; const int c = r >> 6;
        Ws16[tap][c][i] = (_Float16)W[((size_t)(c0 + c) * 512 + kc + i) * 3 + tap];
      }
    } else {
      for (int e = tid; e < 1024; e += 256) {
        const int c = e >> 4, i0 = (e & 15) << 2;
        const float4 wv = *reinterpret_cast<const float4*>(W + (size_t)(c0 + c) * 512 + kc + i0);
        Ws16[0][c][i0 + 0] = (_Float16)wv.x; Ws16[0][c][i0 + 1] = (_Float16)wv.y;
        Ws16[0][c][i0 + 2] = (_Float16)wv.z; Ws16[0][c][i0 + 3] = (_Float16)wv.w;
      }
    }
    __syncthreads();
#pragma unroll
    for (int tap = 0; tap < NTAPS; tap++) {
#pragma unroll
      for (int ks = 0; ks < 4; ks++) {
        const int k0 = ks * 16 + q * 8;
        const f16x8 a = *reinterpret_cast<const f16x8*>(&Ws16[tap][wm * 32 + l31][k0]);
        const int row0 = wn * 64 + l31 + tap * d;
        const f16x8 b0 = *reinterpret_cast<const f16x8*>(&Xs16[row0][k0]);
        acc0 = __builtin_amdgcn_mfma_f32_32x32x16_f16(a, b0, acc0, 0, 0, 0);
        const f16x8 b1 = *reinterpret_cast<const f16x8*>(&Xs16[row0 + 32][k0]);
        acc1 = __builtin_amdgcn_mfma_f32_32x32x16_f16(a, b1, acc1, 0, 0, 0);
      }
    }
  }
#pragma unroll
  for (int r = 0; r < 16; r++) {
    const int m = wm * 32 + (r & 3) + 8 * (r >> 2) + 4 * q;
    const int c = c0 + m;
    const float bb = bias[c];
    {
      const int t = t0 + wn * 64 + l31;
      float v = acc0[r] + bb;
      if (RES) v += Res[(size_t)c * TT + t];
      if (RELU) v = fmaxf(v, 0.f);
      Y[(size_t)c * TT + t] = v;
    }
    {
      const int t = t0 + wn * 64 + 32 + l31;
      float v = acc1[r] + bb;
      if (RES) v += Res[(size_t)c * TT + t];
      if (RELU) v = fmaxf(v, 0.f);
      Y[(size_t)c * TT + t] = v;
    }
  }
}

// -------------------- tiled transpose (512,T) -> out (T,512) + f32 copy (T,512)
__launch_bounds__(256)
__global__ void temit_k(const float* __restrict__ Xin, float* __restrict__ outp,
                        float* __restrict__ Aout) {
  __shared__ float tile[32][33];
  const int t0 = blockIdx.x * 32, d0 = blockIdx.y * 32;
  const int lx = threadIdx.x & 31, ly = threadIdx.x >> 5;
#pragma unroll
  for (int r = 0; r < 4; r++)
    tile[ly + 8 * r][lx] = Xin[(size_t)(d0 + ly + 8 * r) * TT + t0 + lx];
  __syncthreads();
#pragma unroll
  for (int r = 0; r < 4; r++) {
    const int t = t0 + ly + 8 * r, dd = d0 + lx;
    const float v = tile[lx][ly + 8 * r];
    outp[(size_t)t * 512 + dd] = v;
    Aout[(size_t)t * 512 + dd] = v;
  }
}

// ---------------------------------------------------------------- cosine sim
__global__ void nsim_k(const float* __restrict__ V, const float* __restrict__ text,
                       const float* __restrict__ tnorm, float* __restrict__ out, int R) {
  int idx = blockIdx.x * 256 + threadIdx.x;  // r*32 + c
  if (idx >= R * 32) return;
  int r = idx >> 5, c = idx & 31;
  const float* vr = V + (size_t)r * 512;
  float ss = 0.f, dot = 0.f;
  for (int dd = 0; dd < 512; dd++) {
    float v = vr[dd];
    ss += v * v;
    dot += v * text[(size_t)c * 512 + dd];
  }
  out[idx] = dot / (sqrtf(ss) * tnorm[c]);
}

// ======================================================================= host
extern "C" void kernel_launch(void* const* d_in, const int* in_sizes, int n_in,
                              void* d_out, int out_size, void* d_ws, size_t ws_size,
                              hipStream_t stream) {
  const float* in_ff   = (const float*)d_in[0];
  const float* in_act  = (const float*)d_in[1];
  const float* in_fpos = (const float*)d_in[2];
  const float* in_apos = (const float*)d_in[3];
  const float* in_text = (const float*)d_in[4];
  const float* Wf2c = (const float*)d_in[5];  const float* bf2c = (const float*)d_in[6];
  const float* Wa2c = (const float*)d_in[7];  const float* ba2c = (const float*)d_in[8];
  const float* Ws2c = (const float*)d_in[9];  const float* bs2c = (const float*)d_in[10];
  const float* Wih_f = (const float*)d_in[11]; const float* Whh_f = (const float*)d_in[12];
  const float* bih_f = (const float*)d_in[13]; const float* bhh_f = (const float*)d_in[14];
  const float* Wih_b = (const float*)d_in[15]; const float* Whh_b = (const float*)d_in[16];
  const float* bih_b = (const float*)d_in[17]; const float* bhh_b = (const float*)d_in[18];
  const float* Wcomb = (const float*)d_in[19]; const float* bcomb = (const float*)d_in[20];
  const float* f2a_Wq = (const float*)d_in[21]; const float* f2a_Wk = (const float*)d_in[22];
  const float* f2a_Wv = (const float*)d_in[23]; const float* f2a_Wo = (const float*)d_in[24];
  const float* f2a_bo = (const float*)d_in[25];
  const float* ag_Wih = (const float*)d_in[26]; const float* ag_Whh = (const float*)d_in[27];
  const float* ag_bih = (const float*)d_in[28]; const float* ag_bhh = (const float*)d_in[29];
  const float* a2f_Wq = (const float*)d_in[30]; const float* a2f_Wk = (const float*)d_in[31];
  const float* a2f_Wv = (const float*)d_in[32]; const float* a2f_Wo = (const float*)d_in[33];
  const float* a2f_bo = (const float*)d_in[34];
  const float* Wsf = (const float*)d_in[35]; const float* bsf = (const float*)d_in[36];
  const float* tcn_inW = (const float*)d_in[37]; const float* tcn_inb = (const float*)d_in[38];
  const float* tcn_dW = (const float*)d_in[39]; const float* tcn_db = (const float*)d_in[40];
  const float* tcn_pW = (const float*)d_in[41]; const float* tcn_pb = (const float*)d_in[42];
  const float* tcn_outW = (const float*)d_in[43]; const float* tcn_outb = (const float*)d_in[44];

  int S = (out_size - (TT * DD + MM * DD + TT * CC + MM * CC)) / CC;
  if (S < 1) S = 1;
  if (S > TT) S = TT;
  const int Spad = (S + 63) & ~63;

  // ---------------- workspace layout (flags FIRST so one zero call covers)
  char* ws = (char*)d_ws;
  size_t off = 0;
  auto alloc = [&](size_t b) -> char* { char* p = ws + off; off += (b + 255) & ~(size_t)255; return p; };
  int* flgF = (int*)alloc((size_t)S * 64 * 4);    // seg fwd flags: step*64 + part*16
  int* flgB = (int*)alloc((size_t)S * 64 * 4);    // seg bwd flags
  int* flgA = (int*)alloc((size_t)MM * 256 * 4);  // act flags: step*256 + part*16
  const size_t zero_words = off / 4;
  const size_t BTD = (size_t)TT * DD * 4;
  float* bufA = (float*)alloc(BTD);
  float* bufB = (float*)alloc(BTD);
  int* pred    = (int*)alloc((size_t)TT * 4);
  int* segid   = (int*)alloc((size_t)TT * 4);
  int* starts  = (int*)alloc((size_t)TT * 4);
  int* centers = (int*)alloc((size_t)TT * 4);
  int* cnts    = (int*)alloc((size_t)TT * 4);
  float* tnorm = (float*)alloc(32 * 4);
  float* segmean = (float*)alloc((size_t)Spad * 512 * 4);
  float* gif  = (float*)alloc((size_t)Spad * 768 * 4);
  float* gib  = (float*)alloc((size_t)Spad * 768 * 4);
  float* hfb  = (float*)alloc((size_t)Spad * 256 * 4);
  float* hbb  = (float*)alloc((size_t)Spad * 256 * 4);
  float* acmb = (float*)alloc((size_t)Spad * 512 * 4);
  float* segc = (float*)alloc((size_t)Spad * 512 * 4);
  float* segpos = (float*)alloc((size_t)Spad * 512 * 4);
  float* kin  = (float*)alloc((size_t)Spad * 512 * 4);
  float* kf2a = (float*)alloc((size_t)Spad * 512 * 4);
  float* vf2a = (float*)alloc((size_t)Spad * 512 * 4);
  float* q2   = (float*)alloc((size_t)Spad * 512 * 4);
  float* att2 = (float*)alloc((size_t)Spad * 512 * 4);
  float* seg2 = (float*)alloc((size_t)Spad * 512 * 4);
  float* vseg = (float*)alloc((size_t)Spad * 512 * 4);
  float* pbuf = (float*)alloc((size_t)64 * Spad * 4);
  float* qin  = (float*)alloc((size_t)64 * 512 * 4);
  float* qf2a = (float*)alloc((size_t)64 * 512 * 4);
  float* att1 = (float*)alloc((size_t)64 * 512 * 4);
  float* af0  = (float*)alloc((size_t)64 * 512 * 4);
  float* aggi = (float*)alloc((size_t)64 * 1536 * 4);
  float* afg  = (float*)alloc((size_t)64 * 512 * 4);
  float* k2in = (float*)alloc((size_t)64 * 512 * 4);
  float* k2   = (float*)alloc((size_t)64 * 512 * 4);
  float* v2   = (float*)alloc((size_t)64 * 512 * 4);
  float* vaf  = (float*)alloc((size_t)64 * 512 * 4);
  (void)ws_size; (void)in_sizes; (void)n_in;

  float* outp = (float*)d_out;
  float* out_ff   = outp;
  float* out_af   = outp + (size_t)TT * DD;
  float* out_fsim = out_af + (size_t)MM * DD;
  float* out_asim = out_fsim + (size_t)TT * CC;
  float* out_ssim = out_asim + (size_t)MM * CC;

  auto GR = [](long n) { return (unsigned)((n + 255) / 256); };
  const unsigned Sg = (unsigned)(Spad / 64);

  // zero ONLY the flag arrays (everything else is write-before-read)
  zero_k<<<256, 256, 0, stream>>>((float*)d_ws, (long)zero_words);

  tnorm_k<<<1, 256, 0, stream>>>(in_text, tnorm);

  // segmentation (tiled GEMM for the T-sized projection)
  gemm_k<<<dim3(8, 128), 256, 0, stream>>>(in_ff, Wf2c, bf2c, bufA, TT, 512, 512);
  argmax_k<<<TT, 256, 0, stream>>>(bufA, in_text, tnorm, pred);
  segscan_k<<<1, 256, 0, stream>>>(pred, segid, starts, centers, cnts);
  segmean_k<<<GR((long)S * 512), 256, 0, stream>>>(in_ff, starts, cnts, segmean, S);

  // seg BiGRU (multi-block LDS-resident scan)
  gemm_k<<<dim3(12, Sg), 256, 0, stream>>>(segmean, Wih_f, bih_f, gif, Spad, 768, 512);
  gemm_k<<<dim3(12, Sg), 256, 0, stream>>>(segmean, Wih_b, bih_b, gib, Spad, 768, 512);
  gru_seg_mb_k<<<8, 192, 0, stream>>>(gif, gib, Whh_f, bhh_f, Whh_b, bhh_b,
                                      hfb, hbb, S, flgF, flgB);
  acomb_k<<<GR((long)S * 512), 256, 0, stream>>>(hfb, hbb, acmb, S * 512);
  gemm_k<<<dim3(8, Sg), 256, 0, stream>>>(acmb, Wcomb, bcomb, segc, Spad, 512, 512);
  gatherpos_k<<<GR((long)S * 512), 256, 0, stream>>>(in_fpos, centers, segpos, S * 512);

  // f2a attention (actions query segments)
  addff_k<<<GR(64 * 512), 256, 0, stream>>>(in_act, in_apos, qin, 64 * 512);
  addff_k<<<GR((long)S * 512), 256, 0, stream>>>(segc, segpos, kin, S * 512);
  gemm_k<<<dim3(8, 1), 256, 0, stream>>>(qin, f2a_Wq, nullptr, qf2a, 64, 512, 512);
  gemm_k<<<dim3(8, Sg), 256, 0, stream>>>(kin, f2a_Wk, nullptr, kf2a, Spad, 512, 512);
  gemm_k<<<dim3(8, Sg), 256, 0, stream>>>(segc, f2a_Wv, nullptr, vf2a, Spad, 512, 512);
  nlogit_k<<<GR((long)64 * S), 256, 0, stream>>>(qf2a, kf2a, pbuf, 64, S);
  nsoft_k<<<1, 256, 0, stream>>>(pbuf, 64, S);
  nav_k<<<GR(64 * 512), 256, 0, stream>>>(pbuf, vf2a, att1, 64, S);
  gemm_k<<<dim3(8, 1), 256, 0, stream>>>(att1, f2a_Wo, f2a_bo, af0, 64, 512, 512);

  // action GRU (multi-block LDS-resident scan)
  gemm_k<<<dim3(24, 1), 256, 0, stream>>>(af0, ag_Wih, ag_bih, aggi, 64, 1536, 512);
  gru_act_mb_k<<<16, 128, 0, stream>>>(aggi, ag_Whh, ag_bhh, afg, MM, flgA);
  copy_k<<<GR(64 * 512), 256, 0, stream>>>(afg, out_af, 64 * 512);

  // a2f attention (segments query actions)
  addff_k<<<GR(64 * 512), 256, 0, stream>>>(afg, in_apos, k2in, 64 * 512);
  gemm_k<<<dim3(8, Sg), 256, 0, stream>>>(kin, a2f_Wq, nullptr, q2, Spad, 512, 512);
  gemm_k<<<dim3(8, 1), 256, 0, stream>>>(k2in, a2f_Wk, nullptr, k2, 64, 512, 512);
  gemm_k<<<dim3(8, 1), 256, 0, stream>>>(afg, a2f_Wv, nullptr, v2, 64, 512, 512);
  nlogit_k<<<GR((long)S * 64), 256, 0, stream>>>(q2, k2, pbuf, S, 64);
  nsoft_k<<<GR(S), 256, 0, stream>>>(pbuf, S, 64);
  nav_k<<<GR((long)S * 512), 256, 0, stream>>>(pbuf, v2, att2, S, 64);
  gemm_k<<<dim3(8, Sg), 256, 0, stream>>>(att2, a2f_Wo, a2f_bo, seg2, Spad, 512, 512);

  // frame fusion + TCN (MFMA convs), ping-pong bufA <-> bufB as (D,T)
  ff2_k<<<dim3(128, 8), 256, 0, stream>>>(seg2, in_ff, segid, Wsf, bsf, bufA, S);
  convm_k<1, 0, 0><<<dim3(64, 8), 256, 0, stream>>>(bufA, tcn_inW, tcn_inb, nullptr, bufB, 1);
  for (int l = 0; l < 6; l++) {
    convm_k<3, 1, 0><<<dim3(64, 8), 256, 0, stream>>>(
        bufB, tcn_dW + (size_t)l * 512 * 512 * 3, tcn_db + (size_t)l * 512, nullptr, bufA, 1 << l);
    convm_k<1, 0, 1><<<dim3(64, 8), 256, 0, stream>>>(
        bufA, tcn_pW + (size_t)l * 512 * 512, tcn_pb + (size_t)l * 512, bufB, bufB, 1);
  }
  convm_k<1, 0, 0><<<dim3(64, 8), 256, 0, stream>>>(bufB, tcn_outW, tcn_outb, nullptr, bufA, 1);
  temit_k<<<dim3(256, 16), 256, 0, stream>>>(bufA, out_ff, bufB);

  // similarity heads (tiled GEMM for the T-sized projection)
  gemm_k<<<dim3(8, 128), 256, 0, stream>>>(bufB, Wf2c, bf2c, bufA, TT, 512, 512);
  nsim_k<<<GR((long)TT * 32), 256, 0, stream>>>(bufA, in_text, tnorm, out_fsim, TT);
  gemm_k<<<dim3(8, 1), 256, 0, stream>>>(afg, Wa2c, ba2c, vaf, 64, 512, 512);
  nsim_k<<<GR(64 * 32), 256, 0, stream>>>(vaf, in_text, tnorm, out_asim, 64);
  gemm_k<<<dim3(8, Sg), 256, 0, stream>>>(seg2, Ws2c, bs2c, vseg, Spad, 512, 512);
  nsim_k<<<GR((long)S * 32), 256, 0, stream>>>(vseg, in_text, tnorm, out_ssim, S);
}

// Round 12
// 4379.071 us; speedup vs baseline: 3.7610x; 1.1445x over previous
//
#include <hip/hip_runtime.h>
#include <cstdint>
#include <cstddef>

__device__ __forceinline__ float sigf(float x) { return 1.f / (1.f + expf(-x)); }

__device__ __forceinline__ unsigned packh(float a, float b) {
  union { unsigned u; _Float16 h[2]; } cv;
  cv.h[0] = (_Float16)a; cv.h[1] = (_Float16)b; return cv.u;
}
__device__ __forceinline__ float2 uph(unsigned u) {
  union { unsigned uu; _Float16 h[2]; } cv; cv.uu = u;
  return make_float2((float)cv.h[0], (float)cv.h[1]);
}

typedef _Float16 f16x8 __attribute__((ext_vector_type(8)));
typedef float f32x16 __attribute__((ext_vector_type(16)));

static constexpr int TT = 8192;
static constexpr int MM = 64;
static constexpr int CC = 32;
static constexpr int DD = 512;
static constexpr unsigned GUARD_MAX = 1u << 30;

// ---------------------------------------------------------------- ws zeroing
__global__ void zero_k(float* __restrict__ p, long n) {
  long i = (long)blockIdx.x * 256 + threadIdx.x;
  long stride = (long)gridDim.x * 256;
  for (; i < n; i += stride) p[i] = 0.f;
}

// ---------------------------------------------------------------- elementwise
__global__ void copy_k(const float* __restrict__ a, float* __restrict__ o, int n) {
  int i = blockIdx.x * 256 + threadIdx.x;
  if (i < n) o[i] = a[i];
}
__global__ void addff_k(const float* __restrict__ a, const float* __restrict__ b, float* __restrict__ o, int n) {
  int i = blockIdx.x * 256 + threadIdx.x;
  if (i < n) o[i] = a[i] + b[i];
}
__global__ void acomb_k(const float* __restrict__ hf, const float* __restrict__ hb, float* __restrict__ o, int n) {
  int i = blockIdx.x * 256 + threadIdx.x;
  if (i >= n) return;
  int s = i >> 9, j = i & 511;
  float v = (j < 256) ? hf[(size_t)s * 256 + j] : hb[(size_t)s * 256 + (j - 256)];
  o[i] = fmaxf(v, 0.f);
}
__global__ void gatherpos_k(const float* __restrict__ fpos, const int* __restrict__ centers,
                            float* __restrict__ segpos, int n) {
  int i = blockIdx.x * 256 + threadIdx.x;
  if (i >= n) return;
  int s = i >> 9, dd = i & 511;
  int ct = centers[s];
  ct = ct < 0 ? 0 : (ct > TT - 1 ? TT - 1 : ct);
  segpos[i] = fpos[(size_t)ct * 512 + dd];
}

// ---------------------------------------------------------------- text norms
__global__ void tnorm_k(const float* __restrict__ text, float* __restrict__ tnorm) {
  int c = blockIdx.x * 256 + threadIdx.x;
  if (c >= 32) return;
  float s = 0.f;
  for (int dd = 0; dd < 512; dd++) { float v = text[(size_t)c * 512 + dd]; s += v * v; }
  tnorm[c] = sqrtf(s);
}

// ---------------------------------------------------- naive attention pieces
__global__ void nlogit_k(const float* __restrict__ Q, const float* __restrict__ Kk,
                         float* __restrict__ L, int NY, int NX) {
  int idx = blockIdx.x * 256 + threadIdx.x;
  if (idx >= NY * NX) return;
  int y = idx / NX, x = idx - y * NX;
  const float* qr = Q + (size_t)y * 512;
  const float* kr = Kk + (size_t)x * 512;
  float d = 0.f;
  for (int k = 0; k < 512; k++) d += qr[k] * kr[k];
  L[idx] = d * 0.044194173824159216f;
}
__global__ void nsoft_k(float* __restrict__ L, int NY, int NX) {
  int y = blockIdx.x * 256 + threadIdx.x;
  if (y >= NY) return;
  float* row = L + (size_t)y * NX;
  float m = row[0];
  for (int x = 1; x < NX; x++) m = fmaxf(m, row[x]);
  float s = 0.f;
  for (int x = 0; x < NX; x++) { float p = expf(row[x] - m); row[x] = p; s += p; }
  const float inv = 1.f / s;
  for (int x = 0; x < NX; x++) row[x] *= inv;
}
__global__ void nav_k(const float* __restrict__ P, const float* __restrict__ V,
                      float* __restrict__ O, int NY, int NX) {
  int idx = blockIdx.x * 256 + threadIdx.x;
  if (idx >= NY * 512) return;
  int y = idx >> 9, dd = idx & 511;
  const float* pr = P + (size_t)y * NX;
  float o = 0.f;
  for (int x = 0; x < NX; x++) o += pr[x] * V[(size_t)x * 512 + dd];
  O[idx] = o;
}

// ------------------------------------------ argmax over classes: block per row
__global__ void argmax_k(const float* __restrict__ V, const float* __restrict__ text,
                         const float* __restrict__ tnorm, int* __restrict__ pred) {
  __shared__ float vs[512];
  __shared__ float dots[32];
  const int r = blockIdx.x, tid = threadIdx.x;
  for (int dd = tid; dd < 512; dd += 256) vs[dd] = V[(size_t)r * 512 + dd];
  __syncthreads();
  if (tid < 32) {
    float dot = 0.f;
    const float* tr = text + (size_t)tid * 512;
    for (int dd = 0; dd < 512; dd++) dot += vs[dd] * tr[dd];
    dots[tid] = dot / tnorm[tid];
  }
  __syncthreads();
  if (tid == 0) {
    int best = 0; float bv = dots[0];
    for (int c = 1; c < 32; c++) if (dots[c] > bv) { bv = dots[c]; best = c; }
    pred[r] = best;
  }
}

// ------------------------------- parallel run-length segmentation (one block)
__global__ void segscan_k(const int* __restrict__ pred, int* __restrict__ segid,
                          int* __restrict__ starts, int* __restrict__ centers,
                          int* __restrict__ cnts) {
  __shared__ int base[256];
  __shared__ int SS;
  const int tid = threadIdx.x;
  int lc = 0;
  unsigned flags = 0;
  int prev = (tid > 0) ? pred[tid * 32 - 1] : 0;
  for (int i = 0; i < 32; i++) {
    const int t = tid * 32 + i;
    const int cur = pred[t];
    const int c = (t > 0) && (cur != prev);
    prev = cur;
    flags |= ((unsigned)c) << i;
    lc += c;
  }
  base[tid] = lc;
  __syncthreads();
  if (tid == 0) {
    int run = 0;
    for (int i = 0; i < 256; i++) { const int v = base[i]; base[i] = run; run += v; }
    SS = run + 1;
  }
  __syncthreads();
  int b = base[tid];
  for (int i = 0; i < 32; i++) {
    const int t = tid * 32 + i;
    if ((flags >> i) & 1u) { b++; starts[b] = t; }
    segid[t] = b;
  }
  if (tid == 0) starts[0] = 0;
  __threadfence_block();
  __syncthreads();
  const int S = SS;
  for (int s = tid; s < TT; s += 256) {
    if (s < S) {
      const int e = (s == S - 1) ? (TT - 1) : (starts[s + 1] - 1);
      centers[s] = (starts[s] + e) >> 1;
      cnts[s] = e - starts[s] + 1;
    } else {
      starts[s] = 0; cnts[s] = 1; centers[s] = 0;
    }
  }
}

// ---------------------------------------------------------- segment mean pool
__global__ void segmean_k(const float* __restrict__ ff, const int* __restrict__ starts,
                          const int* __restrict__ cnts, float* __restrict__ segmean, int S) {
  int idx = blockIdx.x * 256 + threadIdx.x;
  if (idx >= S * 512) return;
  int s = idx >> 9, dd = idx & 511;
  int st = starts[s], n = cnts[s];
  st = st < 0 ? 0 : (st > TT - 1 ? TT - 1 : st);
  n = n < 1 ? 1 : n;
  if (st + n > TT) n = TT - st;
  float a = 0.f;
  for (int t = st; t < st + n; t++) a += ff[(size_t)t * 512 + dd];
  segmean[idx] = a / (float)n;
}

// ------------------- multi-block bidirectional seg GRU (H=256), LDS weights
// gi prefetched into registers; next-step gi load overlaps the flag spin.
__launch_bounds__(192)
__global__ void gru_seg_mb_k(const float* __restrict__ gi_f, const float* __restrict__ gi_b,
                             const float* __restrict__ Whh_f, const float* __restrict__ bhh_f,
                             const float* __restrict__ Whh_b, const float* __restrict__ bhh_b,
                             float* __restrict__ hf, float* __restrict__ hb, int S,
                             int* __restrict__ flag_f, int* __restrict__ flag_b) {
  const int dir = blockIdx.x >> 2;
  const int part = blockIdx.x & 3;
  const float* gi = dir ? gi_b : gi_f;
  const float* Whh = dir ? Whh_b : Whh_f;
  const float* bhh = dir ? bhh_b : bhh_f;
  float* ho = dir ? hb : hf;
  int* flg = dir ? flag_b : flag_f;
  const int tid = threadIdx.x;
  const int h0 = part * 64;
  const int grp = tid >> 6;
  const int jj = tid & 63;
  const int j = grp * 256 + h0 + jj;
  __shared__ __align__(16) unsigned wlds[128 * 192];
  __shared__ __align__(16) unsigned hpk[128];
  __shared__ float hcur[256];
  __shared__ float rbuf[64], zbuf[64], gnbuf[64];
  for (int e = tid; e < 128 * 192; e += 192) {
    const int q = e / 768, rem = e % 768;
    const int g = rem >> 2, r = rem & 3;
    const int i2 = q * 4 + r;
    const int gg = (g >> 6) * 256 + h0 + (g & 63);
    wlds[e] = packh(Whh[(size_t)(2 * i2) * 768 + gg], Whh[(size_t)(2 * i2 + 1) * 768 + gg]);
  }
  for (int e = tid; e < 128; e += 192) hpk[e] = 0u;
  for (int e = tid; e < 256; e += 192) hcur[e] = 0.f;
  const float bj = bhh[j];
  __syncthreads();
  const uint4* hp4 = reinterpret_cast<const uint4*>(hpk);
  const uint4* wp4 = reinterpret_cast<const uint4*>(wlds);
  // prefetch step 0 gi
  int s = dir ? (S - 1) : 0;
  float g_j = gi[(size_t)s * 768 + j];
  float g_n = (tid < 64) ? gi[(size_t)s * 768 + 512 + h0 + tid] : 0.f;
  for (int step = 0; step < S; step++) {
    float a0 = 0.f, a1 = 0.f, a2 = 0.f, a3 = 0.f;
#pragma unroll 8
    for (int q = 0; q < 32; q++) {
      const uint4 h4 = hp4[q];
      const uint4 w4 = wp4[q * 192 + tid];
      const float2 hh0 = uph(h4.x), hh1 = uph(h4.y), hh2 = uph(h4.z), hh3 = uph(h4.w);
      const float2 ww0 = uph(w4.x), ww1 = uph(w4.y), ww2 = uph(w4.z), ww3 = uph(w4.w);
      a0 += hh0.x * ww0.x + hh0.y * ww0.y;
      a1 += hh1.x * ww1.x + hh1.y * ww1.y;
      a2 += hh2.x * ww2.x + hh2.y * ww2.y;
      a3 += hh3.x * ww3.x + hh3.y * ww3.y;
    }
    const float gh = bj + (a0 + a1) + (a2 + a3);
    if (grp == 0)      rbuf[jj] = sigf(g_j + gh);
    else if (grp == 1) zbuf[jj] = sigf(g_j + gh);
    else               gnbuf[jj] = gh;
    __syncthreads();
    if (tid < 64) {
      const float nval = tanhf(g_n + rbuf[tid] * gnbuf[tid]);
      const float hn = (1.f - zbuf[tid]) * nval + zbuf[tid] * hcur[h0 + tid];
      __hip_atomic_store(&ho[(size_t)s * 256 + h0 + tid], hn,
                         __ATOMIC_RELAXED, __HIP_MEMORY_SCOPE_AGENT);
    }
    __syncthreads();
    if (tid == 0)
      __hip_atomic_store(&flg[step * 64 + part * 16], 1,
                         __ATOMIC_RELEASE, __HIP_MEMORY_SCOPE_AGENT);
    // prefetch next-step gi while peers arrive (overlaps the spin below)
    const int sn = dir ? (s - 1) : (s + 1);
    if (step + 1 < S) {
      g_j = gi[(size_t)sn * 768 + j];
      if (tid < 64) g_n = gi[(size_t)sn * 768 + 512 + h0 + tid];
    }
    if (tid < 4) {
      int* fp = &flg[step * 64 + tid * 16];
      unsigned guard = 0;
      while (__hip_atomic_load(fp, __ATOMIC_RELAXED, __HIP_MEMORY_SCOPE_AGENT) == 0 &&
             ++guard < GUARD_MAX) {
        __builtin_amdgcn_s_sleep(2);
      }
      (void)__hip_atomic_load(fp, __ATOMIC_ACQUIRE, __HIP_MEMORY_SCOPE_AGENT);
    }
    __syncthreads();
    for (int e = tid; e < 256; e += 192)
      hcur[e] = __hip_atomic_load(&ho[(size_t)s * 256 + e],
                                  __ATOMIC_RELAXED, __HIP_MEMORY_SCOPE_AGENT);
    __syncthreads();
    for (int e = tid; e < 128; e += 192) hpk[e] = packh(hcur[2 * e], hcur[2 * e + 1]);
    __syncthreads();
    s = sn;
  }
}

// ------------------------- multi-block action GRU (H=512), LDS weights
__launch_bounds__(128)
__global__ void gru_act_mb_k(const float* __restrict__ gi, const float* __restrict__ Whh,
                             const float* __restrict__ bhh, float* __restrict__ hout,
                             int steps, int* __restrict__ flg) {
  const int part = blockIdx.x;
  const int tid = threadIdx.x;
  const int h0 = part * 32;
  const int grp = tid >> 5;
  const int jj = tid & 31;
  const bool act = (tid < 96);
  const int j = act ? (grp * 512 + h0 + jj) : 0;
  __shared__ __align__(16) unsigned wlds[256 * 96];
  __shared__ __align__(16) unsigned hpk[256];
  __shared__ float hcur[512];
  __shared__ float rbuf[32], zbuf[32], gnbuf[32];
  for (int e = tid; e < 256 * 96; e += 128) {
    const int q = e / 384, rem = e % 384;
    const int g = rem >> 2, r = rem & 3;
    const int i2 = q * 4 + r;
    const int gg = (g >> 5) * 512 + h0 + (g & 31);
    wlds[e] = packh(Whh[(size_t)(2 * i2) * 1536 + gg], Whh[(size_t)(2 * i2 + 1) * 1536 + gg]);
  }
  for (int e = tid; e < 256; e += 128) hpk[e] = 0u;
  for (int e = tid; e < 512; e += 128) hcur[e] = 0.f;
  const float bj = act ? bhh[j] : 0.f;
  __syncthreads();
  const uint4* hp4 = reinterpret_cast<const uint4*>(hpk);
  const uint4* wp4 = reinterpret_cast<const uint4*>(wlds);
  float g_j = act ? gi[j] : 0.f;
  float g_n = (tid < 32) ? gi[1024 + h0 + tid] : 0.f;
  for (int step = 0; step < steps; step++) {
    if (act) {
      float a0 = 0.f, a1 = 0.f, a2 = 0.f, a3 = 0.f;
#pragma unroll 8
      for (int q = 0; q < 64; q++) {
        const uint4 h4 = hp4[q];
        const uint4 w4 = wp4[q * 96 + tid];
        const float2 hh0 = uph(h4.x), hh1 = uph(h4.y), hh2 = uph(h4.z), hh3 = uph(h4.w);
        const float2 ww0 = uph(w4.x), ww1 = uph(w4.y), ww2 = uph(w4.z), ww3 = uph(w4.w);
        a0 += hh0.x * ww0.x + hh0.y * ww0.y;
        a1 += hh1.x * ww1.x + hh1.y * ww1.y;
        a2 += hh2.x * ww2.x + hh2.y * ww2.y;
        a3 += hh3.x * ww3.x + hh3.y * ww3.y;
      }
      const float gh = bj + (a0 + a1) + (a2 + a3);
      if (grp == 0)      rbuf[jj] = sigf(g_j + gh);
      else if (grp == 1) zbuf[jj] = sigf(g_j + gh);
      else               gnbuf[jj] = gh;
    }
    __syncthreads();
    if (tid < 32) {
      const float nval = tanhf(g_n + rbuf[tid] * gnbuf[tid]);
      const float hn = (1.f - zbuf[tid]) * nval + zbuf[tid] * hcur[h0 + tid];
      __hip_atomic_store(&hout[(size_t)step * 512 + h0 + tid], hn,
                         __ATOMIC_RELAXED, __HIP_MEMORY_SCOPE_AGENT);
    }
    __syncthreads();
    if (tid == 0)
      __hip_atomic_store(&flg[step * 256 + part * 16], 1,
                         __ATOMIC_RELEASE, __HIP_MEMORY_SCOPE_AGENT);
    if (step + 1 < steps) {
      if (act) g_j = gi[(size_t)(step + 1) * 1536 + j];
      if (tid < 32) g_n = gi[(size_t)(step + 1) * 1536 + 1024 + h0 + tid];
    }
    if (tid < 16) {
      int* fp = &flg[step * 256 + tid * 16];
      unsigned guard = 0;
      while (__hip_atomic_load(fp, __ATOMIC_RELAXED, __HIP_MEMORY_SCOPE_AGENT) == 0 &&
             ++guard < GUARD_MAX) {
        __builtin_amdgcn_s_sleep(2);
      }
      (void)__hip_atomic_load(fp, __ATOMIC_ACQUIRE, __HIP_MEMORY_SCOPE_AGENT);
    }
    __syncthreads();
    for (int e = tid; e < 512; e += 128)
      hcur[e] = __hip_atomic_load(&hout[(size_t)step * 512 + e],
                                  __ATOMIC_RELAXED, __HIP_MEMORY_SCOPE_AGENT);
    __syncthreads();
    for (int e = tid; e < 256; e += 128) hpk[e] = packh(hcur[2 * e], hcur[2 * e + 1]);
    __syncthreads();
  }
}

// ---------------------------------------------------- fp32 tiled GEMM (argmax path)
__launch_bounds__(256)
__global__ void gemm_k(const float* __restrict__ A, const float* __restrict__ B,
                       const float* __restrict__ bias, float* __restrict__ C,
                       int M, int N, int K) {
  __shared__ float As[16][64];
  __shared__ float Bs[16][64];
  const int tid = threadIdx.x;
  const int n0 = blockIdx.x * 64, m0 = blockIdx.y * 64;
  const int tx = tid & 15, ty = tid >> 4;
  const int am = tid >> 2, ak = (tid & 3) << 2;
  const int bk = tid >> 4, bn = (tid & 15) << 2;
  float acc[4][4] = {};
  for (int k0 = 0; k0 < K; k0 += 16) {
    const float4 av = *reinterpret_cast<const float4*>(A + (size_t)(m0 + am) * K + k0 + ak);
    As[ak + 0][am] = av.x; As[ak + 1][am] = av.y; As[ak + 2][am] = av.z; As[ak + 3][am] = av.w;
    const float4 bv = *reinterpret_cast<const float4*>(B + (size_t)(k0 + bk) * N + n0 + bn);
    Bs[bk][bn + 0] = bv.x; Bs[bk][bn + 1] = bv.y; Bs[bk][bn + 2] = bv.z; Bs[bk][bn + 3] = bv.w;
    __syncthreads();
#pragma unroll
    for (int i = 0; i < 16; i++) {
      const float4 a4 = *reinterpret_cast<const float4*>(&As[i][ty * 4]);
      const float4 b4 = *reinterpret_cast<const float4*>(&Bs[i][tx * 4]);
      const float aa[4] = {a4.x, a4.y, a4.z, a4.w};
      const float bb[4] = {b4.x, b4.y, b4.z, b4.w};
#pragma unroll
      for (int x = 0; x < 4; x++)
#pragma unroll
        for (int y = 0; y < 4; y++) acc[x][y] += aa[x] * bb[y];
    }
    __syncthreads();
  }
#pragma unroll
  for (int x = 0; x < 4; x++) {
    const int m = m0 + ty * 4 + x;
#pragma unroll
    for (int y = 0; y < 4; y++) {
      const int n = n0 + tx * 4 + y;
      float v = acc[x][y];
      if (bias) v += bias[n];
      C[(size_t)m * N + n] = v;
    }
  }
}

// ------------------------------------------------ MFMA GEMM (fp16 staged)
// C[M,N] = A[M,K] @ B[K,N] + bias.  Tile M64 x N128, K-chunk 64.
// M mult of 64, N mult of 128, K mult of 64.
__launch_bounds__(256)
__global__ void gemmm_k(const float* __restrict__ A, const float* __restrict__ B,
                        const float* __restrict__ bias, float* __restrict__ C,
                        int M, int N, int K) {
  __shared__ __align__(16) _Float16 As16[64][72];
  __shared__ __align__(16) _Float16 Bs16[128][72];
  const int n0 = blockIdx.x * 128, m0 = blockIdx.y * 64;
  const int tid = threadIdx.x;
  const int l = tid & 63, w = tid >> 6;
  const int wm = w & 1, wn = w >> 1;
  const int l31 = l & 31, q = l >> 5;
  f32x16 acc0, acc1;
#pragma unroll
  for (int i = 0; i < 16; i++) { acc0[i] = 0.f; acc1[i] = 0.f; }
  const int am = tid >> 2, ak0 = (tid & 3) * 16;
  const int bk = tid >> 2, bn0 = (tid & 3) * 32;
  for (int kc = 0; kc < K; kc += 64) {
    __syncthreads();
#pragma unroll
    for (int kk = 0; kk < 16; kk += 4) {
      const float4 av = *reinterpret_cast<const float4*>(A + (size_t)(m0 + am) * K + kc + ak0 + kk);
      As16[am][ak0 + kk + 0] = (_Float16)av.x; As16[am][ak0 + kk + 1] = (_Float16)av.y;
      As16[am][ak0 + kk + 2] = (_Float16)av.z; As16[am][ak0 + kk + 3] = (_Float16)av.w;
    }
#pragma unroll
    for (int nn = 0; nn < 32; nn += 4) {
      const float4 bv = *reinterpret_cast<const float4*>(B + (size_t)(kc + bk) * N + n0 + bn0 + nn);
      Bs16[bn0 + nn + 0][bk] = (_Float16)bv.x; Bs16[bn0 + nn + 1][bk] = (_Float16)bv.y;
      Bs16[bn0 + nn + 2][bk] = (_Float16)bv.z; Bs16[bn0 + nn + 3][bk] = (_Float16)bv.w;
    }
    __syncthreads();
#pragma unroll
    for (int ks = 0; ks < 4; ks++) {
      const int k0 = ks * 16 + q * 8;
      const f16x8 a = *reinterpret_cast<const f16x8*>(&As16[wm * 32 + l31][k0]);
      const f16x8 b0 = *reinterpret_cast<const f16x8*>(&Bs16[wn * 64 + l31][k0]);
      acc0 = __builtin_amdgcn_mfma_f32_32x32x16_f16(a, b0, acc0, 0, 0, 0);
      const f16x8 b1 = *reinterpret_cast<const f16x8*>(&Bs16[wn * 64 + 32 + l31][k0]);
      acc1 = __builtin_amdgcn_mfma_f32_32x32x16_f16(a, b1, acc1, 0, 0, 0);
    }
  }
#pragma unroll
  for (int r = 0; r < 16; r++) {
    const int m = m0 + wm * 32 + (r & 3) + 8 * (r >> 2) + 4 * q;
    {
      const int n = n0 + wn * 64 + l31;
      float v = acc0[r];
      if (bias) v += bias[n];
      C[(size_t)m * N + n] = v;
    }
    {
      const int n = n0 + wn * 64 + 32 + l31;
      float v = acc1[r];
      if (bias) v += bias[n];
      C[(size_t)m * N + n] = v;
    }
  }
}

// ------------------- MFMA ff2: Y(D,T) = relu([seg2[sid[t]], ff[t]] @ Wsf + b)^T
// Tile: 64 dims (m) x 128 frames (n), K=1024 in chunks of 64.
__launch_bounds__(256)
__global__ void ff2m_k(const float* __restrict__ seg2, const float* __restrict__ ff,
                       const int* __restrict__ segid, const float* __restrict__ Wsf,
                       const float* __restrict__ bsf, float* __restrict__ Y, int S) {
  __shared__ __align__(16) _Float16 As16[64][72];    // [dim][k]
  __shared__ __align__(16) _Float16 Bs16[128][72];   // [frame][k]
  const int t0 = blockIdx.x * 128, nd0 = blockIdx.y * 64;
  const int tid = threadIdx.x;
  const int l = tid & 63, w = tid >> 6;
  const int wm = w & 1, wn = w >> 1;
  const int l31 = l & 31, q = l >> 5;
  f32x16 acc0, acc1;
#pragma unroll
  for (int i = 0; i < 16; i++) { acc0[i] = 0.f; acc1[i] = 0.f; }
  const int ak = tid >> 2, an0 = (tid & 3) * 16;     // Wsf: k-row, 16 dims each
  const int bt = tid >> 1, bk0 = (tid & 1) * 32;     // frames: 32 k each
  const int tglob = t0 + bt;
  int sid = segid[tglob];
  sid = sid < 0 ? 0 : (sid >= S ? S - 1 : sid);
  for (int kc = 0; kc < 1024; kc += 64) {
    __syncthreads();
    // stage Wsf[kc+ak][nd0 + an0 .. +15] -> As16[nd][k] (scatter)
#pragma unroll
    for (int nn = 0; nn < 16; nn += 4) {
      const float4 wv = *reinterpret_cast<const float4*>(Wsf + (size_t)(kc + ak) * 512 + nd0 + an0 + nn);
      As16[an0 + nn + 0][ak] = (_Float16)wv.x; As16[an0 + nn + 1][ak] = (_Float16)wv.y;
      As16[an0 + nn + 2][ak] = (_Float16)wv.z; As16[an0 + nn + 3][ak] = (_Float16)wv.w;
    }
    // stage input rows (concat): frame bt, k = kc+bk0 .. +31
    {
      const float* src = (kc < 512) ? (seg2 + (size_t)sid * 512 + kc + bk0)
                                    : (ff + (size_t)tglob * 512 + (kc - 512) + bk0);
#pragma unroll
      for (int kk = 0; kk < 32; kk += 4) {
        const float4 xv = *reinterpret_cast<const float4*>(src + kk);
        Bs16[bt][bk0 + kk + 0] = (_Float16)xv.x; Bs16[bt][bk0 + kk + 1] = (_Float16)xv.y;
        Bs16[bt][bk0 + kk + 2] = (_Float16)xv.z; Bs16[bt][bk0 + kk + 3] = (_Float16)xv.w;
      }
    }
    __syncthreads();
#pragma unroll
    for (int ks = 0; ks < 4; ks++) {
      const int k0 = ks * 16 + q * 8;
      const f16x8 a = *reinterpret_cast<const f16x8*>(&As16[wm * 32 + l31][k0]);
      const f16x8 b0 = *reinterpret_cast<const f16x8*>(&Bs16[wn * 64 + l31][k0]);
      acc0 = __builtin_amdgcn_mfma_f32_32x32x16_f16(a, b0, acc0, 0, 0, 0);
      const f16x8 b1 = *reinterpret_cast<const f16x8*>(&Bs16[wn * 64 + 32 + l31][k0]);
      acc1 = __builtin_amdgcn_mfma_f32_32x32x16_f16(a, b1, acc1, 0, 0, 0);
    }
  }
#pragma unroll
  for (int r = 0; r < 16; r++) {
    const int nd = nd0 + wm * 32 + (r & 3) + 8 * (r >> 2) + 4 * q;
    const float bb = bsf[nd];
    {
      const int t = t0 + wn * 64 + l31;
      Y[(size_t)nd * TT + t] = fmaxf(acc0[r] + bb, 0.f);
    }
    {
      const int t = t0 + wn * 64 + 32 + l31;
      Y[(size_t)nd * TT + t] = fmaxf(acc1[r] + bb, 0.f);
    }
  }
}

// --------------------------------------------------- MFMA TCN conv (fp16 in)
template<int NTAPS, int RELU, int RES>
__launch_bounds__(256)
__global__ void convm_k(const float* __restrict__ X, const float* __restrict__ W,
                        const float* __restrict__ bias, const float* __restrict__ Res,
                        float* __restrict__ Y, int dil) {
  const int d = (NTAPS == 3) ? dil : 0;
  const int width = 128 + 2 * d;
  __shared__ __align__(16) _Float16 Ws16[NTAPS][64][72];
  __shared__ __align__(16) _Float16 Xs16[192][72];
  const int t0 = blockIdx.x * 128, c0 = blockIdx.y * 64;
  const int tid = threadIdx.x;
  const int l = tid & 63, w = tid >> 6;
  const int wm = w & 1, wn = w >> 1;
  const int l31 = l & 31, q = l >> 5;
  f32x16 acc0, acc1;
#pragma unroll
  for (int i = 0; i < 16; i++) { acc0[i] = 0.f; acc1[i] = 0.f; }
  const int xk = tid >> 2;
  const int xu0 = tid & 3;
  for (int kc = 0; kc < 512; kc += 64) {
    __syncthreads();
    {
      const float* xr = X + (size_t)(kc + xk) * TT;
      for (int u = xu0; u < width; u += 4) {
        const int gt = t0 - d + u;
        const float v = (gt >= 0 && gt < TT) ? xr[gt] : 0.f;
        Xs16[u][xk] = (_Float16)v;
      }
    }
    if (NTAPS == 3) {
      for (int e = tid; e < 64 * 64 * 3; e += 256) {
        const int tap = e % 3; const int r = e / 3;
        const int i = r & 63; const int c = r >> 6;
        Ws16[tap][c][i] = (_Float16)W[((size_t)(c0 + c) * 512 + kc + i) * 3 + tap];
      }
    } else {
      for (int e = tid; e < 1024; e += 256) {
        const int c = e >> 4, i0 = (e & 15) << 2;
        const float4 wv = *reinterpret_cast<const float4*>(W + (size_t)(c0 + c) * 512 + kc + i0);
        Ws16[0][c][i0 + 0] = (_Float16)wv.x; Ws16[0][c][i0 + 1] = (_Float16)wv.y;
        Ws16[0][c][i0 + 2] = (_Float16)wv.z; Ws16[0][c][i0 + 3] = (_Float16)wv.w;
      }
    }
    __syncthreads();
#pragma unroll
    for (int tap = 0; tap < NTAPS; tap++) {
#pragma unroll
      for (int ks = 0; ks < 4; ks++) {
        const int k0 = ks * 16 + q * 8;
        const f16x8 a = *reinterpret_cast<const f16x8*>(&Ws16[tap][wm * 32 + l31][k0]);
        const int row0 = wn * 64 + l31 + tap * d;
        const f16x8 b0 = *reinterpret_cast<const f16x8*>(&Xs16[row0][k0]);
        acc0 = __builtin_amdgcn_mfma_f32_32x32x16_f16(a, b0, acc0, 0, 0, 0);
        const f16x8 b1 = *reinterpret_cast<const f16x8*>(&Xs16[row0 + 32][k0]);
        acc1 = __builtin_amdgcn_mfma_f32_32x32x16_f16(a, b1, acc1, 0, 0, 0);
      }
    }
  }
#pragma unroll
  for (int r = 0; r < 16; r++) {
    const int m = wm * 32 + (r & 3) + 8 * (r >> 2) + 4 * q;
    const int c = c0 + m;
    const float bb = bias[c];
    {
      const int t = t0 + wn * 64 + l31;
      float v = acc0[r] + bb;
      if (RES) v += Res[(size_t)c * TT + t];
      if (RELU) v = fmaxf(v, 0.f);
      Y[(size_t)c * TT + t] = v;
    }
    {
      const int t = t0 + wn * 64 + 32 + l31;
      float v = acc1[r] + bb;
      if (RES) v += Res[(size_t)c * TT + t];
      if (RELU) v = fmaxf(v, 0.f);
      Y[(size_t)c * TT + t] = v;
    }
  }
}

// -------------------- tiled transpose (512,T) -> out (T,512) + f32 copy (T,512)
__launch_bounds__(256)
__global__ void temit_k(const float* __restrict__ Xin, float* __restrict__ outp,
                        float* __restrict__ Aout) {
  __shared__ float tile[32][33];
  const int t0 = blockIdx.x * 32, d0 = blockIdx.y * 32;
  const int lx = threadIdx.x & 31, ly = threadIdx.x >> 5;
#pragma unroll
  for (int r = 0; r < 4; r++)
    tile[ly + 8 * r][lx] = Xin[(size_t)(d0 + ly + 8 * r) * TT + t0 + lx];
  __syncthreads();
#pragma unroll
  for (int r = 0; r < 4; r++) {
    const int t = t0 + ly + 8 * r, dd = d0 + lx;
    const float v = tile[lx][ly + 8 * r];
    outp[(size_t)t * 512 + dd] = v;
    Aout[(size_t)t * 512 + dd] = v;
  }
}

// ---------------------------------------------------------------- cosine sim
__global__ void nsim_k(const float* __restrict__ V, const float* __restrict__ text,
                       const float* __restrict__ tnorm, float* __restrict__ out, int R) {
  int idx = blockIdx.x * 256 + threadIdx.x;
  if (idx >= R * 32) return;
  int r = idx >> 5, c = idx & 31;
  const float* vr = V + (size_t)r * 512;
  float ss = 0.f, dot = 0.f;
  for (int dd = 0; dd < 512; dd++) {
    float v = vr[dd];
    ss += v * v;
    dot += v * text[(size_t)c * 512 + dd];
  }
  out[idx] = dot / (sqrtf(ss) * tnorm[c]);
}

// ======================================================================= host
extern "C" void kernel_launch(void* const* d_in, const int* in_sizes, int n_in,
                              void* d_out, int out_size, void* d_ws, size_t ws_size,
                              hipStream_t stream) {
  const float* in_ff   = (const float*)d_in[0];
  const float* in_act  = (const float*)d_in[1];
  const float* in_fpos = (const float*)d_in[2];
  const float* in_apos = (const float*)d_in[3];
  const float* in_text = (const float*)d_in[4];
  const float* Wf2c = (const float*)d_in[5];  const float* bf2c = (const float*)d_in[6];
  const float* Wa2c = (const float*)d_in[7];  const float* ba2c = (const float*)d_in[8];
  const float* Ws2c = (const float*)d_in[9];  const float* bs2c = (const float*)d_in[10];
  const float* Wih_f = (const float*)d_in[11]; const float* Whh_f = (const float*)d_in[12];
  const float* bih_f = (const float*)d_in[13]; const float* bhh_f = (const float*)d_in[14];
  const float* Wih_b = (const float*)d_in[15]; const float* Whh_b = (const float*)d_in[16];
  const float* bih_b = (const float*)d_in[17]; const float* bhh_b = (const float*)d_in[18];
  const float* Wcomb = (const float*)d_in[19]; const float* bcomb = (const float*)d_in[20];
  const float* f2a_Wq = (const float*)d_in[21]; const float* f2a_Wk = (const float*)d_in[22];
  const float* f2a_Wv = (const float*)d_in[23]; const float* f2a_Wo = (const float*)d_in[24];
  const float* f2a_bo = (const float*)d_in[25];
  const float* ag_Wih = (const float*)d_in[26]; const float* ag_Whh = (const float*)d_in[27];
  const float* ag_bih = (const float*)d_in[28]; const float* ag_bhh = (const float*)d_in[29];
  const float* a2f_Wq = (const float*)d_in[30]; const float* a2f_Wk = (const float*)d_in[31];
  const float* a2f_Wv = (const float*)d_in[32]; const float* a2f_Wo = (const float*)d_in[33];
  const float* a2f_bo = (const float*)d_in[34];
  const float* Wsf = (const float*)d_in[35]; const float* bsf = (const float*)d_in[36];
  const float* tcn_inW = (const float*)d_in[37]; const float* tcn_inb = (const float*)d_in[38];
  const float* tcn_dW = (const float*)d_in[39]; const float* tcn_db = (const float*)d_in[40];
  const float* tcn_pW = (const float*)d_in[41]; const float* tcn_pb = (const float*)d_in[42];
  const float* tcn_outW = (const float*)d_in[43]; const float* tcn_outb = (const float*)d_in[44];

  int S = (out_size - (TT * DD + MM * DD + TT * CC + MM * CC)) / CC;
  if (S < 1) S = 1;
  if (S > TT) S = TT;
  const int Spad = (S + 63) & ~63;

  char* ws = (char*)d_ws;
  size_t off = 0;
  auto alloc = [&](size_t b) -> char* { char* p = ws + off; off += (b + 255) & ~(size_t)255; return p; };
  int* flgF = (int*)alloc((size_t)S * 64 * 4);
  int* flgB = (int*)alloc((size_t)S * 64 * 4);
  int* flgA = (int*)alloc((size_t)MM * 256 * 4);
  const size_t zero_words = off / 4;
  const size_t BTD = (size_t)TT * DD * 4;
  float* bufA = (float*)alloc(BTD);
  float* bufB = (float*)alloc(BTD);
  int* pred    = (int*)alloc((size_t)TT * 4);
  int* segid   = (int*)alloc((size_t)TT * 4);
  int* starts  = (int*)alloc((size_t)TT * 4);
  int* centers = (int*)alloc((size_t)TT * 4);
  int* cnts    = (int*)alloc((size_t)TT * 4);
  float* tnorm = (float*)alloc(32 * 4);
  float* segmean = (float*)alloc((size_t)Spad * 512 * 4);
  float* gif  = (float*)alloc((size_t)Spad * 768 * 4);
  float* gib  = (float*)alloc((size_t)Spad * 768 * 4);
  float* hfb  = (float*)alloc((size_t)Spad * 256 * 4);
  float* hbb  = (float*)alloc((size_t)Spad * 256 * 4);
  float* acmb = (float*)alloc((size_t)Spad * 512 * 4);
  float* segc = (float*)alloc((size_t)Spad * 512 * 4);
  float* segpos = (float*)alloc((size_t)Spad * 512 * 4);
  float* kin  = (float*)alloc((size_t)Spad * 512 * 4);
  float* kf2a = (float*)alloc((size_t)Spad * 512 * 4);
  float* vf2a = (float*)alloc((size_t)Spad * 512 * 4);
  float* q2   = (float*)alloc((size_t)Spad * 512 * 4);
  float* att2 = (float*)alloc((size_t)Spad * 512 * 4);
  float* seg2 = (float*)alloc((size_t)Spad * 512 * 4);
  float* vseg = (float*)alloc((size_t)Spad * 512 * 4);
  float* pbuf = (float*)alloc((size_t)64 * Spad * 4);
  float* qin  = (float*)alloc((size_t)64 * 512 * 4);
  float* qf2a = (float*)alloc((size_t)64 * 512 * 4);
  float* att1 = (float*)alloc((size_t)64 * 512 * 4);
  float* af0  = (float*)alloc((size_t)64 * 512 * 4);
  float* aggi = (float*)alloc((size_t)64 * 1536 * 4);
  float* afg  = (float*)alloc((size_t)64 * 512 * 4);
  float* k2in = (float*)alloc((size_t)64 * 512 * 4);
  float* k2   = (float*)alloc((size_t)64 * 512 * 4);
  float* v2   = (float*)alloc((size_t)64 * 512 * 4);
  float* vaf  = (float*)alloc((size_t)64 * 512 * 4);
  (void)ws_size; (void)in_sizes; (void)n_in;

  float* outp = (float*)d_out;
  float* out_ff   = outp;
  float* out_af   = outp + (size_t)TT * DD;
  float* out_fsim = out_af + (size_t)MM * DD;
  float* out_asim = out_fsim + (size_t)TT * CC;
  float* out_ssim = out_asim + (size_t)MM * CC;

  auto GR = [](long n) { return (unsigned)((n + 255) / 256); };
  const unsigned Sg = (unsigned)(Spad / 64);

  zero_k<<<256, 256, 0, stream>>>((float*)d_ws, (long)zero_words);

  tnorm_k<<<1, 256, 0, stream>>>(in_text, tnorm);

  // segmentation (fp32 GEMM: argmax stability)
  gemm_k<<<dim3(8, 128), 256, 0, stream>>>(in_ff, Wf2c, bf2c, bufA, TT, 512, 512);
  argmax_k<<<TT, 256, 0, stream>>>(bufA, in_text, tnorm, pred);
  segscan_k<<<1, 256, 0, stream>>>(pred, segid, starts, centers, cnts);
  segmean_k<<<GR((long)S * 512), 256, 0, stream>>>(in_ff, starts, cnts, segmean, S);

  // seg BiGRU
  gemmm_k<<<dim3(6, Sg), 256, 0, stream>>>(segmean, Wih_f, bih_f, gif, Spad, 768, 512);
  gemmm_k<<<dim3(6, Sg), 256, 0, stream>>>(segmean, Wih_b, bih_b, gib, Spad, 768, 512);
  gru_seg_mb_k<<<8, 192, 0, stream>>>(gif, gib, Whh_f, bhh_f, Whh_b, bhh_b,
                                      hfb, hbb, S, flgF, flgB);
  acomb_k<<<GR((long)S * 512), 256, 0, stream>>>(hfb, hbb, acmb, S * 512);
  gemmm_k<<<dim3(4, Sg), 256, 0, stream>>>(acmb, Wcomb, bcomb, segc, Spad, 512, 512);
  gatherpos_k<<<GR((long)S * 512), 256, 0, stream>>>(in_fpos, centers, segpos, S * 512);

  // f2a attention (actions query segments)
  addff_k<<<GR(64 * 512), 256, 0, stream>>>(in_act, in_apos, qin, 64 * 512);
  addff_k<<<GR((long)S * 512), 256, 0, stream>>>(segc, segpos, kin, S * 512);
  gemmm_k<<<dim3(4, 1), 256, 0, stream>>>(qin, f2a_Wq, nullptr, qf2a, 64, 512, 512);
  gemmm_k<<<dim3(4, Sg), 256, 0, stream>>>(kin, f2a_Wk, nullptr, kf2a, Spad, 512, 512);
  gemmm_k<<<dim3(4, Sg), 256, 0, stream>>>(segc, f2a_Wv, nullptr, vf2a, Spad, 512, 512);
  nlogit_k<<<GR((long)64 * S), 256, 0, stream>>>(qf2a, kf2a, pbuf, 64, S);
  nsoft_k<<<1, 256, 0, stream>>>(pbuf, 64, S);
  nav_k<<<GR(64 * 512), 256, 0, stream>>>(pbuf, vf2a, att1, 64, S);
  gemmm_k<<<dim3(4, 1), 256, 0, stream>>>(att1, f2a_Wo, f2a_bo, af0, 64, 512, 512);

  // action GRU
  gemmm_k<<<dim3(12, 1), 256, 0, stream>>>(af0, ag_Wih, ag_bih, aggi, 64, 1536, 512);
  gru_act_mb_k<<<16, 128, 0, stream>>>(aggi, ag_Whh, ag_bhh, afg, MM, flgA);
  copy_k<<<GR(64 * 512), 256, 0, stream>>>(afg, out_af, 64 * 512);

  // a2f attention (segments query actions)
  addff_k<<<GR(64 * 512), 256, 0, stream>>>(afg, in_apos, k2in, 64 * 512);
  gemmm_k<<<dim3(4, Sg), 256, 0, stream>>>(kin, a2f_Wq, nullptr, q2, Spad, 512, 512);
  gemmm_k<<<dim3(4, 1), 256, 0, stream>>>(k2in, a2f_Wk, nullptr, k2, 64, 512, 512);
  gemmm_k<<<dim3(4, 1), 256, 0, stream>>>(afg, a2f_Wv, nullptr, v2, 64, 512, 512);
  nlogit_k<<<GR((long)S * 64), 256, 0, stream>>>(q2, k2, pbuf, S, 64);
  nsoft_k<<<GR(S), 256, 0, stream>>>(pbuf, S, 64);
  nav_k<<<GR((long)S * 512), 256, 0, stream>>>(pbuf, v2, att2, S, 64);
  gemmm_k<<<dim3(4, Sg), 256, 0, stream>>>(att2, a2f_Wo, a2f_bo, seg2, Spad, 512, 512);

  // frame fusion + TCN (MFMA), ping-pong bufA <-> bufB as (D,T)
  ff2m_k<<<dim3(64, 8), 256, 0, stream>>>(seg2, in_ff, segid, Wsf, bsf, bufA, S);
  convm_k<1, 0, 0><<<dim3(64, 8), 256, 0, stream>>>(bufA, tcn_inW, tcn_inb, nullptr, bufB, 1);
  for (int l = 0; l < 6; l++) {
    convm_k<3, 1, 0><<<dim3(64, 8), 256, 0, stream>>>(
        bufB, tcn_dW + (size_t)l * 512 * 512 * 3, tcn_db + (size_t)l * 512, nullptr, bufA, 1 << l);
    convm_k<1, 0, 1><<<dim3(64, 8), 256, 0, stream>>>(
        bufA, tcn_pW + (size_t)l * 512 * 512, tcn_pb + (size_t)l * 512, bufB, bufB, 1);
  }
  convm_k<1, 0, 0><<<dim3(64, 8), 256, 0, stream>>>(bufB, tcn_outW, tcn_outb, nullptr, bufA, 1);
  temit_k<<<dim3(256, 16), 256, 0, stream>>>(bufA, out_ff, bufB);

  // similarity heads
  gemmm_k<<<dim3(4, 128), 256, 0, stream>>>(bufB, Wf2c, bf2c, bufA, TT, 512, 512);
  nsim_k<<<GR((long)TT * 32), 256, 0, stream>>>(bufA, in_text, tnorm, out_fsim, TT);
  gemmm_k<<<dim3(4, 1), 256, 0, stream>>>(afg, Wa2c, ba2c, vaf, 64, 512, 512);
  nsim_k<<<GR(64 * 32), 256, 0, stream>>>(vaf, in_text, tnorm, out_asim, 64);
  gemmm_k<<<dim3(4, Sg), 256, 0, stream>>>(seg2, Ws2c, bs2c, vseg, Spad, 512, 512);
  nsim_k<<<GR((long)S * 32), 256, 0, stream>>>(vseg, in_text, tnorm, out_ssim, S);
}